// Round 7
// baseline (4956.844 us; speedup 1.0000x reference)
//
#include <hip/hip_runtime.h>
#include <math.h>

// Problem constants
#define NB 64      // batch
#define NS 128     // seq len
#define ND 1024    // input dim
#define NH 512     // hidden
#define NG 2048    // 4*H
#define NTOT 255   // 2S-1
#define NSTEPS 127 // S-1
#define NWV 511
#define NPV 152

// ws layout:
//  xpb    : ushort [2][128][2048][64] = 33,554,432 us
//  h_all  : float  [2][128][512][64]  =  8,388,608 f
//  vec    : float  [64][255][512]     =  8,355,840 f
//  h_bf   : ushort [2][128][64][512]  =  8,388,608 us   ([pos][b][k])
//  elmo_bf: ushort [128*64][1024]     =  8,388,608 us   ([t*64+b][k])
//  W_bf   : ushort [4096][1024]       =  4,194,304 us
//  bar    : int [8192]
static const size_t XPB_SZ = (size_t)2 * NS * NG * NB;
static const size_t H_SZ   = (size_t)2 * NS * NH * NB;
static const size_t VEC_SZ = (size_t)NB * NTOT * NH;
static const size_t HB_SZ  = (size_t)2 * NS * NH * NB;
static const size_t EB_SZ  = (size_t)NB * NS * ND;
static const size_t WB_SZ  = (size_t)4096 * ND;

typedef __attribute__((ext_vector_type(8))) short short8v;
typedef __attribute__((ext_vector_type(8))) unsigned short ushort8v;
typedef __attribute__((ext_vector_type(4))) float float4v;

__device__ __forceinline__ float sigm(float x) { return 1.f / (1.f + __expf(-x)); }
__device__ __forceinline__ float tanh_fast(float x) {
  const float e = __expf(2.f * x);
  return 1.f - 2.f / (e + 1.f);
}
__device__ __forceinline__ unsigned short f2bf(float x) {
  unsigned b = __float_as_uint(x);
  return (unsigned short)((b + 0x7FFFu + ((b >> 16) & 1u)) >> 16);
}
__device__ __forceinline__ float bf2f(unsigned short u) {
  return __uint_as_float(((unsigned)u) << 16);
}

#define FMA4x4(acc, av, bv)                                                    \
  acc[0][0] += av.x * bv.x; acc[0][1] += av.x * bv.y;                          \
  acc[0][2] += av.x * bv.z; acc[0][3] += av.x * bv.w;                          \
  acc[1][0] += av.y * bv.x; acc[1][1] += av.y * bv.y;                          \
  acc[1][2] += av.y * bv.z; acc[1][3] += av.y * bv.w;                          \
  acc[2][0] += av.z * bv.x; acc[2][1] += av.z * bv.y;                          \
  acc[2][2] += av.z * bv.z; acc[2][3] += av.z * bv.w;                          \
  acc[3][0] += av.w * bv.x; acc[3][1] += av.w * bv.y;                          \
  acc[3][2] += av.w * bv.z; acc[3][3] += av.w * bv.w;

// ---------------- K0: fp32 -> bf16 conversions + barrier zero -------------
// elmo[b][t][k] -> elmo_bf[(t*64+b)][k]; wf||wb -> W_bf[n][k]; bar = 0.
__global__ __launch_bounds__(256) void k_cvt(
    const float* __restrict__ elmo, const float* __restrict__ wf,
    const float* __restrict__ wb, unsigned short* __restrict__ elmo_bf,
    unsigned short* __restrict__ W_bf, int* __restrict__ bar) {
  const int gid = blockIdx.x * 256 + threadIdx.x;
  if (gid < 8192) bar[gid] = 0;
  const int NE4 = (NB * NS * ND) / 4;   // 2,097,152
  const int NW4 = (4096 * ND) / 4;      // 1,048,576
  const int NW4h = NW4 / 2;
  for (int i = gid; i < NE4 + NW4; i += gridDim.x * 256) {
    float4 v;
    unsigned short* dst;
    if (i < NE4) {
      const int e0 = i << 2;
      const int b = e0 >> 17;            // /(128*1024)
      const int t = (e0 >> 10) & 127;
      const int k = e0 & 1023;
      v = *(const float4*)(elmo + e0);
      dst = elmo_bf + ((size_t)((t << 6) + b) << 10) + k;
    } else {
      const int j = i - NE4;
      v = (j < NW4h) ? *(const float4*)(wf + ((size_t)j << 2))
                     : *(const float4*)(wb + ((size_t)(j - NW4h) << 2));
      dst = W_bf + ((size_t)j << 2);
    }
    uint2 u;
    u.x = (unsigned)f2bf(v.x) | ((unsigned)f2bf(v.y) << 16);
    u.y = (unsigned)f2bf(v.z) | ((unsigned)f2bf(v.w) << 16);
    *(uint2*)dst = u;
  }
}

// ---------------- K1: xp = elmo @ w_ih^T + bias (bf16 MFMA) ---------------
// M = 8192 (m = t*64+b), N = 4096 (dir*2048+grow), K = 1024. 128x128 tile.
// Output bf16 xpb[dir][t][grow][b].
// FIX r7: staging now covers ALL 128 rows (r6 bug: only rows 0..63 staged).
__global__ __launch_bounds__(256) void k_xp(
    const unsigned short* __restrict__ elmo_bf,
    const unsigned short* __restrict__ W_bf,
    const float* __restrict__ biasf, const float* __restrict__ biasb,
    unsigned short* __restrict__ xpb) {
  __shared__ unsigned short As[128 * 64];  // 16 KB, swizzled
  __shared__ unsigned short Bs[128 * 64];  // 16 KB
  const int tid = threadIdx.x;
  const int n0 = blockIdx.x * 128;
  const int m0 = blockIdx.y * 128;
  const int wv = tid >> 6, lane = tid & 63;
  const int cl = lane & 15, bq = lane >> 4;
  const int wm = (wv >> 1) << 6;   // 0 / 64
  const int wn = (wv & 1) << 6;    // 0 / 64
  // staging: thread -> (row sr of 128, k-half skc of 32)
  const int sr = tid >> 1, skc = (tid & 1) << 5;
  const unsigned short* asrc = elmo_bf + (size_t)(m0 + sr) * ND + skc;
  const unsigned short* bsrc = W_bf + (size_t)(n0 + sr) * ND + skc;
  const int sswz = (sr & 15) << 3;
  // bias-initialized accumulators
  float4v acc[4][4];
#pragma unroll
  for (int nt = 0; nt < 4; ++nt) {
    const int n = n0 + wn + nt * 16 + cl;
    const float bv = (n < 2048) ? biasf[n] : biasb[n - 2048];
#pragma unroll
    for (int mt = 0; mt < 4; ++mt) acc[mt][nt] = (float4v){bv, bv, bv, bv};
  }
  for (int k0 = 0; k0 < ND; k0 += 64) {
    ushort8v av4[4], bv4[4];
#pragma unroll
    for (int i = 0; i < 4; ++i) av4[i] = *(const ushort8v*)(asrc + k0 + 8 * i);
#pragma unroll
    for (int i = 0; i < 4; ++i) bv4[i] = *(const ushort8v*)(bsrc + k0 + 8 * i);
    __syncthreads();  // prior-iter reads done
#pragma unroll
    for (int i = 0; i < 4; ++i) {
      *(ushort8v*)&As[((sr << 6) + skc + 8 * i) ^ sswz] = av4[i];
      *(ushort8v*)&Bs[((sr << 6) + skc + 8 * i) ^ sswz] = bv4[i];
    }
    __syncthreads();
#pragma unroll
    for (int ks = 0; ks < 2; ++ks) {
      const int koff = (ks << 5) + (bq << 3);
      short8v af[4], bf_[4];
#pragma unroll
      for (int mt = 0; mt < 4; ++mt) {
        const int ar = wm + mt * 16 + cl;
        af[mt] = *(const short8v*)&As[((ar << 6) + koff) ^ ((ar & 15) << 3)];
      }
#pragma unroll
      for (int nt = 0; nt < 4; ++nt) {
        const int br = wn + nt * 16 + cl;
        bf_[nt] = *(const short8v*)&Bs[((br << 6) + koff) ^ ((br & 15) << 3)];
      }
#pragma unroll
      for (int mt = 0; mt < 4; ++mt)
#pragma unroll
        for (int nt = 0; nt < 4; ++nt)
          acc[mt][nt] =
              __builtin_amdgcn_mfma_f32_16x16x32_bf16(af[mt], bf_[nt], acc[mt][nt], 0, 0, 0);
    }
  }
  // epilogue: bf16 stores, 4 consecutive b per lane
#pragma unroll
  for (int mt = 0; mt < 4; ++mt) {
    const int mbase = m0 + wm + mt * 16 + (bq << 2);
    const int t = mbase >> 6, b4 = mbase & 63;
#pragma unroll
    for (int nt = 0; nt < 4; ++nt) {
      const int n = n0 + wn + nt * 16 + cl;
      const int dir = n >> 11, grow = n & 2047;
      const float4v a = acc[mt][nt];
      uint2 u;
      u.x = (unsigned)f2bf(a[0]) | ((unsigned)f2bf(a[1]) << 16);
      u.y = (unsigned)f2bf(a[2]) | ((unsigned)f2bf(a[3]) << 16);
      *(uint2*)&xpb[(((size_t)dir * NS + t) * NG + grow) * NB + b4] = u;
    }
  }
}

// ---------------- K2: persistent BiLSTM scan, v5 --------------------------
// 64 blocks (2 dir x 32 cols-of-16) x 1024 thr (4 waves/SIMD).
// 16 waves = 4 M-tiles x 4 gates; full-K per wave (no cross-wave reduce).
// gateS exchange (17 KB); 1024 update threads own one (b,col) cell each.
__global__ __launch_bounds__(1024) void k_lstm(
    const float* __restrict__ whh_f, const float* __restrict__ whh_b,
    const unsigned short* __restrict__ xpb, float* __restrict__ h_all,
    unsigned short* __restrict__ h_bf, int* __restrict__ bar) {
  __shared__ unsigned short WS[64 * 512];              // 64 KB, swizzled
  __shared__ unsigned short hS[64 * 512];              // 64 KB, swizzled
  __shared__ __align__(16) float gateS[4][16][68];     // 17 KB
  const int bid = blockIdx.x;
  const int dir = bid >> 5;
  const int col0 = (bid & 31) << 4;
  const int tid = threadIdx.x;
  const int lane = tid & 63;
  const int wv = tid >> 6;          // 0..15
  const int cl = lane & 15, bq = lane >> 4;
  const int g = wv & 3, mt = wv >> 2;
  const float* whh = dir ? whh_b : whh_f;

  // one-time: W slice fp32 -> bf16 LDS. thread -> (gr, kc of 32)
  {
    const int gr = tid >> 4;              // 0..63 = g*16 + col_local
    const int kc = (tid & 15) << 5;
    const int gg = gr >> 4, cc = gr & 15;
    const float* src = whh + (size_t)(gg * NH + col0 + cc) * NH + kc;
    const int swz = (gr & 15) << 3;
#pragma unroll
    for (int i = 0; i < 4; ++i) {
      const float4 f0 = *(const float4*)(src + 8 * i);
      const float4 f1 = *(const float4*)(src + 8 * i + 4);
      ushort8v u;
      u[0] = f2bf(f0.x); u[1] = f2bf(f0.y); u[2] = f2bf(f0.z); u[3] = f2bf(f0.w);
      u[4] = f2bf(f1.x); u[5] = f2bf(f1.y); u[6] = f2bf(f1.z); u[7] = f2bf(f1.w);
      *(ushort8v*)&WS[((gr << 9) + kc + 8 * i) ^ swz] = u;
    }
  }
  __syncthreads();

  const unsigned short* xpd = xpb + (size_t)dir * NS * NG * NB;
  float* hd = h_all + (size_t)dir * NS * NH * NB;
  unsigned short* hb = h_bf + (size_t)dir * NS * NH * NB;

  // update-thread identity
  const int ub = tid >> 4;     // b 0..63
  const int uc = tid & 15;     // col_local 0..15
  const int ucol = col0 + uc;
  float c = 0.f;

  // staging identity: thread -> (b, kc of 32)
  const int stb = tid >> 4;
  const int stk = (tid & 15) << 5;
  const int stswz = (stb & 15) << 3;

  // MFMA read bases
  const int arow = mt * 16 + cl;
  const int gr_b = g * 16 + cl;
  const int aswz = (arow & 15) << 3;
  const int bswz = (cl & 15) << 3;

  for (int t = 0; t < NS; ++t) {
    const int pos = dir ? (NS - 1 - t) : t;
    // xp prefetch (bf16 scalars, consumed after MFMA)
    const unsigned short* xrow = xpd + (size_t)pos * NG * NB;
    unsigned short xu0 = xrow[(size_t)(0 * NH + ucol) * NB + ub];
    unsigned short xu1 = xrow[(size_t)(1 * NH + ucol) * NB + ub];
    unsigned short xu2 = xrow[(size_t)(2 * NH + ucol) * NB + ub];
    unsigned short xu3 = xrow[(size_t)(3 * NH + ucol) * NB + ub];
    float4v acc = {0.f, 0.f, 0.f, 0.f};
    if (t > 0) {
      const int prevpos = dir ? (pos + 1) : (pos - 1);
      const unsigned short* hsrc = hb + (size_t)prevpos * NH * NB;  // [b][k]
#pragma unroll
      for (int i = 0; i < 4; ++i) {
        const ushort8v v = *(const ushort8v*)(hsrc + ((size_t)stb << 9) + stk + 8 * i);
        *(ushort8v*)&hS[((stb << 9) + stk + 8 * i) ^ stswz] = v;
      }
      __syncthreads();
#pragma unroll
      for (int ks = 0; ks < 16; ++ks) {
        const int koff = (ks << 5) + (bq << 3);
        const short8v a = *(const short8v*)&hS[((arow << 9) + koff) ^ aswz];
        const short8v b = *(const short8v*)&WS[((gr_b << 9) + koff) ^ bswz];
        acc = __builtin_amdgcn_mfma_f32_16x16x32_bf16(a, b, acc, 0, 0, 0);
      }
      *(float4*)&gateS[g][cl][(mt << 4) + (bq << 2)] =
          make_float4(acc[0], acc[1], acc[2], acc[3]);
      __syncthreads();
    }
    // update (all 1024 threads, one cell each)
    float gv0 = bf2f(xu0), gv1 = bf2f(xu1), gv2 = bf2f(xu2), gv3 = bf2f(xu3);
    if (t > 0) {
      gv0 += gateS[0][uc][ub];
      gv1 += gateS[1][uc][ub];
      gv2 += gateS[2][uc][ub];
      gv3 += gateS[3][uc][ub];
    }
    const float ig = sigm(gv0), fg = sigm(gv1), og = sigm(gv3);
    const float gc = tanh_fast(gv2);
    c = fg * c + ig * gc;
    const float h = og * tanh_fast(c);
    hd[((size_t)pos * NH + ucol) * NB + ub] = h;            // fp32 [pos][k][b]
    hb[((size_t)pos * NB + ub) * NH + ucol] = f2bf(h);      // bf16 [pos][b][k]
    if (t < NS - 1) {
      __builtin_amdgcn_fence(__ATOMIC_RELEASE, "agent");
      __syncthreads();
      if (tid == 0) {
        int* ctr = &bar[(((t << 1) + dir) << 5)];
        __hip_atomic_fetch_add(ctr, 1, __ATOMIC_RELAXED, __HIP_MEMORY_SCOPE_AGENT);
        while (__hip_atomic_load(ctr, __ATOMIC_ACQUIRE, __HIP_MEMORY_SCOPE_AGENT) < 32)
          __builtin_amdgcn_s_sleep(1);
      }
      __syncthreads();
      __builtin_amdgcn_fence(__ATOMIC_ACQUIRE, "agent");
    }
  }
}

// ---------------- K3: combined = lrelu(fwd@W1^T + bwd@W2^T) -> vec --------
__global__ __launch_bounds__(256) void k_comb(
    const float* __restrict__ h_all, const float* __restrict__ W1,
    const float* __restrict__ W2, float* __restrict__ vec) {
  __shared__ float A1[16][68], A2[16][68], B1[16][68], B2[16][68];
  const int tid = threadIdx.x;
  const int n0 = blockIdx.x * 64;
  const int s = blockIdx.y;
  const float* h0 = h_all + (size_t)s * NH * NB;
  const float* h1 = h_all + ((size_t)NS + s) * NH * NB;
  const int aj = tid >> 4, ai4 = (tid & 15) << 2;
  const int lr = tid >> 2, lc4 = (tid & 3) << 2;
  const int tx = tid & 15, ty = tid >> 4;
  const float* b1row = W1 + (size_t)(n0 + lr) * NH;
  const float* b2row = W2 + (size_t)(n0 + lr) * NH;
  float acc[4][4] = {};
  for (int k0 = 0; k0 < NH; k0 += 16) {
    *(float4*)&A1[aj][ai4] = *(const float4*)(h0 + (size_t)(k0 + aj) * NB + ai4);
    *(float4*)&A2[aj][ai4] = *(const float4*)(h1 + (size_t)(k0 + aj) * NB + ai4);
    const float4 w1 = *(const float4*)(b1row + k0 + lc4);
    B1[lc4 + 0][lr] = w1.x; B1[lc4 + 1][lr] = w1.y;
    B1[lc4 + 2][lr] = w1.z; B1[lc4 + 3][lr] = w1.w;
    const float4 w2 = *(const float4*)(b2row + k0 + lc4);
    B2[lc4 + 0][lr] = w2.x; B2[lc4 + 1][lr] = w2.y;
    B2[lc4 + 2][lr] = w2.z; B2[lc4 + 3][lr] = w2.w;
    __syncthreads();
#pragma unroll
    for (int kk = 0; kk < 16; ++kk) {
      const float4 a1 = *(const float4*)&A1[kk][ty << 2];
      const float4 b1 = *(const float4*)&B1[kk][tx << 2];
      FMA4x4(acc, a1, b1)
      const float4 a2 = *(const float4*)&A2[kk][ty << 2];
      const float4 b2 = *(const float4*)&B2[kk][tx << 2];
      FMA4x4(acc, a2, b2)
    }
    __syncthreads();
  }
#pragma unroll
  for (int i = 0; i < 4; ++i) {
    const int b = (ty << 2) + i;
#pragma unroll
    for (int j = 0; j < 4; ++j) {
      const int nn = n0 + (tx << 2) + j;
      float v = acc[i][j];
      v = v > 0.f ? v : 0.01f * v;
      vec[((size_t)b * NTOT + s) * NH + nn] = v;
    }
  }
}

// ---------------- K4: l2-normalize word rows of vec -----------------------
__global__ __launch_bounds__(256) void k_norm(float* __restrict__ vec) {
  const int row = (blockIdx.x << 2) + (threadIdx.x >> 6);  // 0..8191
  const int lane = threadIdx.x & 63;
  const int b = row >> 7, s = row & 127;
  float* p = vec + ((size_t)b * NTOT + s) * NH;
  float4 v0 = *(float4*)(p + (lane << 3));
  float4 v1 = *(float4*)(p + (lane << 3) + 4);
  float ss = v0.x * v0.x + v0.y * v0.y + v0.z * v0.z + v0.w * v0.w +
             v1.x * v1.x + v1.y * v1.y + v1.z * v1.z + v1.w * v1.w;
#pragma unroll
  for (int off = 32; off; off >>= 1) ss += __shfl_down(ss, off);
  ss = __shfl(ss, 0);
  const float sc = 1.f / fmaxf(sqrtf(ss), 1e-12f);
  v0.x *= sc; v0.y *= sc; v0.z *= sc; v0.w *= sc;
  v1.x *= sc; v1.y *= sc; v1.z *= sc; v1.w *= sc;
  *(float4*)(p + (lane << 3)) = v0;
  *(float4*)(p + (lane << 3) + 4) = v1;
}

// ---------------- K5: per-batch tree composition scan ---------------------
__global__ __launch_bounds__(512) void k_compose(
    float* __restrict__ vec, const int* __restrict__ cinfo) {
  __shared__ float lv[512];
  __shared__ float rvd[1028];
  __shared__ float cpart[4][512];
  __shared__ float red[9];
  const int b = blockIdx.x;
  const int tid = threadIdx.x;
  float* vb = vec + (size_t)b * NTOT * NH;
  const int* ib = cinfo + b * NSTEPS * 4;
  const int jq = tid >> 7;
  const int k4 = (tid & 127) << 2;
  const int wid = tid >> 6, lane = tid & 63;
  for (int i = 0; i < NSTEPS; ++i) {
    const int tt = ib[i * 4 + 0], p = ib[i * 4 + 1];
    const int l = ib[i * 4 + 2], r = ib[i * 4 + 3];
    lv[tid] = vb[(size_t)l * NH + tid];
    const float rvv = vb[(size_t)r * NH + tid];
    rvd[tid] = rvv;
    rvd[512 + tid] = rvv;
    __syncthreads();
    float a0 = 0.f, a1 = 0.f, a2 = 0.f, a3 = 0.f;
    if (tt == 2) {
      const int jb = jq << 7;
#pragma unroll 8
      for (int jj = 0; jj < 128; jj += 4) {
        const int j = jb + jj;
        const float4 l4 = *(const float4*)&lv[j];
        const float4 r0 = *(const float4*)&rvd[j + k4];
        const float4 r1 = *(const float4*)&rvd[j + k4 + 4];
        a0 += l4.x * r0.x + l4.y * r0.y + l4.z * r0.z + l4.w * r0.w;
        a1 += l4.x * r0.y + l4.y * r0.z + l4.z * r0.w + l4.w * r1.x;
        a2 += l4.x * r0.z + l4.y * r0.w + l4.z * r1.x + l4.w * r1.y;
        a3 += l4.x * r0.w + l4.y * r1.x + l4.z * r1.y + l4.w * r1.z;
      }
    }
    cpart[jq][k4 + 0] = a0; cpart[jq][k4 + 1] = a1;
    cpart[jq][k4 + 2] = a2; cpart[jq][k4 + 3] = a3;
    __syncthreads();
    const float ck = cpart[0][tid] + cpart[1][tid] + cpart[2][tid] + cpart[3][tid];
    float ss = ck * ck;
#pragma unroll
    for (int off = 32; off; off >>= 1) ss += __shfl_down(ss, off);
    if (lane == 0) red[wid] = ss;
    __syncthreads();
    if (tid == 0) {
      float tot = 0.f;
#pragma unroll
      for (int w = 0; w < 8; ++w) tot += red[w];
      red[8] = 1.f / fmaxf(sqrtf(tot), 1e-12f);
    }
    __syncthreads();
    if (tt == 2) {
      vb[(size_t)p * NH + tid] = ck * red[8];
    } else if (tt == 1) {
      vb[(size_t)p * NH + tid] = lv[tid];
    }
    __syncthreads();
  }
}

// ---------------- K6: output GEMMs (word / phrase) ------------------------
template <int MODE>
__global__ __launch_bounds__(256) void k_out(
    const float* __restrict__ vec, const float* __restrict__ W,
    const float* __restrict__ bias, float* __restrict__ out) {
  constexpr int NOUT = MODE ? NPV : NWV;
  __shared__ float As[16][68], Bs[16][68];
  const int tid = threadIdx.x;
  const int n0 = blockIdx.x * 64, m0 = blockIdx.y * 64;
  const int lr = tid >> 2, lc4 = (tid & 3) << 2;
  const int tx = tid & 15, ty = tid >> 4;
  const int m = m0 + lr;
  int vr;
  if (MODE == 0) {
    vr = (m >> 7) * NTOT + (m & 127);
  } else {
    const int bb = m / 127;
    vr = bb * NTOT + NS + (m - bb * 127);
  }
  const float* arow = vec + (size_t)vr * NH;
  const int n = n0 + lr;
  const float* brow = W + (size_t)n * NH;
  const bool bok = (n < NOUT);
  float acc[4][4] = {};
  for (int k0 = 0; k0 < NH; k0 += 16) {
    const float4 a4 = *(const float4*)(arow + k0 + lc4);
    As[lc4 + 0][lr] = a4.x; As[lc4 + 1][lr] = a4.y;
    As[lc4 + 2][lr] = a4.z; As[lc4 + 3][lr] = a4.w;
    float4 b4 = make_float4(0.f, 0.f, 0.f, 0.f);
    if (bok) b4 = *(const float4*)(brow + k0 + lc4);
    Bs[lc4 + 0][lr] = b4.x; Bs[lc4 + 1][lr] = b4.y;
    Bs[lc4 + 2][lr] = b4.z; Bs[lc4 + 3][lr] = b4.w;
    __syncthreads();
#pragma unroll
    for (int kk = 0; kk < 16; ++kk) {
      const float4 av = *(const float4*)&As[kk][ty << 2];
      const float4 bv = *(const float4*)&Bs[kk][tx << 2];
      FMA4x4(acc, av, bv)
    }
    __syncthreads();
  }
#pragma unroll
  for (int i = 0; i < 4; ++i)
#pragma unroll
    for (int j = 0; j < 4; ++j) {
      const int nn = n0 + (tx << 2) + j;
      if (nn < NOUT)
        out[(size_t)(m0 + (ty << 2) + i) * NOUT + nn] = acc[i][j] + bias[nn];
    }
}

// ---------------- K7: labels (int32 -> f32 copy) --------------------------
__global__ __launch_bounds__(256) void k_labels(
    const int* __restrict__ lab, float* __restrict__ outw,
    float* __restrict__ outp) {
  const int i = blockIdx.x * 256 + threadIdx.x;
  if (i < NB * NS) {
    const int b = i >> 7, s = i & 127;
    outw[i] = (float)lab[b * NTOT + s];
  }
  if (i < NB * NSTEPS) {
    const int b = i / 127;
    outp[i] = (float)lab[b * NTOT + NS + (i - b * 127)];
  }
}

extern "C" void kernel_launch(void* const* d_in, const int* in_sizes, int n_in,
                              void* d_out, int out_size, void* d_ws, size_t ws_size,
                              hipStream_t stream) {
  (void)in_sizes; (void)n_in; (void)out_size; (void)ws_size;
  const float* elmo     = (const float*)d_in[0];
  const float* w_ih_f   = (const float*)d_in[1];
  const float* w_hh_f   = (const float*)d_in[2];
  const float* b_f      = (const float*)d_in[3];
  const float* w_ih_b   = (const float*)d_in[4];
  const float* w_hh_b   = (const float*)d_in[5];
  const float* b_b      = (const float*)d_in[6];
  const float* W1       = (const float*)d_in[7];
  const float* W2       = (const float*)d_in[8];
  const float* word_W   = (const float*)d_in[9];
  const float* word_b   = (const float*)d_in[10];
  const float* phrase_W = (const float*)d_in[11];
  const float* phrase_b = (const float*)d_in[12];
  const int* cinfo      = (const int*)d_in[13];
  const int* lab        = (const int*)d_in[15];

  unsigned short* xpb  = (unsigned short*)d_ws;
  float* h_all         = (float*)(xpb + XPB_SZ);
  float* vec           = h_all + H_SZ;
  unsigned short* h_bf = (unsigned short*)(vec + VEC_SZ);
  unsigned short* e_bf = h_bf + HB_SZ;
  unsigned short* W_bf = e_bf + EB_SZ;
  int* bar             = (int*)(W_bf + WB_SZ);

  float* out_word = (float*)d_out;                       // 8192 x 511
  float* out_phr  = out_word + (size_t)8192 * NWV;       // 8128 x 152
  float* out_lw   = out_phr + (size_t)8128 * NPV;        // 8192
  float* out_lp   = out_lw + 8192;                       // 8128

  k_cvt<<<dim3(2048), 256, 0, stream>>>(elmo, w_ih_f, w_ih_b, e_bf, W_bf, bar);
  k_xp<<<dim3(32, 64), 256, 0, stream>>>(e_bf, W_bf, b_f, b_b, xpb);
  k_lstm<<<dim3(64), 1024, 0, stream>>>(w_hh_f, w_hh_b, xpb, h_all, h_bf, bar);
  k_comb<<<dim3(8, 128), 256, 0, stream>>>(h_all, W1, W2, vec);
  k_norm<<<dim3(2048), 256, 0, stream>>>(vec);
  k_compose<<<dim3(64), 512, 0, stream>>>(vec, cinfo);
  k_out<0><<<dim3(8, 128), 256, 0, stream>>>(vec, word_W, word_b, out_word);
  k_out<1><<<dim3(3, 127), 256, 0, stream>>>(vec, phrase_W, phrase_b, out_phr);
  k_labels<<<dim3(32), 256, 0, stream>>>(lab, out_lw, out_lp);
}

// Round 8
// 2642.919 us; speedup vs baseline: 1.8755x; 1.8755x over previous
//
#include <hip/hip_runtime.h>
#include <math.h>

// Problem constants
#define NB 64      // batch
#define NS 128     // seq len
#define ND 1024    // input dim
#define NH 512     // hidden
#define NG 2048    // 4*H
#define NTOT 255   // 2S-1
#define NSTEPS 127 // S-1
#define NWV 511
#define NPV 152

// ws layout:
//  xpb    : ushort [2][128][32][4][16][64] = 33,554,432 us  (per-block chunks)
//  h_all  : float  [2][128][512][64]  =  8,388,608 f
//  vec    : float  [64][255][512]     =  8,355,840 f
//  h_bf   : ushort [2][128][64][512]  =  8,388,608 us   ([pos][b][k])
//  elmo_bf: ushort [128*64][1024]     =  8,388,608 us   ([t*64+b][k])
//  W_bf   : ushort [4096][1024]       =  4,194,304 us
//  bar    : int [8192]
static const size_t XPB_SZ = (size_t)2 * NS * NG * NB;
static const size_t H_SZ   = (size_t)2 * NS * NH * NB;
static const size_t VEC_SZ = (size_t)NB * NTOT * NH;
static const size_t HB_SZ  = (size_t)2 * NS * NH * NB;
static const size_t EB_SZ  = (size_t)NB * NS * ND;
static const size_t WB_SZ  = (size_t)4096 * ND;

typedef __attribute__((ext_vector_type(8))) short short8v;
typedef __attribute__((ext_vector_type(8))) unsigned short ushort8v;
typedef __attribute__((ext_vector_type(4))) float float4v;

__device__ __forceinline__ float sigm(float x) { return 1.f / (1.f + __expf(-x)); }
__device__ __forceinline__ float tanh_fast(float x) {
  const float e = __expf(2.f * x);
  return 1.f - 2.f / (e + 1.f);
}
__device__ __forceinline__ unsigned short f2bf(float x) {
  unsigned b = __float_as_uint(x);
  return (unsigned short)((b + 0x7FFFu + ((b >> 16) & 1u)) >> 16);
}
__device__ __forceinline__ float bf2f(unsigned short u) {
  return __uint_as_float(((unsigned)u) << 16);
}

#define FMA4x4(acc, av, bv)                                                    \
  acc[0][0] += av.x * bv.x; acc[0][1] += av.x * bv.y;                          \
  acc[0][2] += av.x * bv.z; acc[0][3] += av.x * bv.w;                          \
  acc[1][0] += av.y * bv.x; acc[1][1] += av.y * bv.y;                          \
  acc[1][2] += av.y * bv.z; acc[1][3] += av.y * bv.w;                          \
  acc[2][0] += av.z * bv.x; acc[2][1] += av.z * bv.y;                          \
  acc[2][2] += av.z * bv.z; acc[2][3] += av.z * bv.w;                          \
  acc[3][0] += av.w * bv.x; acc[3][1] += av.w * bv.y;                          \
  acc[3][2] += av.w * bv.z; acc[3][3] += av.w * bv.w;

// ---------------- K0: fp32 -> bf16 conversions + barrier zero -------------
__global__ __launch_bounds__(256) void k_cvt(
    const float* __restrict__ elmo, const float* __restrict__ wf,
    const float* __restrict__ wb, unsigned short* __restrict__ elmo_bf,
    unsigned short* __restrict__ W_bf, int* __restrict__ bar) {
  const int gid = blockIdx.x * 256 + threadIdx.x;
  if (gid < 8192) bar[gid] = 0;
  const int NE4 = (NB * NS * ND) / 4;   // 2,097,152
  const int NW4 = (4096 * ND) / 4;      // 1,048,576
  const int NW4h = NW4 / 2;
  for (int i = gid; i < NE4 + NW4; i += gridDim.x * 256) {
    float4 v;
    unsigned short* dst;
    if (i < NE4) {
      const int e0 = i << 2;
      const int b = e0 >> 17;
      const int t = (e0 >> 10) & 127;
      const int k = e0 & 1023;
      v = *(const float4*)(elmo + e0);
      dst = elmo_bf + ((size_t)((t << 6) + b) << 10) + k;
    } else {
      const int j = i - NE4;
      v = (j < NW4h) ? *(const float4*)(wf + ((size_t)j << 2))
                     : *(const float4*)(wb + ((size_t)(j - NW4h) << 2));
      dst = W_bf + ((size_t)j << 2);
    }
    uint2 u;
    u.x = (unsigned)f2bf(v.x) | ((unsigned)f2bf(v.y) << 16);
    u.y = (unsigned)f2bf(v.z) | ((unsigned)f2bf(v.w) << 16);
    *(uint2*)dst = u;
  }
}

// ---------------- K1: xp = elmo @ w_ih^T + bias (bf16 MFMA) ---------------
// Output layout (for k_lstm block-contiguous reads):
//   xpb[(((dir*128 + t)*32 + cb)*4 + g)*1024 + cl*64 + b]   (ushort bf16)
__global__ __launch_bounds__(256) void k_xp(
    const unsigned short* __restrict__ elmo_bf,
    const unsigned short* __restrict__ W_bf,
    const float* __restrict__ biasf, const float* __restrict__ biasb,
    unsigned short* __restrict__ xpb) {
  __shared__ unsigned short As[128 * 64];  // 16 KB, swizzled
  __shared__ unsigned short Bs[128 * 64];  // 16 KB
  const int tid = threadIdx.x;
  const int n0 = blockIdx.x * 128;
  const int m0 = blockIdx.y * 128;
  const int wv = tid >> 6, lane = tid & 63;
  const int cl = lane & 15, bq = lane >> 4;
  const int wm = (wv >> 1) << 6;   // 0 / 64
  const int wn = (wv & 1) << 6;    // 0 / 64
  // staging: thread -> (row sr of 128, k-half skc of 32)
  const int sr = tid >> 1, skc = (tid & 1) << 5;
  const unsigned short* asrc = elmo_bf + (size_t)(m0 + sr) * ND + skc;
  const unsigned short* bsrc = W_bf + (size_t)(n0 + sr) * ND + skc;
  const int sswz = (sr & 15) << 3;
  float4v acc[4][4];
#pragma unroll
  for (int nt = 0; nt < 4; ++nt) {
    const int n = n0 + wn + nt * 16 + cl;
    const float bv = (n < 2048) ? biasf[n] : biasb[n - 2048];
#pragma unroll
    for (int mt = 0; mt < 4; ++mt) acc[mt][nt] = (float4v){bv, bv, bv, bv};
  }
  for (int k0 = 0; k0 < ND; k0 += 64) {
    ushort8v av4[4], bv4[4];
#pragma unroll
    for (int i = 0; i < 4; ++i) av4[i] = *(const ushort8v*)(asrc + k0 + 8 * i);
#pragma unroll
    for (int i = 0; i < 4; ++i) bv4[i] = *(const ushort8v*)(bsrc + k0 + 8 * i);
    __syncthreads();
#pragma unroll
    for (int i = 0; i < 4; ++i) {
      *(ushort8v*)&As[((sr << 6) + skc + 8 * i) ^ sswz] = av4[i];
      *(ushort8v*)&Bs[((sr << 6) + skc + 8 * i) ^ sswz] = bv4[i];
    }
    __syncthreads();
#pragma unroll
    for (int ks = 0; ks < 2; ++ks) {
      const int koff = (ks << 5) + (bq << 3);
      short8v af[4], bf_[4];
#pragma unroll
      for (int mt = 0; mt < 4; ++mt) {
        const int ar = wm + mt * 16 + cl;
        af[mt] = *(const short8v*)&As[((ar << 6) + koff) ^ ((ar & 15) << 3)];
      }
#pragma unroll
      for (int nt = 0; nt < 4; ++nt) {
        const int br = wn + nt * 16 + cl;
        bf_[nt] = *(const short8v*)&Bs[((br << 6) + koff) ^ ((br & 15) << 3)];
      }
#pragma unroll
      for (int mt = 0; mt < 4; ++mt)
#pragma unroll
        for (int nt = 0; nt < 4; ++nt)
          acc[mt][nt] =
              __builtin_amdgcn_mfma_f32_16x16x32_bf16(af[mt], bf_[nt], acc[mt][nt], 0, 0, 0);
    }
  }
  // epilogue: 8B stores into block-chunked layout
#pragma unroll
  for (int mt = 0; mt < 4; ++mt) {
    const int mbase = m0 + wm + mt * 16 + (bq << 2);
    const int t = mbase >> 6, b4 = mbase & 63;
#pragma unroll
    for (int nt = 0; nt < 4; ++nt) {
      const int n = n0 + wn + nt * 16 + cl;
      const int dir = n >> 11, grow = n & 2047;
      const int g = grow >> 9, cb = (grow & 511) >> 4;
      const float4v a = acc[mt][nt];
      uint2 u;
      u.x = (unsigned)f2bf(a[0]) | ((unsigned)f2bf(a[1]) << 16);
      u.y = (unsigned)f2bf(a[2]) | ((unsigned)f2bf(a[3]) << 16);
      const size_t idx =
          ((((size_t)(dir * NS + t) * 32 + cb) * 4 + g) << 10) + (cl << 6) + b4;
      *(uint2*)&xpb[idx] = u;
    }
  }
}

// ---------------- K2: persistent BiLSTM scan, v6 --------------------------
// 64 blocks (2 dir x 32 col-blocks of 16) x 256 thr (4 waves).
// Wave = 16-b M-tile; per wave 4 gates x 16 K-step MFMAs (full K=512).
// h exchange via agent-scope RELAXED atomics (SC-bit coherence, NO fences:
// L2 stays warm for xp/W). Barrier: syncthreads -> tid0 relaxed add+poll.
__global__ __launch_bounds__(256) void k_lstm(
    const float* __restrict__ whh_f, const float* __restrict__ whh_b,
    const unsigned short* __restrict__ xpb, float* __restrict__ h_all,
    unsigned short* __restrict__ h_bf, int* __restrict__ bar) {
  __shared__ unsigned short WS[64 * 512];   // 64 KB, swizzled [gr][k]
  __shared__ unsigned short hS[64 * 512];   // 64 KB, swizzled [b][k]
  const int bid = blockIdx.x;
  const int dir = bid >> 5;
  const int cb = bid & 31;
  const int col0 = cb << 4;
  const int tid = threadIdx.x;
  const int lane = tid & 63;
  const int w = tid >> 6;          // wave = M-tile
  const int cl = lane & 15, bq = lane >> 4;
  const int b4 = (w << 4) + (bq << 2);   // 4 owned b rows
  const float* whh = dir ? whh_b : whh_f;

  // one-time: W slice fp32 -> bf16 LDS. thread -> (gr = tid>>2, kc = (tid&3)*128)
  {
    const int gr = tid >> 2;
    const int kc = (tid & 3) << 7;
    const int gg = gr >> 4, cc = gr & 15;
    const float* src = whh + (size_t)(gg * NH + col0 + cc) * NH + kc;
    const int swz = (gr & 15) << 3;
#pragma unroll
    for (int i = 0; i < 16; ++i) {
      const float4 f0 = *(const float4*)(src + 8 * i);
      const float4 f1 = *(const float4*)(src + 8 * i + 4);
      ushort8v u;
      u[0] = f2bf(f0.x); u[1] = f2bf(f0.y); u[2] = f2bf(f0.z); u[3] = f2bf(f0.w);
      u[4] = f2bf(f1.x); u[5] = f2bf(f1.y); u[6] = f2bf(f1.z); u[7] = f2bf(f1.w);
      *(ushort8v*)&WS[((gr << 9) + kc + 8 * i) ^ swz] = u;
    }
  }
  __syncthreads();

  float* hd = h_all + (size_t)dir * NS * NH * NB;
  unsigned short* hb_us = h_bf + ((size_t)dir * NS << 15);      // [pos][b][k]
  unsigned long long* hb_ull = (unsigned long long*)h_bf + ((size_t)dir * NS << 12);

  const int aswz = (((w << 4) + cl) & 15) << 3;   // = cl<<3
  const int arow = (w << 4) + cl;
  float4v c4 = {0.f, 0.f, 0.f, 0.f};

  for (int t = 0; t < NS; ++t) {
    const int pos = dir ? (NS - 1 - t) : t;
    // xp prefetch: 4 gates x uint2 (4 b) from block-contiguous chunk
    const unsigned short* xc =
        xpb + ((((size_t)(dir * NS + pos) * 32 + cb) << 12));
    uint2 xg[4];
#pragma unroll
    for (int g = 0; g < 4; ++g)
      xg[g] = *(const uint2*)&xc[(g << 10) + (cl << 6) + b4];

    float4v acc[4] = {{0.f, 0.f, 0.f, 0.f}, {0.f, 0.f, 0.f, 0.f},
                      {0.f, 0.f, 0.f, 0.f}, {0.f, 0.f, 0.f, 0.f}};
    if (t > 0) {
      const int prevpos = dir ? (pos + 1) : (pos - 1);
      unsigned long long* hsrc = hb_ull + ((size_t)prevpos << 13);  // 8192 ull
#pragma unroll
      for (int i = 0; i < 32; ++i) {
        const int u = (i << 8) + tid;
        const int bb = u >> 7, k4 = (u & 127) << 2;
        const unsigned long long v = __hip_atomic_load(
            &hsrc[u], __ATOMIC_RELAXED, __HIP_MEMORY_SCOPE_AGENT);
        *(unsigned long long*)&hS[((bb << 9) + k4) ^ ((bb & 15) << 3)] = v;
      }
      __syncthreads();
#pragma unroll
      for (int ks = 0; ks < 16; ++ks) {
        const int koff = (ks << 5) + (bq << 3);
        const short8v a = *(const short8v*)&hS[((arow << 9) + koff) ^ aswz];
#pragma unroll
        for (int g = 0; g < 4; ++g) {
          const short8v bb =
              *(const short8v*)&WS[((((g << 4) + cl) << 9) + koff) ^ (cl << 3)];
          acc[g] = __builtin_amdgcn_mfma_f32_16x16x32_bf16(a, bb, acc[g], 0, 0, 0);
        }
      }
    }
    // cell update: this thread owns (col0+cl, b4..b4+3)
    float hv[4];
#pragma unroll
    for (int i = 0; i < 4; ++i) {
      const unsigned xw0 = (i < 2) ? xg[0].x : xg[0].y;
      const unsigned xw1 = (i < 2) ? xg[1].x : xg[1].y;
      const unsigned xw2 = (i < 2) ? xg[2].x : xg[2].y;
      const unsigned xw3 = (i < 2) ? xg[3].x : xg[3].y;
      const int sh = (i & 1) << 4;
      const float gi = sigm(acc[0][i] + bf2f((unsigned short)(xw0 >> sh)));
      const float gf = sigm(acc[1][i] + bf2f((unsigned short)(xw1 >> sh)));
      const float gc = tanh_fast(acc[2][i] + bf2f((unsigned short)(xw2 >> sh)));
      const float go = sigm(acc[3][i] + bf2f((unsigned short)(xw3 >> sh)));
      c4[i] = gf * c4[i] + gi * gc;
      hv[i] = go * tanh_fast(c4[i]);
    }
    // fp32 h for k_comb (normal store; consumed after kernel end)
    *(float4*)(hd + ((size_t)pos * NH + col0 + cl) * NB + b4) =
        make_float4(hv[0], hv[1], hv[2], hv[3]);
    // bf16 h exchange: SC-coherent scalar stores [pos][b][col0+cl]
    unsigned short* hp = hb_us + ((size_t)pos << 15) + col0 + cl;
#pragma unroll
    for (int i = 0; i < 4; ++i)
      __hip_atomic_store(&hp[(size_t)(b4 + i) << 9], f2bf(hv[i]),
                         __ATOMIC_RELAXED, __HIP_MEMORY_SCOPE_AGENT);
    if (t < NS - 1) {
      __syncthreads();  // implicit vmcnt drain: h stores complete per wave
      if (tid == 0) {
        int* ctr = &bar[(((t << 1) + dir) << 5)];
        __hip_atomic_fetch_add(ctr, 1, __ATOMIC_RELAXED, __HIP_MEMORY_SCOPE_AGENT);
        while (__hip_atomic_load(ctr, __ATOMIC_RELAXED, __HIP_MEMORY_SCOPE_AGENT) < 32)
          __builtin_amdgcn_s_sleep(1);
      }
      __syncthreads();
    }
  }
}

// ---------------- K3: combined = lrelu(fwd@W1^T + bwd@W2^T) -> vec --------
__global__ __launch_bounds__(256) void k_comb(
    const float* __restrict__ h_all, const float* __restrict__ W1,
    const float* __restrict__ W2, float* __restrict__ vec) {
  __shared__ float A1[16][68], A2[16][68], B1[16][68], B2[16][68];
  const int tid = threadIdx.x;
  const int n0 = blockIdx.x * 64;
  const int s = blockIdx.y;
  const float* h0 = h_all + (size_t)s * NH * NB;
  const float* h1 = h_all + ((size_t)NS + s) * NH * NB;
  const int aj = tid >> 4, ai4 = (tid & 15) << 2;
  const int lr = tid >> 2, lc4 = (tid & 3) << 2;
  const int tx = tid & 15, ty = tid >> 4;
  const float* b1row = W1 + (size_t)(n0 + lr) * NH;
  const float* b2row = W2 + (size_t)(n0 + lr) * NH;
  float acc[4][4] = {};
  for (int k0 = 0; k0 < NH; k0 += 16) {
    *(float4*)&A1[aj][ai4] = *(const float4*)(h0 + (size_t)(k0 + aj) * NB + ai4);
    *(float4*)&A2[aj][ai4] = *(const float4*)(h1 + (size_t)(k0 + aj) * NB + ai4);
    const float4 w1 = *(const float4*)(b1row + k0 + lc4);
    B1[lc4 + 0][lr] = w1.x; B1[lc4 + 1][lr] = w1.y;
    B1[lc4 + 2][lr] = w1.z; B1[lc4 + 3][lr] = w1.w;
    const float4 w2 = *(const float4*)(b2row + k0 + lc4);
    B2[lc4 + 0][lr] = w2.x; B2[lc4 + 1][lr] = w2.y;
    B2[lc4 + 2][lr] = w2.z; B2[lc4 + 3][lr] = w2.w;
    __syncthreads();
#pragma unroll
    for (int kk = 0; kk < 16; ++kk) {
      const float4 a1 = *(const float4*)&A1[kk][ty << 2];
      const float4 b1 = *(const float4*)&B1[kk][tx << 2];
      FMA4x4(acc, a1, b1)
      const float4 a2 = *(const float4*)&A2[kk][ty << 2];
      const float4 b2 = *(const float4*)&B2[kk][tx << 2];
      FMA4x4(acc, a2, b2)
    }
    __syncthreads();
  }
#pragma unroll
  for (int i = 0; i < 4; ++i) {
    const int b = (ty << 2) + i;
#pragma unroll
    for (int j = 0; j < 4; ++j) {
      const int nn = n0 + (tx << 2) + j;
      float v = acc[i][j];
      v = v > 0.f ? v : 0.01f * v;
      vec[((size_t)b * NTOT + s) * NH + nn] = v;
    }
  }
}

// ---------------- K4: l2-normalize word rows of vec -----------------------
__global__ __launch_bounds__(256) void k_norm(float* __restrict__ vec) {
  const int row = (blockIdx.x << 2) + (threadIdx.x >> 6);  // 0..8191
  const int lane = threadIdx.x & 63;
  const int b = row >> 7, s = row & 127;
  float* p = vec + ((size_t)b * NTOT + s) * NH;
  float4 v0 = *(float4*)(p + (lane << 3));
  float4 v1 = *(float4*)(p + (lane << 3) + 4);
  float ss = v0.x * v0.x + v0.y * v0.y + v0.z * v0.z + v0.w * v0.w +
             v1.x * v1.x + v1.y * v1.y + v1.z * v1.z + v1.w * v1.w;
#pragma unroll
  for (int off = 32; off; off >>= 1) ss += __shfl_down(ss, off);
  ss = __shfl(ss, 0);
  const float sc = 1.f / fmaxf(sqrtf(ss), 1e-12f);
  v0.x *= sc; v0.y *= sc; v0.z *= sc; v0.w *= sc;
  v1.x *= sc; v1.y *= sc; v1.z *= sc; v1.w *= sc;
  *(float4*)(p + (lane << 3)) = v0;
  *(float4*)(p + (lane << 3) + 4) = v1;
}

// ---------------- K5: per-batch tree composition scan ---------------------
__global__ __launch_bounds__(512) void k_compose(
    float* __restrict__ vec, const int* __restrict__ cinfo) {
  __shared__ float lv[512];
  __shared__ float rvd[1028];
  __shared__ float cpart[4][512];
  __shared__ float red[9];
  const int b = blockIdx.x;
  const int tid = threadIdx.x;
  float* vb = vec + (size_t)b * NTOT * NH;
  const int* ib = cinfo + b * NSTEPS * 4;
  const int jq = tid >> 7;
  const int k4 = (tid & 127) << 2;
  const int wid = tid >> 6, lane = tid & 63;
  for (int i = 0; i < NSTEPS; ++i) {
    const int tt = ib[i * 4 + 0], p = ib[i * 4 + 1];
    const int l = ib[i * 4 + 2], r = ib[i * 4 + 3];
    lv[tid] = vb[(size_t)l * NH + tid];
    const float rvv = vb[(size_t)r * NH + tid];
    rvd[tid] = rvv;
    rvd[512 + tid] = rvv;
    __syncthreads();
    float a0 = 0.f, a1 = 0.f, a2 = 0.f, a3 = 0.f;
    if (tt == 2) {
      const int jb = jq << 7;
#pragma unroll 8
      for (int jj = 0; jj < 128; jj += 4) {
        const int j = jb + jj;
        const float4 l4 = *(const float4*)&lv[j];
        const float4 r0 = *(const float4*)&rvd[j + k4];
        const float4 r1 = *(const float4*)&rvd[j + k4 + 4];
        a0 += l4.x * r0.x + l4.y * r0.y + l4.z * r0.z + l4.w * r0.w;
        a1 += l4.x * r0.y + l4.y * r0.z + l4.z * r0.w + l4.w * r1.x;
        a2 += l4.x * r0.z + l4.y * r0.w + l4.z * r1.x + l4.w * r1.y;
        a3 += l4.x * r0.w + l4.y * r1.x + l4.z * r1.y + l4.w * r1.z;
      }
    }
    cpart[jq][k4 + 0] = a0; cpart[jq][k4 + 1] = a1;
    cpart[jq][k4 + 2] = a2; cpart[jq][k4 + 3] = a3;
    __syncthreads();
    const float ck = cpart[0][tid] + cpart[1][tid] + cpart[2][tid] + cpart[3][tid];
    float ss = ck * ck;
#pragma unroll
    for (int off = 32; off; off >>= 1) ss += __shfl_down(ss, off);
    if (lane == 0) red[wid] = ss;
    __syncthreads();
    if (tid == 0) {
      float tot = 0.f;
#pragma unroll
      for (int w = 0; w < 8; ++w) tot += red[w];
      red[8] = 1.f / fmaxf(sqrtf(tot), 1e-12f);
    }
    __syncthreads();
    if (tt == 2) {
      vb[(size_t)p * NH + tid] = ck * red[8];
    } else if (tt == 1) {
      vb[(size_t)p * NH + tid] = lv[tid];
    }
    __syncthreads();
  }
}

// ---------------- K6: output GEMMs (word / phrase) ------------------------
template <int MODE>
__global__ __launch_bounds__(256) void k_out(
    const float* __restrict__ vec, const float* __restrict__ W,
    const float* __restrict__ bias, float* __restrict__ out) {
  constexpr int NOUT = MODE ? NPV : NWV;
  __shared__ float As[16][68], Bs[16][68];
  const int tid = threadIdx.x;
  const int n0 = blockIdx.x * 64, m0 = blockIdx.y * 64;
  const int lr = tid >> 2, lc4 = (tid & 3) << 2;
  const int tx = tid & 15, ty = tid >> 4;
  const int m = m0 + lr;
  int vr;
  if (MODE == 0) {
    vr = (m >> 7) * NTOT + (m & 127);
  } else {
    const int bb = m / 127;
    vr = bb * NTOT + NS + (m - bb * 127);
  }
  const float* arow = vec + (size_t)vr * NH;
  const int n = n0 + lr;
  const float* brow = W + (size_t)n * NH;
  const bool bok = (n < NOUT);
  float acc[4][4] = {};
  for (int k0 = 0; k0 < NH; k0 += 16) {
    const float4 a4 = *(const float4*)(arow + k0 + lc4);
    As[lc4 + 0][lr] = a4.x; As[lc4 + 1][lr] = a4.y;
    As[lc4 + 2][lr] = a4.z; As[lc4 + 3][lr] = a4.w;
    float4 b4 = make_float4(0.f, 0.f, 0.f, 0.f);
    if (bok) b4 = *(const float4*)(brow + k0 + lc4);
    Bs[lc4 + 0][lr] = b4.x; Bs[lc4 + 1][lr] = b4.y;
    Bs[lc4 + 2][lr] = b4.z; Bs[lc4 + 3][lr] = b4.w;
    __syncthreads();
#pragma unroll
    for (int kk = 0; kk < 16; ++kk) {
      const float4 av = *(const float4*)&As[kk][ty << 2];
      const float4 bv = *(const float4*)&Bs[kk][tx << 2];
      FMA4x4(acc, av, bv)
    }
    __syncthreads();
  }
#pragma unroll
  for (int i = 0; i < 4; ++i)
#pragma unroll
    for (int j = 0; j < 4; ++j) {
      const int nn = n0 + (tx << 2) + j;
      if (nn < NOUT)
        out[(size_t)(m0 + (ty << 2) + i) * NOUT + nn] = acc[i][j] + bias[nn];
    }
}

// ---------------- K7: labels (int32 -> f32 copy) --------------------------
__global__ __launch_bounds__(256) void k_labels(
    const int* __restrict__ lab, float* __restrict__ outw,
    float* __restrict__ outp) {
  const int i = blockIdx.x * 256 + threadIdx.x;
  if (i < NB * NS) {
    const int b = i >> 7, s = i & 127;
    outw[i] = (float)lab[b * NTOT + s];
  }
  if (i < NB * NSTEPS) {
    const int b = i / 127;
    outp[i] = (float)lab[b * NTOT + NS + (i - b * 127)];
  }
}

extern "C" void kernel_launch(void* const* d_in, const int* in_sizes, int n_in,
                              void* d_out, int out_size, void* d_ws, size_t ws_size,
                              hipStream_t stream) {
  (void)in_sizes; (void)n_in; (void)out_size; (void)ws_size;
  const float* elmo     = (const float*)d_in[0];
  const float* w_ih_f   = (const float*)d_in[1];
  const float* w_hh_f   = (const float*)d_in[2];
  const float* b_f      = (const float*)d_in[3];
  const float* w_ih_b   = (const float*)d_in[4];
  const float* w_hh_b   = (const float*)d_in[5];
  const float* b_b      = (const float*)d_in[6];
  const float* W1       = (const float*)d_in[7];
  const float* W2       = (const float*)d_in[8];
  const float* word_W   = (const float*)d_in[9];
  const float* word_b   = (const float*)d_in[10];
  const float* phrase_W = (const float*)d_in[11];
  const float* phrase_b = (const float*)d_in[12];
  const int* cinfo      = (const int*)d_in[13];
  const int* lab        = (const int*)d_in[15];

  unsigned short* xpb  = (unsigned short*)d_ws;
  float* h_all         = (float*)(xpb + XPB_SZ);
  float* vec           = h_all + H_SZ;
  unsigned short* h_bf = (unsigned short*)(vec + VEC_SZ);
  unsigned short* e_bf = h_bf + HB_SZ;
  unsigned short* W_bf = e_bf + EB_SZ;
  int* bar             = (int*)(W_bf + WB_SZ);

  float* out_word = (float*)d_out;                       // 8192 x 511
  float* out_phr  = out_word + (size_t)8192 * NWV;       // 8128 x 152
  float* out_lw   = out_phr + (size_t)8128 * NPV;        // 8192
  float* out_lp   = out_lw + 8192;                       // 8128

  k_cvt<<<dim3(2048), 256, 0, stream>>>(elmo, w_ih_f, w_ih_b, e_bf, W_bf, bar);
  k_xp<<<dim3(32, 64), 256, 0, stream>>>(e_bf, W_bf, b_f, b_b, xpb);
  k_lstm<<<dim3(64), 256, 0, stream>>>(w_hh_f, w_hh_b, xpb, h_all, h_bf, bar);
  k_comb<<<dim3(8, 128), 256, 0, stream>>>(h_all, W1, W2, vec);
  k_norm<<<dim3(2048), 256, 0, stream>>>(vec);
  k_compose<<<dim3(64), 512, 0, stream>>>(vec, cinfo);
  k_out<0><<<dim3(8, 128), 256, 0, stream>>>(vec, word_W, word_b, out_word);
  k_out<1><<<dim3(3, 127), 256, 0, stream>>>(vec, phrase_W, phrase_b, out_phr);
  k_labels<<<dim3(32), 256, 0, stream>>>(lab, out_lw, out_lp);
}

// Round 9
// 2621.958 us; speedup vs baseline: 1.8905x; 1.0080x over previous
//
#include <hip/hip_runtime.h>
#include <math.h>

// Problem constants
#define NB 64      // batch
#define NS 128     // seq len
#define ND 1024    // input dim
#define NH 512     // hidden
#define NG 2048    // 4*H
#define NTOT 255   // 2S-1
#define NSTEPS 127 // S-1
#define NWV 511
#define NPV 152

// ws layout:
//  xpb    : ushort [2][128][32][4][16][64] = 33,554,432 us  (per-block chunks)
//  h_all  : float  [2][128][512][64]  =  8,388,608 f
//  vec    : float  [64][255][512]     =  8,355,840 f
//  h_bf   : ushort [2][128][64][512]  =  8,388,608 us   ([pos][b][k])
//  elmo_bf: ushort [128*64][1024]     =  8,388,608 us   ([t*64+b][k])
//  W_bf   : ushort [4096][1024]       =  4,194,304 us
//  bar    : int [8192]
static const size_t XPB_SZ = (size_t)2 * NS * NG * NB;
static const size_t H_SZ   = (size_t)2 * NS * NH * NB;
static const size_t VEC_SZ = (size_t)NB * NTOT * NH;
static const size_t HB_SZ  = (size_t)2 * NS * NH * NB;
static const size_t EB_SZ  = (size_t)NB * NS * ND;
static const size_t WB_SZ  = (size_t)4096 * ND;

typedef __attribute__((ext_vector_type(8))) short short8v;
typedef __attribute__((ext_vector_type(8))) unsigned short ushort8v;
typedef __attribute__((ext_vector_type(4))) float float4v;

__device__ __forceinline__ float sigm(float x) { return 1.f / (1.f + __expf(-x)); }
__device__ __forceinline__ float tanh_fast(float x) {
  const float e = __expf(2.f * x);
  return 1.f - 2.f / (e + 1.f);
}
__device__ __forceinline__ unsigned short f2bf(float x) {
  unsigned b = __float_as_uint(x);
  return (unsigned short)((b + 0x7FFFu + ((b >> 16) & 1u)) >> 16);
}
__device__ __forceinline__ float bf2f(unsigned short u) {
  return __uint_as_float(((unsigned)u) << 16);
}

#define FMA4x4(acc, av, bv)                                                    \
  acc[0][0] += av.x * bv.x; acc[0][1] += av.x * bv.y;                          \
  acc[0][2] += av.x * bv.z; acc[0][3] += av.x * bv.w;                          \
  acc[1][0] += av.y * bv.x; acc[1][1] += av.y * bv.y;                          \
  acc[1][2] += av.y * bv.z; acc[1][3] += av.y * bv.w;                          \
  acc[2][0] += av.z * bv.x; acc[2][1] += av.z * bv.y;                          \
  acc[2][2] += av.z * bv.z; acc[2][3] += av.z * bv.w;                          \
  acc[3][0] += av.w * bv.x; acc[3][1] += av.w * bv.y;                          \
  acc[3][2] += av.w * bv.z; acc[3][3] += av.w * bv.w;

// ---------------- K0: fp32 -> bf16 conversions + barrier zero -------------
__global__ __launch_bounds__(256) void k_cvt(
    const float* __restrict__ elmo, const float* __restrict__ wf,
    const float* __restrict__ wb, unsigned short* __restrict__ elmo_bf,
    unsigned short* __restrict__ W_bf, int* __restrict__ bar) {
  const int gid = blockIdx.x * 256 + threadIdx.x;
  if (gid < 8192) bar[gid] = 0;
  const int NE4 = (NB * NS * ND) / 4;   // 2,097,152
  const int NW4 = (4096 * ND) / 4;      // 1,048,576
  const int NW4h = NW4 / 2;
  for (int i = gid; i < NE4 + NW4; i += gridDim.x * 256) {
    float4 v;
    unsigned short* dst;
    if (i < NE4) {
      const int e0 = i << 2;
      const int b = e0 >> 17;
      const int t = (e0 >> 10) & 127;
      const int k = e0 & 1023;
      v = *(const float4*)(elmo + e0);
      dst = elmo_bf + ((size_t)((t << 6) + b) << 10) + k;
    } else {
      const int j = i - NE4;
      v = (j < NW4h) ? *(const float4*)(wf + ((size_t)j << 2))
                     : *(const float4*)(wb + ((size_t)(j - NW4h) << 2));
      dst = W_bf + ((size_t)j << 2);
    }
    uint2 u;
    u.x = (unsigned)f2bf(v.x) | ((unsigned)f2bf(v.y) << 16);
    u.y = (unsigned)f2bf(v.z) | ((unsigned)f2bf(v.w) << 16);
    *(uint2*)dst = u;
  }
}

// ---------------- K1: xp = elmo @ w_ih^T + bias (bf16 MFMA) ---------------
// Output layout (for k_lstm block-contiguous reads):
//   xpb[(((dir*128 + t)*32 + cb)*4 + g)*1024 + cl*64 + b]   (ushort bf16)
__global__ __launch_bounds__(256) void k_xp(
    const unsigned short* __restrict__ elmo_bf,
    const unsigned short* __restrict__ W_bf,
    const float* __restrict__ biasf, const float* __restrict__ biasb,
    unsigned short* __restrict__ xpb) {
  __shared__ unsigned short As[128 * 64];  // 16 KB, swizzled
  __shared__ unsigned short Bs[128 * 64];  // 16 KB
  const int tid = threadIdx.x;
  const int n0 = blockIdx.x * 128;
  const int m0 = blockIdx.y * 128;
  const int wv = tid >> 6, lane = tid & 63;
  const int cl = lane & 15, bq = lane >> 4;
  const int wm = (wv >> 1) << 6;   // 0 / 64
  const int wn = (wv & 1) << 6;    // 0 / 64
  // staging: thread -> (row sr of 128, k-half skc of 32)
  const int sr = tid >> 1, skc = (tid & 1) << 5;
  const unsigned short* asrc = elmo_bf + (size_t)(m0 + sr) * ND + skc;
  const unsigned short* bsrc = W_bf + (size_t)(n0 + sr) * ND + skc;
  const int sswz = (sr & 15) << 3;
  float4v acc[4][4];
#pragma unroll
  for (int nt = 0; nt < 4; ++nt) {
    const int n = n0 + wn + nt * 16 + cl;
    const float bv = (n < 2048) ? biasf[n] : biasb[n - 2048];
#pragma unroll
    for (int mt = 0; mt < 4; ++mt) acc[mt][nt] = (float4v){bv, bv, bv, bv};
  }
  for (int k0 = 0; k0 < ND; k0 += 64) {
    ushort8v av4[4], bv4[4];
#pragma unroll
    for (int i = 0; i < 4; ++i) av4[i] = *(const ushort8v*)(asrc + k0 + 8 * i);
#pragma unroll
    for (int i = 0; i < 4; ++i) bv4[i] = *(const ushort8v*)(bsrc + k0 + 8 * i);
    __syncthreads();
#pragma unroll
    for (int i = 0; i < 4; ++i) {
      *(ushort8v*)&As[((sr << 6) + skc + 8 * i) ^ sswz] = av4[i];
      *(ushort8v*)&Bs[((sr << 6) + skc + 8 * i) ^ sswz] = bv4[i];
    }
    __syncthreads();
#pragma unroll
    for (int ks = 0; ks < 2; ++ks) {
      const int koff = (ks << 5) + (bq << 3);
      short8v af[4], bf_[4];
#pragma unroll
      for (int mt = 0; mt < 4; ++mt) {
        const int ar = wm + mt * 16 + cl;
        af[mt] = *(const short8v*)&As[((ar << 6) + koff) ^ ((ar & 15) << 3)];
      }
#pragma unroll
      for (int nt = 0; nt < 4; ++nt) {
        const int br = wn + nt * 16 + cl;
        bf_[nt] = *(const short8v*)&Bs[((br << 6) + koff) ^ ((br & 15) << 3)];
      }
#pragma unroll
      for (int mt = 0; mt < 4; ++mt)
#pragma unroll
        for (int nt = 0; nt < 4; ++nt)
          acc[mt][nt] =
              __builtin_amdgcn_mfma_f32_16x16x32_bf16(af[mt], bf_[nt], acc[mt][nt], 0, 0, 0);
    }
  }
  // epilogue: 8B stores into block-chunked layout
#pragma unroll
  for (int mt = 0; mt < 4; ++mt) {
    const int mbase = m0 + wm + mt * 16 + (bq << 2);
    const int t = mbase >> 6, b4 = mbase & 63;
#pragma unroll
    for (int nt = 0; nt < 4; ++nt) {
      const int n = n0 + wn + nt * 16 + cl;
      const int dir = n >> 11, grow = n & 2047;
      const int g = grow >> 9, cb = (grow & 511) >> 4;
      const float4v a = acc[mt][nt];
      uint2 u;
      u.x = (unsigned)f2bf(a[0]) | ((unsigned)f2bf(a[1]) << 16);
      u.y = (unsigned)f2bf(a[2]) | ((unsigned)f2bf(a[3]) << 16);
      const size_t idx =
          ((((size_t)(dir * NS + t) * 32 + cb) * 4 + g) << 10) + (cl << 6) + b4;
      *(uint2*)&xpb[idx] = u;
    }
  }
}

// ---------------- K2: persistent BiLSTM scan, v7 --------------------------
// v6 + (1) hard-spin barrier (no s_sleep), (2) packed 8B h-exchange stores
// via 2KB LDS bounce (1024 scalar SC stores -> 128 packed), (3) xp(t+1)
// prefetched before the barrier so its L3 latency overlaps the poll.
__global__ __launch_bounds__(256) void k_lstm(
    const float* __restrict__ whh_f, const float* __restrict__ whh_b,
    const unsigned short* __restrict__ xpb, float* __restrict__ h_all,
    unsigned short* __restrict__ h_bf, int* __restrict__ bar) {
  __shared__ unsigned short WS[64 * 512];   // 64 KB, swizzled [gr][k]
  __shared__ unsigned short hS[64 * 512];   // 64 KB, swizzled [b][k]
  __shared__ unsigned short hOut[64 * 16];  // 2 KB bounce [b][col_local]
  const int bid = blockIdx.x;
  const int dir = bid >> 5;
  const int cb = bid & 31;
  const int col0 = cb << 4;
  const int tid = threadIdx.x;
  const int lane = tid & 63;
  const int w = tid >> 6;          // wave = M-tile
  const int cl = lane & 15, bq = lane >> 4;
  const int b4 = (w << 4) + (bq << 2);   // 4 owned b rows
  const float* whh = dir ? whh_b : whh_f;

  // one-time: W slice fp32 -> bf16 LDS. thread -> (gr = tid>>2, kc = (tid&3)*128)
  {
    const int gr = tid >> 2;
    const int kc = (tid & 3) << 7;
    const int gg = gr >> 4, cc = gr & 15;
    const float* src = whh + (size_t)(gg * NH + col0 + cc) * NH + kc;
    const int swz = (gr & 15) << 3;
#pragma unroll
    for (int i = 0; i < 16; ++i) {
      const float4 f0 = *(const float4*)(src + 8 * i);
      const float4 f1 = *(const float4*)(src + 8 * i + 4);
      ushort8v u;
      u[0] = f2bf(f0.x); u[1] = f2bf(f0.y); u[2] = f2bf(f0.z); u[3] = f2bf(f0.w);
      u[4] = f2bf(f1.x); u[5] = f2bf(f1.y); u[6] = f2bf(f1.z); u[7] = f2bf(f1.w);
      *(ushort8v*)&WS[((gr << 9) + kc + 8 * i) ^ swz] = u;
    }
  }
  __syncthreads();

  float* hd = h_all + (size_t)dir * NS * NH * NB;
  unsigned short* hb_us = h_bf + ((size_t)dir * NS << 15);      // [pos][b][k]
  unsigned long long* hb_ull = (unsigned long long*)h_bf + ((size_t)dir * NS << 12);

  const int aswz = cl << 3;
  const int arow = (w << 4) + cl;
  float4v c4 = {0.f, 0.f, 0.f, 0.f};

  // prime xp for t=0
  uint2 xg0, xg1, xg2, xg3;
  {
    const int pos0 = dir ? (NS - 1) : 0;
    const unsigned short* xc = xpb + (((size_t)(dir * NS + pos0) * 32 + cb) << 12);
    xg0 = *(const uint2*)&xc[(0 << 10) + (cl << 6) + b4];
    xg1 = *(const uint2*)&xc[(1 << 10) + (cl << 6) + b4];
    xg2 = *(const uint2*)&xc[(2 << 10) + (cl << 6) + b4];
    xg3 = *(const uint2*)&xc[(3 << 10) + (cl << 6) + b4];
  }

  for (int t = 0; t < NS; ++t) {
    const int pos = dir ? (NS - 1 - t) : t;
    float4v acc[4] = {{0.f, 0.f, 0.f, 0.f}, {0.f, 0.f, 0.f, 0.f},
                      {0.f, 0.f, 0.f, 0.f}, {0.f, 0.f, 0.f, 0.f}};
    if (t > 0) {
      const int prevpos = dir ? (pos + 1) : (pos - 1);
      unsigned long long* hsrc = hb_ull + ((size_t)prevpos << 13);  // 8192 ull
#pragma unroll
      for (int i = 0; i < 32; ++i) {
        const int u = (i << 8) + tid;
        const int bb = u >> 7, k4 = (u & 127) << 2;
        const unsigned long long v = __hip_atomic_load(
            &hsrc[u], __ATOMIC_RELAXED, __HIP_MEMORY_SCOPE_AGENT);
        *(unsigned long long*)&hS[((bb << 9) + k4) ^ ((bb & 15) << 3)] = v;
      }
      __syncthreads();
#pragma unroll
      for (int ks = 0; ks < 16; ++ks) {
        const int koff = (ks << 5) + (bq << 3);
        const short8v a = *(const short8v*)&hS[((arow << 9) + koff) ^ aswz];
#pragma unroll
        for (int g = 0; g < 4; ++g) {
          const short8v bb =
              *(const short8v*)&WS[((((g << 4) + cl) << 9) + koff) ^ (cl << 3)];
          acc[g] = __builtin_amdgcn_mfma_f32_16x16x32_bf16(a, bb, acc[g], 0, 0, 0);
        }
      }
    }
    // cell update: this thread owns (col0+cl, b4..b4+3)
    float hv[4];
#pragma unroll
    for (int i = 0; i < 4; ++i) {
      const unsigned xw0 = (i < 2) ? xg0.x : xg0.y;
      const unsigned xw1 = (i < 2) ? xg1.x : xg1.y;
      const unsigned xw2 = (i < 2) ? xg2.x : xg2.y;
      const unsigned xw3 = (i < 2) ? xg3.x : xg3.y;
      const int sh = (i & 1) << 4;
      const float gi = sigm(acc[0][i] + bf2f((unsigned short)(xw0 >> sh)));
      const float gf = sigm(acc[1][i] + bf2f((unsigned short)(xw1 >> sh)));
      const float gc = tanh_fast(acc[2][i] + bf2f((unsigned short)(xw2 >> sh)));
      const float go = sigm(acc[3][i] + bf2f((unsigned short)(xw3 >> sh)));
      c4[i] = gf * c4[i] + gi * gc;
      hv[i] = go * tanh_fast(c4[i]);
    }
    // fp32 h for k_comb (normal store; consumed after kernel end)
    *(float4*)(hd + ((size_t)pos * NH + col0 + cl) * NB + b4) =
        make_float4(hv[0], hv[1], hv[2], hv[3]);
    if (t < NS - 1) {
      // bf16 h into LDS bounce [b][col_local]
#pragma unroll
      for (int i = 0; i < 4; ++i) hOut[((b4 + i) << 4) + cl] = f2bf(hv[i]);
      // prefetch next-step xp while stores/barrier are in flight
      const int npos = dir ? (pos - 1) : (pos + 1);
      const unsigned short* xc =
          xpb + (((size_t)(dir * NS + npos) * 32 + cb) << 12);
      const uint2 nx0 = *(const uint2*)&xc[(0 << 10) + (cl << 6) + b4];
      const uint2 nx1 = *(const uint2*)&xc[(1 << 10) + (cl << 6) + b4];
      const uint2 nx2 = *(const uint2*)&xc[(2 << 10) + (cl << 6) + b4];
      const uint2 nx3 = *(const uint2*)&xc[(3 << 10) + (cl << 6) + b4];
      __syncthreads();  // hOut visible
      if (tid < 128) {
        const int bb = tid >> 1, half = tid & 1;
        const unsigned long long v =
            *(const unsigned long long*)&hOut[(bb << 4) + (half << 3)];
        __hip_atomic_store(
            (unsigned long long*)&hb_us[((size_t)pos << 15) + (bb << 9) + col0 +
                                        (half << 3)],
            v, __ATOMIC_RELAXED, __HIP_MEMORY_SCOPE_AGENT);
      }
      __syncthreads();  // drains the 128 packed SC stores (vmcnt before barrier)
      if (tid == 0) {
        int* ctr = &bar[(((t << 1) + dir) << 5)];
        __hip_atomic_fetch_add(ctr, 1, __ATOMIC_RELAXED, __HIP_MEMORY_SCOPE_AGENT);
        while (__hip_atomic_load(ctr, __ATOMIC_RELAXED, __HIP_MEMORY_SCOPE_AGENT) < 32) {
        }
      }
      __syncthreads();
      xg0 = nx0; xg1 = nx1; xg2 = nx2; xg3 = nx3;
    }
  }
}

// ---------------- K3: combined = lrelu(fwd@W1^T + bwd@W2^T) -> vec --------
__global__ __launch_bounds__(256) void k_comb(
    const float* __restrict__ h_all, const float* __restrict__ W1,
    const float* __restrict__ W2, float* __restrict__ vec) {
  __shared__ float A1[16][68], A2[16][68], B1[16][68], B2[16][68];
  const int tid = threadIdx.x;
  const int n0 = blockIdx.x * 64;
  const int s = blockIdx.y;
  const float* h0 = h_all + (size_t)s * NH * NB;
  const float* h1 = h_all + ((size_t)NS + s) * NH * NB;
  const int aj = tid >> 4, ai4 = (tid & 15) << 2;
  const int lr = tid >> 2, lc4 = (tid & 3) << 2;
  const int tx = tid & 15, ty = tid >> 4;
  const float* b1row = W1 + (size_t)(n0 + lr) * NH;
  const float* b2row = W2 + (size_t)(n0 + lr) * NH;
  float acc[4][4] = {};
  for (int k0 = 0; k0 < NH; k0 += 16) {
    *(float4*)&A1[aj][ai4] = *(const float4*)(h0 + (size_t)(k0 + aj) * NB + ai4);
    *(float4*)&A2[aj][ai4] = *(const float4*)(h1 + (size_t)(k0 + aj) * NB + ai4);
    const float4 w1 = *(const float4*)(b1row + k0 + lc4);
    B1[lc4 + 0][lr] = w1.x; B1[lc4 + 1][lr] = w1.y;
    B1[lc4 + 2][lr] = w1.z; B1[lc4 + 3][lr] = w1.w;
    const float4 w2 = *(const float4*)(b2row + k0 + lc4);
    B2[lc4 + 0][lr] = w2.x; B2[lc4 + 1][lr] = w2.y;
    B2[lc4 + 2][lr] = w2.z; B2[lc4 + 3][lr] = w2.w;
    __syncthreads();
#pragma unroll
    for (int kk = 0; kk < 16; ++kk) {
      const float4 a1 = *(const float4*)&A1[kk][ty << 2];
      const float4 b1 = *(const float4*)&B1[kk][tx << 2];
      FMA4x4(acc, a1, b1)
      const float4 a2 = *(const float4*)&A2[kk][ty << 2];
      const float4 b2 = *(const float4*)&B2[kk][tx << 2];
      FMA4x4(acc, a2, b2)
    }
    __syncthreads();
  }
#pragma unroll
  for (int i = 0; i < 4; ++i) {
    const int b = (ty << 2) + i;
#pragma unroll
    for (int j = 0; j < 4; ++j) {
      const int nn = n0 + (tx << 2) + j;
      float v = acc[i][j];
      v = v > 0.f ? v : 0.01f * v;
      vec[((size_t)b * NTOT + s) * NH + nn] = v;
    }
  }
}

// ---------------- K4: l2-normalize word rows of vec -----------------------
__global__ __launch_bounds__(256) void k_norm(float* __restrict__ vec) {
  const int row = (blockIdx.x << 2) + (threadIdx.x >> 6);  // 0..8191
  const int lane = threadIdx.x & 63;
  const int b = row >> 7, s = row & 127;
  float* p = vec + ((size_t)b * NTOT + s) * NH;
  float4 v0 = *(float4*)(p + (lane << 3));
  float4 v1 = *(float4*)(p + (lane << 3) + 4);
  float ss = v0.x * v0.x + v0.y * v0.y + v0.z * v0.z + v0.w * v0.w +
             v1.x * v1.x + v1.y * v1.y + v1.z * v1.z + v1.w * v1.w;
#pragma unroll
  for (int off = 32; off; off >>= 1) ss += __shfl_down(ss, off);
  ss = __shfl(ss, 0);
  const float sc = 1.f / fmaxf(sqrtf(ss), 1e-12f);
  v0.x *= sc; v0.y *= sc; v0.z *= sc; v0.w *= sc;
  v1.x *= sc; v1.y *= sc; v1.z *= sc; v1.w *= sc;
  *(float4*)(p + (lane << 3)) = v0;
  *(float4*)(p + (lane << 3) + 4) = v1;
}

// ---------------- K5: per-batch tree composition scan ---------------------
__global__ __launch_bounds__(512) void k_compose(
    float* __restrict__ vec, const int* __restrict__ cinfo) {
  __shared__ float lv[512];
  __shared__ float rvd[1028];
  __shared__ float cpart[4][512];
  __shared__ float red[9];
  const int b = blockIdx.x;
  const int tid = threadIdx.x;
  float* vb = vec + (size_t)b * NTOT * NH;
  const int* ib = cinfo + b * NSTEPS * 4;
  const int jq = tid >> 7;
  const int k4 = (tid & 127) << 2;
  const int wid = tid >> 6, lane = tid & 63;
  for (int i = 0; i < NSTEPS; ++i) {
    const int tt = ib[i * 4 + 0], p = ib[i * 4 + 1];
    const int l = ib[i * 4 + 2], r = ib[i * 4 + 3];
    lv[tid] = vb[(size_t)l * NH + tid];
    const float rvv = vb[(size_t)r * NH + tid];
    rvd[tid] = rvv;
    rvd[512 + tid] = rvv;
    __syncthreads();
    float a0 = 0.f, a1 = 0.f, a2 = 0.f, a3 = 0.f;
    if (tt == 2) {
      const int jb = jq << 7;
#pragma unroll 8
      for (int jj = 0; jj < 128; jj += 4) {
        const int j = jb + jj;
        const float4 l4 = *(const float4*)&lv[j];
        const float4 r0 = *(const float4*)&rvd[j + k4];
        const float4 r1 = *(const float4*)&rvd[j + k4 + 4];
        a0 += l4.x * r0.x + l4.y * r0.y + l4.z * r0.z + l4.w * r0.w;
        a1 += l4.x * r0.y + l4.y * r0.z + l4.z * r0.w + l4.w * r1.x;
        a2 += l4.x * r0.z + l4.y * r0.w + l4.z * r1.x + l4.w * r1.y;
        a3 += l4.x * r0.w + l4.y * r1.x + l4.z * r1.y + l4.w * r1.z;
      }
    }
    cpart[jq][k4 + 0] = a0; cpart[jq][k4 + 1] = a1;
    cpart[jq][k4 + 2] = a2; cpart[jq][k4 + 3] = a3;
    __syncthreads();
    const float ck = cpart[0][tid] + cpart[1][tid] + cpart[2][tid] + cpart[3][tid];
    float ss = ck * ck;
#pragma unroll
    for (int off = 32; off; off >>= 1) ss += __shfl_down(ss, off);
    if (lane == 0) red[wid] = ss;
    __syncthreads();
    if (tid == 0) {
      float tot = 0.f;
#pragma unroll
      for (int w = 0; w < 8; ++w) tot += red[w];
      red[8] = 1.f / fmaxf(sqrtf(tot), 1e-12f);
    }
    __syncthreads();
    if (tt == 2) {
      vb[(size_t)p * NH + tid] = ck * red[8];
    } else if (tt == 1) {
      vb[(size_t)p * NH + tid] = lv[tid];
    }
    __syncthreads();
  }
}

// ---------------- K6: output GEMMs (word / phrase) ------------------------
template <int MODE>
__global__ __launch_bounds__(256) void k_out(
    const float* __restrict__ vec, const float* __restrict__ W,
    const float* __restrict__ bias, float* __restrict__ out) {
  constexpr int NOUT = MODE ? NPV : NWV;
  __shared__ float As[16][68], Bs[16][68];
  const int tid = threadIdx.x;
  const int n0 = blockIdx.x * 64, m0 = blockIdx.y * 64;
  const int lr = tid >> 2, lc4 = (tid & 3) << 2;
  const int tx = tid & 15, ty = tid >> 4;
  const int m = m0 + lr;
  int vr;
  if (MODE == 0) {
    vr = (m >> 7) * NTOT + (m & 127);
  } else {
    const int bb = m / 127;
    vr = bb * NTOT + NS + (m - bb * 127);
  }
  const float* arow = vec + (size_t)vr * NH;
  const int n = n0 + lr;
  const float* brow = W + (size_t)n * NH;
  const bool bok = (n < NOUT);
  float acc[4][4] = {};
  for (int k0 = 0; k0 < NH; k0 += 16) {
    const float4 a4 = *(const float4*)(arow + k0 + lc4);
    As[lc4 + 0][lr] = a4.x; As[lc4 + 1][lr] = a4.y;
    As[lc4 + 2][lr] = a4.z; As[lc4 + 3][lr] = a4.w;
    float4 b4 = make_float4(0.f, 0.f, 0.f, 0.f);
    if (bok) b4 = *(const float4*)(brow + k0 + lc4);
    Bs[lc4 + 0][lr] = b4.x; Bs[lc4 + 1][lr] = b4.y;
    Bs[lc4 + 2][lr] = b4.z; Bs[lc4 + 3][lr] = b4.w;
    __syncthreads();
#pragma unroll
    for (int kk = 0; kk < 16; ++kk) {
      const float4 av = *(const float4*)&As[kk][ty << 2];
      const float4 bv = *(const float4*)&Bs[kk][tx << 2];
      FMA4x4(acc, av, bv)
    }
    __syncthreads();
  }
#pragma unroll
  for (int i = 0; i < 4; ++i)
#pragma unroll
    for (int j = 0; j < 4; ++j) {
      const int nn = n0 + (tx << 2) + j;
      if (nn < NOUT)
        out[(size_t)(m0 + (ty << 2) + i) * NOUT + nn] = acc[i][j] + bias[nn];
    }
}

// ---------------- K7: labels (int32 -> f32 copy) --------------------------
__global__ __launch_bounds__(256) void k_labels(
    const int* __restrict__ lab, float* __restrict__ outw,
    float* __restrict__ outp) {
  const int i = blockIdx.x * 256 + threadIdx.x;
  if (i < NB * NS) {
    const int b = i >> 7, s = i & 127;
    outw[i] = (float)lab[b * NTOT + s];
  }
  if (i < NB * NSTEPS) {
    const int b = i / 127;
    outp[i] = (float)lab[b * NTOT + NS + (i - b * 127)];
  }
}

extern "C" void kernel_launch(void* const* d_in, const int* in_sizes, int n_in,
                              void* d_out, int out_size, void* d_ws, size_t ws_size,
                              hipStream_t stream) {
  (void)in_sizes; (void)n_in; (void)out_size; (void)ws_size;
  const float* elmo     = (const float*)d_in[0];
  const float* w_ih_f   = (const float*)d_in[1];
  const float* w_hh_f   = (const float*)d_in[2];
  const float* b_f      = (const float*)d_in[3];
  const float* w_ih_b   = (const float*)d_in[4];
  const float* w_hh_b   = (const float*)d_in[5];
  const float* b_b      = (const float*)d_in[6];
  const float* W1       = (const float*)d_in[7];
  const float* W2       = (const float*)d_in[8];
  const float* word_W   = (const float*)d_in[9];
  const float* word_b   = (const float*)d_in[10];
  const float* phrase_W = (const float*)d_in[11];
  const float* phrase_b = (const float*)d_in[12];
  const int* cinfo      = (const int*)d_in[13];
  const int* lab        = (const int*)d_in[15];

  unsigned short* xpb  = (unsigned short*)d_ws;
  float* h_all         = (float*)(xpb + XPB_SZ);
  float* vec           = h_all + H_SZ;
  unsigned short* h_bf = (unsigned short*)(vec + VEC_SZ);
  unsigned short* e_bf = h_bf + HB_SZ;
  unsigned short* W_bf = e_bf + EB_SZ;
  int* bar             = (int*)(W_bf + WB_SZ);

  float* out_word = (float*)d_out;                       // 8192 x 511
  float* out_phr  = out_word + (size_t)8192 * NWV;       // 8128 x 152
  float* out_lw   = out_phr + (size_t)8128 * NPV;        // 8192
  float* out_lp   = out_lw + 8192;                       // 8128

  k_cvt<<<dim3(2048), 256, 0, stream>>>(elmo, w_ih_f, w_ih_b, e_bf, W_bf, bar);
  k_xp<<<dim3(32, 64), 256, 0, stream>>>(e_bf, W_bf, b_f, b_b, xpb);
  k_lstm<<<dim3(64), 256, 0, stream>>>(w_hh_f, w_hh_b, xpb, h_all, h_bf, bar);
  k_comb<<<dim3(8, 128), 256, 0, stream>>>(h_all, W1, W2, vec);
  k_norm<<<dim3(2048), 256, 0, stream>>>(vec);
  k_compose<<<dim3(64), 512, 0, stream>>>(vec, cinfo);
  k_out<0><<<dim3(8, 128), 256, 0, stream>>>(vec, word_W, word_b, out_word);
  k_out<1><<<dim3(3, 127), 256, 0, stream>>>(vec, phrase_W, phrase_b, out_phr);
  k_labels<<<dim3(32), 256, 0, stream>>>(lab, out_lw, out_lp);
}

// Round 10
// 1979.134 us; speedup vs baseline: 2.5046x; 1.3248x over previous
//
#include <hip/hip_runtime.h>
#include <math.h>

// Problem constants
#define NB 64      // batch
#define NS 128     // seq len
#define ND 1024    // input dim
#define NH 512     // hidden
#define NG 2048    // 4*H
#define NTOT 255   // 2S-1
#define NSTEPS 127 // S-1
#define NWV 511
#define NPV 152

// ws layout:
//  xpb    : ushort [2][128][32][4][16][64] = 33,554,432 us  (per-block chunks)
//  h_all  : float  [2][128][512][64]  =  8,388,608 f
//  vec    : float  [64][255][512]     =  8,355,840 f
//  h_bf   : ushort [2][128][64][512]  =  8,388,608 us   ([pos][b][k])
//  elmo_bf: ushort [128*64][1024]     =  8,388,608 us   ([t*64+b][k])
//  W_bf   : ushort [4096][1024]       =  4,194,304 us
//  bar    : int [8192]
static const size_t XPB_SZ = (size_t)2 * NS * NG * NB;
static const size_t H_SZ   = (size_t)2 * NS * NH * NB;
static const size_t VEC_SZ = (size_t)NB * NTOT * NH;
static const size_t HB_SZ  = (size_t)2 * NS * NH * NB;
static const size_t EB_SZ  = (size_t)NB * NS * ND;
static const size_t WB_SZ  = (size_t)4096 * ND;

typedef __attribute__((ext_vector_type(8))) short short8v;
typedef __attribute__((ext_vector_type(8))) unsigned short ushort8v;
typedef __attribute__((ext_vector_type(4))) float float4v;

__device__ __forceinline__ float sigm(float x) { return 1.f / (1.f + __expf(-x)); }
__device__ __forceinline__ float tanh_fast(float x) {
  const float e = __expf(2.f * x);
  return 1.f - 2.f / (e + 1.f);
}
__device__ __forceinline__ unsigned short f2bf(float x) {
  unsigned b = __float_as_uint(x);
  return (unsigned short)((b + 0x7FFFu + ((b >> 16) & 1u)) >> 16);
}
__device__ __forceinline__ float bf2f(unsigned short u) {
  return __uint_as_float(((unsigned)u) << 16);
}

#define FMA4x4(acc, av, bv)                                                    \
  acc[0][0] += av.x * bv.x; acc[0][1] += av.x * bv.y;                          \
  acc[0][2] += av.x * bv.z; acc[0][3] += av.x * bv.w;                          \
  acc[1][0] += av.y * bv.x; acc[1][1] += av.y * bv.y;                          \
  acc[1][2] += av.y * bv.z; acc[1][3] += av.y * bv.w;                          \
  acc[2][0] += av.z * bv.x; acc[2][1] += av.z * bv.y;                          \
  acc[2][2] += av.z * bv.z; acc[2][3] += av.z * bv.w;                          \
  acc[3][0] += av.w * bv.x; acc[3][1] += av.w * bv.y;                          \
  acc[3][2] += av.w * bv.z; acc[3][3] += av.w * bv.w;

// ---------------- K0: fp32 -> bf16 conversions + barrier zero -------------
__global__ __launch_bounds__(256) void k_cvt(
    const float* __restrict__ elmo, const float* __restrict__ wf,
    const float* __restrict__ wb, unsigned short* __restrict__ elmo_bf,
    unsigned short* __restrict__ W_bf, int* __restrict__ bar) {
  const int gid = blockIdx.x * 256 + threadIdx.x;
  if (gid < 8192) bar[gid] = 0;
  const int NE4 = (NB * NS * ND) / 4;   // 2,097,152
  const int NW4 = (4096 * ND) / 4;      // 1,048,576
  const int NW4h = NW4 / 2;
  for (int i = gid; i < NE4 + NW4; i += gridDim.x * 256) {
    float4 v;
    unsigned short* dst;
    if (i < NE4) {
      const int e0 = i << 2;
      const int b = e0 >> 17;
      const int t = (e0 >> 10) & 127;
      const int k = e0 & 1023;
      v = *(const float4*)(elmo + e0);
      dst = elmo_bf + ((size_t)((t << 6) + b) << 10) + k;
    } else {
      const int j = i - NE4;
      v = (j < NW4h) ? *(const float4*)(wf + ((size_t)j << 2))
                     : *(const float4*)(wb + ((size_t)(j - NW4h) << 2));
      dst = W_bf + ((size_t)j << 2);
    }
    uint2 u;
    u.x = (unsigned)f2bf(v.x) | ((unsigned)f2bf(v.y) << 16);
    u.y = (unsigned)f2bf(v.z) | ((unsigned)f2bf(v.w) << 16);
    *(uint2*)dst = u;
  }
}

// ---------------- K1: xp = elmo @ w_ih^T + bias (bf16 MFMA) ---------------
// Output layout (for k_lstm block-contiguous reads):
//   xpb[(((dir*128 + t)*32 + cb)*4 + g)*1024 + cl*64 + b]   (ushort bf16)
__global__ __launch_bounds__(256) void k_xp(
    const unsigned short* __restrict__ elmo_bf,
    const unsigned short* __restrict__ W_bf,
    const float* __restrict__ biasf, const float* __restrict__ biasb,
    unsigned short* __restrict__ xpb) {
  __shared__ unsigned short As[128 * 64];  // 16 KB, swizzled
  __shared__ unsigned short Bs[128 * 64];  // 16 KB
  const int tid = threadIdx.x;
  const int n0 = blockIdx.x * 128;
  const int m0 = blockIdx.y * 128;
  const int wv = tid >> 6, lane = tid & 63;
  const int cl = lane & 15, bq = lane >> 4;
  const int wm = (wv >> 1) << 6;   // 0 / 64
  const int wn = (wv & 1) << 6;    // 0 / 64
  // staging: thread -> (row sr of 128, k-half skc of 32)
  const int sr = tid >> 1, skc = (tid & 1) << 5;
  const unsigned short* asrc = elmo_bf + (size_t)(m0 + sr) * ND + skc;
  const unsigned short* bsrc = W_bf + (size_t)(n0 + sr) * ND + skc;
  const int sswz = (sr & 15) << 3;
  float4v acc[4][4];
#pragma unroll
  for (int nt = 0; nt < 4; ++nt) {
    const int n = n0 + wn + nt * 16 + cl;
    const float bv = (n < 2048) ? biasf[n] : biasb[n - 2048];
#pragma unroll
    for (int mt = 0; mt < 4; ++mt) acc[mt][nt] = (float4v){bv, bv, bv, bv};
  }
  for (int k0 = 0; k0 < ND; k0 += 64) {
    ushort8v av4[4], bv4[4];
#pragma unroll
    for (int i = 0; i < 4; ++i) av4[i] = *(const ushort8v*)(asrc + k0 + 8 * i);
#pragma unroll
    for (int i = 0; i < 4; ++i) bv4[i] = *(const ushort8v*)(bsrc + k0 + 8 * i);
    __syncthreads();
#pragma unroll
    for (int i = 0; i < 4; ++i) {
      *(ushort8v*)&As[((sr << 6) + skc + 8 * i) ^ sswz] = av4[i];
      *(ushort8v*)&Bs[((sr << 6) + skc + 8 * i) ^ sswz] = bv4[i];
    }
    __syncthreads();
#pragma unroll
    for (int ks = 0; ks < 2; ++ks) {
      const int koff = (ks << 5) + (bq << 3);
      short8v af[4], bf_[4];
#pragma unroll
      for (int mt = 0; mt < 4; ++mt) {
        const int ar = wm + mt * 16 + cl;
        af[mt] = *(const short8v*)&As[((ar << 6) + koff) ^ ((ar & 15) << 3)];
      }
#pragma unroll
      for (int nt = 0; nt < 4; ++nt) {
        const int br = wn + nt * 16 + cl;
        bf_[nt] = *(const short8v*)&Bs[((br << 6) + koff) ^ ((br & 15) << 3)];
      }
#pragma unroll
      for (int mt = 0; mt < 4; ++mt)
#pragma unroll
        for (int nt = 0; nt < 4; ++nt)
          acc[mt][nt] =
              __builtin_amdgcn_mfma_f32_16x16x32_bf16(af[mt], bf_[nt], acc[mt][nt], 0, 0, 0);
    }
  }
  // epilogue: 8B stores into block-chunked layout
#pragma unroll
  for (int mt = 0; mt < 4; ++mt) {
    const int mbase = m0 + wm + mt * 16 + (bq << 2);
    const int t = mbase >> 6, b4 = mbase & 63;
#pragma unroll
    for (int nt = 0; nt < 4; ++nt) {
      const int n = n0 + wn + nt * 16 + cl;
      const int dir = n >> 11, grow = n & 2047;
      const int g = grow >> 9, cb = (grow & 511) >> 4;
      const float4v a = acc[mt][nt];
      uint2 u;
      u.x = (unsigned)f2bf(a[0]) | ((unsigned)f2bf(a[1]) << 16);
      u.y = (unsigned)f2bf(a[2]) | ((unsigned)f2bf(a[3]) << 16);
      const size_t idx =
          ((((size_t)(dir * NS + t) * 32 + cb) * 4 + g) << 10) + (cl << 6) + b4;
      *(uint2*)&xpb[idx] = u;
    }
  }
}

// ---------------- K2: persistent BiLSTM scan, v8 --------------------------
// v7 minus the LDS h-staging: each lane loads its MFMA A-fragments DIRECTLY
// from h_bf into registers (32 independent 8B SC loads, fully unrolled,
// static indexing). Removes the per-iteration load->ds_write vmcnt(0)
// serialization (~32 dependent L3 round trips/step), the staging barrier,
// and 64KB of LDS.
__global__ __launch_bounds__(256) void k_lstm(
    const float* __restrict__ whh_f, const float* __restrict__ whh_b,
    const unsigned short* __restrict__ xpb, float* __restrict__ h_all,
    unsigned short* __restrict__ h_bf, int* __restrict__ bar) {
  __shared__ unsigned short WS[64 * 512];   // 64 KB, swizzled [gr][k]
  __shared__ unsigned short hOut[64 * 16];  // 2 KB bounce [b][col_local]
  const int bid = blockIdx.x;
  const int dir = bid >> 5;
  const int cb = bid & 31;
  const int col0 = cb << 4;
  const int tid = threadIdx.x;
  const int lane = tid & 63;
  const int w = tid >> 6;          // wave = M-tile
  const int cl = lane & 15, bq = lane >> 4;
  const int b4 = (w << 4) + (bq << 2);   // 4 owned b rows
  const int arow = (w << 4) + cl;        // A-fragment row (b)
  const float* whh = dir ? whh_b : whh_f;

  // one-time: W slice fp32 -> bf16 LDS. thread -> (gr = tid>>2, kc = (tid&3)*128)
  {
    const int gr = tid >> 2;
    const int kc = (tid & 3) << 7;
    const int gg = gr >> 4, cc = gr & 15;
    const float* src = whh + (size_t)(gg * NH + col0 + cc) * NH + kc;
    const int swz = (gr & 15) << 3;
#pragma unroll
    for (int i = 0; i < 16; ++i) {
      const float4 f0 = *(const float4*)(src + 8 * i);
      const float4 f1 = *(const float4*)(src + 8 * i + 4);
      ushort8v u;
      u[0] = f2bf(f0.x); u[1] = f2bf(f0.y); u[2] = f2bf(f0.z); u[3] = f2bf(f0.w);
      u[4] = f2bf(f1.x); u[5] = f2bf(f1.y); u[6] = f2bf(f1.z); u[7] = f2bf(f1.w);
      *(ushort8v*)&WS[((gr << 9) + kc + 8 * i) ^ swz] = u;
    }
  }
  __syncthreads();

  float* hd = h_all + (size_t)dir * NS * NH * NB;
  unsigned short* hb_us = h_bf + ((size_t)dir * NS << 15);      // [pos][b][k]
  unsigned long long* hb_ull = (unsigned long long*)h_bf + ((size_t)dir * NS << 12);

  float4v c4 = {0.f, 0.f, 0.f, 0.f};

  // prime xp for t=0
  uint2 xg0, xg1, xg2, xg3;
  {
    const int pos0 = dir ? (NS - 1) : 0;
    const unsigned short* xc = xpb + (((size_t)(dir * NS + pos0) * 32 + cb) << 12);
    xg0 = *(const uint2*)&xc[(0 << 10) + (cl << 6) + b4];
    xg1 = *(const uint2*)&xc[(1 << 10) + (cl << 6) + b4];
    xg2 = *(const uint2*)&xc[(2 << 10) + (cl << 6) + b4];
    xg3 = *(const uint2*)&xc[(3 << 10) + (cl << 6) + b4];
  }

  for (int t = 0; t < NS; ++t) {
    const int pos = dir ? (NS - 1 - t) : t;
    float4v acc[4] = {{0.f, 0.f, 0.f, 0.f}, {0.f, 0.f, 0.f, 0.f},
                      {0.f, 0.f, 0.f, 0.f}, {0.f, 0.f, 0.f, 0.f}};
    if (t > 0) {
      const int prevpos = dir ? (pos + 1) : (pos - 1);
      const unsigned long long* hsrc = hb_ull + ((size_t)prevpos << 13);
      // 32 independent 8B SC loads -> registers (A-fragments for 16 K-steps)
      unsigned long long ha0[16], ha1[16];
#pragma unroll
      for (int ks = 0; ks < 16; ++ks) {
        const int uidx = (arow << 7) + (ks << 3) + (bq << 1);
        ha0[ks] = __hip_atomic_load(&hsrc[uidx], __ATOMIC_RELAXED,
                                    __HIP_MEMORY_SCOPE_AGENT);
        ha1[ks] = __hip_atomic_load(&hsrc[uidx + 1], __ATOMIC_RELAXED,
                                    __HIP_MEMORY_SCOPE_AGENT);
      }
#pragma unroll
      for (int ks = 0; ks < 16; ++ks) {
        union { unsigned long long u[2]; short8v v; } au;
        au.u[0] = ha0[ks]; au.u[1] = ha1[ks];
        const short8v a = au.v;
        const int koff = (ks << 5) + (bq << 3);
#pragma unroll
        for (int g = 0; g < 4; ++g) {
          const short8v bb =
              *(const short8v*)&WS[((((g << 4) + cl) << 9) + koff) ^ (cl << 3)];
          acc[g] = __builtin_amdgcn_mfma_f32_16x16x32_bf16(a, bb, acc[g], 0, 0, 0);
        }
      }
    }
    // cell update: this thread owns (col0+cl, b4..b4+3)
    float hv[4];
#pragma unroll
    for (int i = 0; i < 4; ++i) {
      const unsigned xw0 = (i < 2) ? xg0.x : xg0.y;
      const unsigned xw1 = (i < 2) ? xg1.x : xg1.y;
      const unsigned xw2 = (i < 2) ? xg2.x : xg2.y;
      const unsigned xw3 = (i < 2) ? xg3.x : xg3.y;
      const int sh = (i & 1) << 4;
      const float gi = sigm(acc[0][i] + bf2f((unsigned short)(xw0 >> sh)));
      const float gf = sigm(acc[1][i] + bf2f((unsigned short)(xw1 >> sh)));
      const float gc = tanh_fast(acc[2][i] + bf2f((unsigned short)(xw2 >> sh)));
      const float go = sigm(acc[3][i] + bf2f((unsigned short)(xw3 >> sh)));
      c4[i] = gf * c4[i] + gi * gc;
      hv[i] = go * tanh_fast(c4[i]);
    }
    // fp32 h for k_comb (normal store; consumed after kernel end)
    *(float4*)(hd + ((size_t)pos * NH + col0 + cl) * NB + b4) =
        make_float4(hv[0], hv[1], hv[2], hv[3]);
    if (t < NS - 1) {
      // bf16 h into LDS bounce [b][col_local]
#pragma unroll
      for (int i = 0; i < 4; ++i) hOut[((b4 + i) << 4) + cl] = f2bf(hv[i]);
      // prefetch next-step xp while stores/barrier are in flight
      const int npos = dir ? (pos - 1) : (pos + 1);
      const unsigned short* xc =
          xpb + (((size_t)(dir * NS + npos) * 32 + cb) << 12);
      const uint2 nx0 = *(const uint2*)&xc[(0 << 10) + (cl << 6) + b4];
      const uint2 nx1 = *(const uint2*)&xc[(1 << 10) + (cl << 6) + b4];
      const uint2 nx2 = *(const uint2*)&xc[(2 << 10) + (cl << 6) + b4];
      const uint2 nx3 = *(const uint2*)&xc[(3 << 10) + (cl << 6) + b4];
      __syncthreads();  // hOut visible
      if (tid < 128) {
        const int bb = tid >> 1, half = tid & 1;
        const unsigned long long v =
            *(const unsigned long long*)&hOut[(bb << 4) + (half << 3)];
        __hip_atomic_store(
            (unsigned long long*)&hb_us[((size_t)pos << 15) + (bb << 9) + col0 +
                                        (half << 3)],
            v, __ATOMIC_RELAXED, __HIP_MEMORY_SCOPE_AGENT);
      }
      __syncthreads();  // drains the 128 packed SC stores before the signal
      if (tid == 0) {
        int* ctr = &bar[(((t << 1) + dir) << 5)];
        __hip_atomic_fetch_add(ctr, 1, __ATOMIC_RELAXED, __HIP_MEMORY_SCOPE_AGENT);
        while (__hip_atomic_load(ctr, __ATOMIC_RELAXED, __HIP_MEMORY_SCOPE_AGENT) < 32) {
        }
      }
      __syncthreads();
      xg0 = nx0; xg1 = nx1; xg2 = nx2; xg3 = nx3;
    }
  }
}

// ---------------- K3: combined = lrelu(fwd@W1^T + bwd@W2^T) -> vec --------
__global__ __launch_bounds__(256) void k_comb(
    const float* __restrict__ h_all, const float* __restrict__ W1,
    const float* __restrict__ W2, float* __restrict__ vec) {
  __shared__ float A1[16][68], A2[16][68], B1[16][68], B2[16][68];
  const int tid = threadIdx.x;
  const int n0 = blockIdx.x * 64;
  const int s = blockIdx.y;
  const float* h0 = h_all + (size_t)s * NH * NB;
  const float* h1 = h_all + ((size_t)NS + s) * NH * NB;
  const int aj = tid >> 4, ai4 = (tid & 15) << 2;
  const int lr = tid >> 2, lc4 = (tid & 3) << 2;
  const int tx = tid & 15, ty = tid >> 4;
  const float* b1row = W1 + (size_t)(n0 + lr) * NH;
  const float* b2row = W2 + (size_t)(n0 + lr) * NH;
  float acc[4][4] = {};
  for (int k0 = 0; k0 < NH; k0 += 16) {
    *(float4*)&A1[aj][ai4] = *(const float4*)(h0 + (size_t)(k0 + aj) * NB + ai4);
    *(float4*)&A2[aj][ai4] = *(const float4*)(h1 + (size_t)(k0 + aj) * NB + ai4);
    const float4 w1 = *(const float4*)(b1row + k0 + lc4);
    B1[lc4 + 0][lr] = w1.x; B1[lc4 + 1][lr] = w1.y;
    B1[lc4 + 2][lr] = w1.z; B1[lc4 + 3][lr] = w1.w;
    const float4 w2 = *(const float4*)(b2row + k0 + lc4);
    B2[lc4 + 0][lr] = w2.x; B2[lc4 + 1][lr] = w2.y;
    B2[lc4 + 2][lr] = w2.z; B2[lc4 + 3][lr] = w2.w;
    __syncthreads();
#pragma unroll
    for (int kk = 0; kk < 16; ++kk) {
      const float4 a1 = *(const float4*)&A1[kk][ty << 2];
      const float4 b1 = *(const float4*)&B1[kk][tx << 2];
      FMA4x4(acc, a1, b1)
      const float4 a2 = *(const float4*)&A2[kk][ty << 2];
      const float4 b2 = *(const float4*)&B2[kk][tx << 2];
      FMA4x4(acc, a2, b2)
    }
    __syncthreads();
  }
#pragma unroll
  for (int i = 0; i < 4; ++i) {
    const int b = (ty << 2) + i;
#pragma unroll
    for (int j = 0; j < 4; ++j) {
      const int nn = n0 + (tx << 2) + j;
      float v = acc[i][j];
      v = v > 0.f ? v : 0.01f * v;
      vec[((size_t)b * NTOT + s) * NH + nn] = v;
    }
  }
}

// ---------------- K4: l2-normalize word rows of vec -----------------------
__global__ __launch_bounds__(256) void k_norm(float* __restrict__ vec) {
  const int row = (blockIdx.x << 2) + (threadIdx.x >> 6);  // 0..8191
  const int lane = threadIdx.x & 63;
  const int b = row >> 7, s = row & 127;
  float* p = vec + ((size_t)b * NTOT + s) * NH;
  float4 v0 = *(float4*)(p + (lane << 3));
  float4 v1 = *(float4*)(p + (lane << 3) + 4);
  float ss = v0.x * v0.x + v0.y * v0.y + v0.z * v0.z + v0.w * v0.w +
             v1.x * v1.x + v1.y * v1.y + v1.z * v1.z + v1.w * v1.w;
#pragma unroll
  for (int off = 32; off; off >>= 1) ss += __shfl_down(ss, off);
  ss = __shfl(ss, 0);
  const float sc = 1.f / fmaxf(sqrtf(ss), 1e-12f);
  v0.x *= sc; v0.y *= sc; v0.z *= sc; v0.w *= sc;
  v1.x *= sc; v1.y *= sc; v1.z *= sc; v1.w *= sc;
  *(float4*)(p + (lane << 3)) = v0;
  *(float4*)(p + (lane << 3) + 4) = v1;
}

// ---------------- K5: per-batch tree composition scan ---------------------
__global__ __launch_bounds__(512) void k_compose(
    float* __restrict__ vec, const int* __restrict__ cinfo) {
  __shared__ float lv[512];
  __shared__ float rvd[1028];
  __shared__ float cpart[4][512];
  __shared__ float red[9];
  const int b = blockIdx.x;
  const int tid = threadIdx.x;
  float* vb = vec + (size_t)b * NTOT * NH;
  const int* ib = cinfo + b * NSTEPS * 4;
  const int jq = tid >> 7;
  const int k4 = (tid & 127) << 2;
  const int wid = tid >> 6, lane = tid & 63;
  for (int i = 0; i < NSTEPS; ++i) {
    const int tt = ib[i * 4 + 0], p = ib[i * 4 + 1];
    const int l = ib[i * 4 + 2], r = ib[i * 4 + 3];
    lv[tid] = vb[(size_t)l * NH + tid];
    const float rvv = vb[(size_t)r * NH + tid];
    rvd[tid] = rvv;
    rvd[512 + tid] = rvv;
    __syncthreads();
    float a0 = 0.f, a1 = 0.f, a2 = 0.f, a3 = 0.f;
    if (tt == 2) {
      const int jb = jq << 7;
#pragma unroll 8
      for (int jj = 0; jj < 128; jj += 4) {
        const int j = jb + jj;
        const float4 l4 = *(const float4*)&lv[j];
        const float4 r0 = *(const float4*)&rvd[j + k4];
        const float4 r1 = *(const float4*)&rvd[j + k4 + 4];
        a0 += l4.x * r0.x + l4.y * r0.y + l4.z * r0.z + l4.w * r0.w;
        a1 += l4.x * r0.y + l4.y * r0.z + l4.z * r0.w + l4.w * r1.x;
        a2 += l4.x * r0.z + l4.y * r0.w + l4.z * r1.x + l4.w * r1.y;
        a3 += l4.x * r0.w + l4.y * r1.x + l4.z * r1.y + l4.w * r1.z;
      }
    }
    cpart[jq][k4 + 0] = a0; cpart[jq][k4 + 1] = a1;
    cpart[jq][k4 + 2] = a2; cpart[jq][k4 + 3] = a3;
    __syncthreads();
    const float ck = cpart[0][tid] + cpart[1][tid] + cpart[2][tid] + cpart[3][tid];
    float ss = ck * ck;
#pragma unroll
    for (int off = 32; off; off >>= 1) ss += __shfl_down(ss, off);
    if (lane == 0) red[wid] = ss;
    __syncthreads();
    if (tid == 0) {
      float tot = 0.f;
#pragma unroll
      for (int w = 0; w < 8; ++w) tot += red[w];
      red[8] = 1.f / fmaxf(sqrtf(tot), 1e-12f);
    }
    __syncthreads();
    if (tt == 2) {
      vb[(size_t)p * NH + tid] = ck * red[8];
    } else if (tt == 1) {
      vb[(size_t)p * NH + tid] = lv[tid];
    }
    __syncthreads();
  }
}

// ---------------- K6: output GEMMs (word / phrase) ------------------------
template <int MODE>
__global__ __launch_bounds__(256) void k_out(
    const float* __restrict__ vec, const float* __restrict__ W,
    const float* __restrict__ bias, float* __restrict__ out) {
  constexpr int NOUT = MODE ? NPV : NWV;
  __shared__ float As[16][68], Bs[16][68];
  const int tid = threadIdx.x;
  const int n0 = blockIdx.x * 64, m0 = blockIdx.y * 64;
  const int lr = tid >> 2, lc4 = (tid & 3) << 2;
  const int tx = tid & 15, ty = tid >> 4;
  const int m = m0 + lr;
  int vr;
  if (MODE == 0) {
    vr = (m >> 7) * NTOT + (m & 127);
  } else {
    const int bb = m / 127;
    vr = bb * NTOT + NS + (m - bb * 127);
  }
  const float* arow = vec + (size_t)vr * NH;
  const int n = n0 + lr;
  const float* brow = W + (size_t)n * NH;
  const bool bok = (n < NOUT);
  float acc[4][4] = {};
  for (int k0 = 0; k0 < NH; k0 += 16) {
    const float4 a4 = *(const float4*)(arow + k0 + lc4);
    As[lc4 + 0][lr] = a4.x; As[lc4 + 1][lr] = a4.y;
    As[lc4 + 2][lr] = a4.z; As[lc4 + 3][lr] = a4.w;
    float4 b4 = make_float4(0.f, 0.f, 0.f, 0.f);
    if (bok) b4 = *(const float4*)(brow + k0 + lc4);
    Bs[lc4 + 0][lr] = b4.x; Bs[lc4 + 1][lr] = b4.y;
    Bs[lc4 + 2][lr] = b4.z; Bs[lc4 + 3][lr] = b4.w;
    __syncthreads();
#pragma unroll
    for (int kk = 0; kk < 16; ++kk) {
      const float4 av = *(const float4*)&As[kk][ty << 2];
      const float4 bv = *(const float4*)&Bs[kk][tx << 2];
      FMA4x4(acc, av, bv)
    }
    __syncthreads();
  }
#pragma unroll
  for (int i = 0; i < 4; ++i)
#pragma unroll
    for (int j = 0; j < 4; ++j) {
      const int nn = n0 + (tx << 2) + j;
      if (nn < NOUT)
        out[(size_t)(m0 + (ty << 2) + i) * NOUT + nn] = acc[i][j] + bias[nn];
    }
}

// ---------------- K7: labels (int32 -> f32 copy) --------------------------
__global__ __launch_bounds__(256) void k_labels(
    const int* __restrict__ lab, float* __restrict__ outw,
    float* __restrict__ outp) {
  const int i = blockIdx.x * 256 + threadIdx.x;
  if (i < NB * NS) {
    const int b = i >> 7, s = i & 127;
    outw[i] = (float)lab[b * NTOT + s];
  }
  if (i < NB * NSTEPS) {
    const int b = i / 127;
    outp[i] = (float)lab[b * NTOT + NS + (i - b * 127)];
  }
}

extern "C" void kernel_launch(void* const* d_in, const int* in_sizes, int n_in,
                              void* d_out, int out_size, void* d_ws, size_t ws_size,
                              hipStream_t stream) {
  (void)in_sizes; (void)n_in; (void)out_size; (void)ws_size;
  const float* elmo     = (const float*)d_in[0];
  const float* w_ih_f   = (const float*)d_in[1];
  const float* w_hh_f   = (const float*)d_in[2];
  const float* b_f      = (const float*)d_in[3];
  const float* w_ih_b   = (const float*)d_in[4];
  const float* w_hh_b   = (const float*)d_in[5];
  const float* b_b      = (const float*)d_in[6];
  const float* W1       = (const float*)d_in[7];
  const float* W2       = (const float*)d_in[8];
  const float* word_W   = (const float*)d_in[9];
  const float* word_b   = (const float*)d_in[10];
  const float* phrase_W = (const float*)d_in[11];
  const float* phrase_b = (const float*)d_in[12];
  const int* cinfo      = (const int*)d_in[13];
  const int* lab        = (const int*)d_in[15];

  unsigned short* xpb  = (unsigned short*)d_ws;
  float* h_all         = (float*)(xpb + XPB_SZ);
  float* vec           = h_all + H_SZ;
  unsigned short* h_bf = (unsigned short*)(vec + VEC_SZ);
  unsigned short* e_bf = h_bf + HB_SZ;
  unsigned short* W_bf = e_bf + EB_SZ;
  int* bar             = (int*)(W_bf + WB_SZ);

  float* out_word = (float*)d_out;                       // 8192 x 511
  float* out_phr  = out_word + (size_t)8192 * NWV;       // 8128 x 152
  float* out_lw   = out_phr + (size_t)8128 * NPV;        // 8192
  float* out_lp   = out_lw + 8192;                       // 8128

  k_cvt<<<dim3(2048), 256, 0, stream>>>(elmo, w_ih_f, w_ih_b, e_bf, W_bf, bar);
  k_xp<<<dim3(32, 64), 256, 0, stream>>>(e_bf, W_bf, b_f, b_b, xpb);
  k_lstm<<<dim3(64), 256, 0, stream>>>(w_hh_f, w_hh_b, xpb, h_all, h_bf, bar);
  k_comb<<<dim3(8, 128), 256, 0, stream>>>(h_all, W1, W2, vec);
  k_norm<<<dim3(2048), 256, 0, stream>>>(vec);
  k_compose<<<dim3(64), 512, 0, stream>>>(vec, cinfo);
  k_out<0><<<dim3(8, 128), 256, 0, stream>>>(vec, word_W, word_b, out_word);
  k_out<1><<<dim3(3, 127), 256, 0, stream>>>(vec, phrase_W, phrase_b, out_phr);
  k_labels<<<dim3(32), 256, 0, stream>>>(lab, out_lw, out_lp);
}

// Round 11
// 1690.660 us; speedup vs baseline: 2.9319x; 1.1706x over previous
//
#include <hip/hip_runtime.h>
#include <math.h>

// Problem constants
#define NB 64      // batch
#define NS 128     // seq len
#define ND 1024    // input dim
#define NH 512     // hidden
#define NG 2048    // 4*H
#define NTOT 255   // 2S-1
#define NSTEPS 127 // S-1
#define NWV 511
#define NPV 152

// ws layout:
//  xpb    : ushort [2][128][32][4][16][64] = 33,554,432 us  (per-block chunks)
//  h_all  : float  [2][128][512][64]  =  8,388,608 f
//  vec    : float  [64][255][512]     =  8,355,840 f
//  h_bf   : ushort [2][128][64][512]  =  8,388,608 us   ([pos][b][k])
//  elmo_bf: ushort [128*64][1024]     =  8,388,608 us   ([t*64+b][k])
//  W_bf   : ushort [4096][1024]       =  4,194,304 us
//  bar    : int [8192]
static const size_t XPB_SZ = (size_t)2 * NS * NG * NB;
static const size_t H_SZ   = (size_t)2 * NS * NH * NB;
static const size_t VEC_SZ = (size_t)NB * NTOT * NH;
static const size_t HB_SZ  = (size_t)2 * NS * NH * NB;
static const size_t EB_SZ  = (size_t)NB * NS * ND;
static const size_t WB_SZ  = (size_t)4096 * ND;

typedef __attribute__((ext_vector_type(8))) short short8v;
typedef __attribute__((ext_vector_type(8))) unsigned short ushort8v;
typedef __attribute__((ext_vector_type(4))) float float4v;

__device__ __forceinline__ float sigm(float x) { return 1.f / (1.f + __expf(-x)); }
__device__ __forceinline__ float tanh_fast(float x) {
  const float e = __expf(2.f * x);
  return 1.f - 2.f / (e + 1.f);
}
__device__ __forceinline__ unsigned short f2bf(float x) {
  unsigned b = __float_as_uint(x);
  return (unsigned short)((b + 0x7FFFu + ((b >> 16) & 1u)) >> 16);
}
__device__ __forceinline__ float bf2f(unsigned short u) {
  return __uint_as_float(((unsigned)u) << 16);
}

#define FMA4x4(acc, av, bv)                                                    \
  acc[0][0] += av.x * bv.x; acc[0][1] += av.x * bv.y;                          \
  acc[0][2] += av.x * bv.z; acc[0][3] += av.x * bv.w;                          \
  acc[1][0] += av.y * bv.x; acc[1][1] += av.y * bv.y;                          \
  acc[1][2] += av.y * bv.z; acc[1][3] += av.y * bv.w;                          \
  acc[2][0] += av.z * bv.x; acc[2][1] += av.z * bv.y;                          \
  acc[2][2] += av.z * bv.z; acc[2][3] += av.z * bv.w;                          \
  acc[3][0] += av.w * bv.x; acc[3][1] += av.w * bv.y;                          \
  acc[3][2] += av.w * bv.z; acc[3][3] += av.w * bv.w;

// ---------------- K0: fp32 -> bf16 conversions + barrier zero -------------
__global__ __launch_bounds__(256) void k_cvt(
    const float* __restrict__ elmo, const float* __restrict__ wf,
    const float* __restrict__ wb, unsigned short* __restrict__ elmo_bf,
    unsigned short* __restrict__ W_bf, int* __restrict__ bar) {
  const int gid = blockIdx.x * 256 + threadIdx.x;
  if (gid < 8192) bar[gid] = 0;
  const int NE4 = (NB * NS * ND) / 4;   // 2,097,152
  const int NW4 = (4096 * ND) / 4;      // 1,048,576
  const int NW4h = NW4 / 2;
  for (int i = gid; i < NE4 + NW4; i += gridDim.x * 256) {
    float4 v;
    unsigned short* dst;
    if (i < NE4) {
      const int e0 = i << 2;
      const int b = e0 >> 17;
      const int t = (e0 >> 10) & 127;
      const int k = e0 & 1023;
      v = *(const float4*)(elmo + e0);
      dst = elmo_bf + ((size_t)((t << 6) + b) << 10) + k;
    } else {
      const int j = i - NE4;
      v = (j < NW4h) ? *(const float4*)(wf + ((size_t)j << 2))
                     : *(const float4*)(wb + ((size_t)(j - NW4h) << 2));
      dst = W_bf + ((size_t)j << 2);
    }
    uint2 u;
    u.x = (unsigned)f2bf(v.x) | ((unsigned)f2bf(v.y) << 16);
    u.y = (unsigned)f2bf(v.z) | ((unsigned)f2bf(v.w) << 16);
    *(uint2*)dst = u;
  }
}

// ---------------- K1: xp = elmo @ w_ih^T + bias (bf16 MFMA) ---------------
// Output layout (for k_lstm block-contiguous reads):
//   xpb[(((dir*128 + t)*32 + cb)*4 + g)*1024 + cl*64 + b]   (ushort bf16)
__global__ __launch_bounds__(256) void k_xp(
    const unsigned short* __restrict__ elmo_bf,
    const unsigned short* __restrict__ W_bf,
    const float* __restrict__ biasf, const float* __restrict__ biasb,
    unsigned short* __restrict__ xpb) {
  __shared__ unsigned short As[128 * 64];  // 16 KB, swizzled
  __shared__ unsigned short Bs[128 * 64];  // 16 KB
  const int tid = threadIdx.x;
  const int n0 = blockIdx.x * 128;
  const int m0 = blockIdx.y * 128;
  const int wv = tid >> 6, lane = tid & 63;
  const int cl = lane & 15, bq = lane >> 4;
  const int wm = (wv >> 1) << 6;   // 0 / 64
  const int wn = (wv & 1) << 6;    // 0 / 64
  // staging: thread -> (row sr of 128, k-half skc of 32)
  const int sr = tid >> 1, skc = (tid & 1) << 5;
  const unsigned short* asrc = elmo_bf + (size_t)(m0 + sr) * ND + skc;
  const unsigned short* bsrc = W_bf + (size_t)(n0 + sr) * ND + skc;
  const int sswz = (sr & 15) << 3;
  float4v acc[4][4];
#pragma unroll
  for (int nt = 0; nt < 4; ++nt) {
    const int n = n0 + wn + nt * 16 + cl;
    const float bv = (n < 2048) ? biasf[n] : biasb[n - 2048];
#pragma unroll
    for (int mt = 0; mt < 4; ++mt) acc[mt][nt] = (float4v){bv, bv, bv, bv};
  }
  for (int k0 = 0; k0 < ND; k0 += 64) {
    ushort8v av4[4], bv4[4];
#pragma unroll
    for (int i = 0; i < 4; ++i) av4[i] = *(const ushort8v*)(asrc + k0 + 8 * i);
#pragma unroll
    for (int i = 0; i < 4; ++i) bv4[i] = *(const ushort8v*)(bsrc + k0 + 8 * i);
    __syncthreads();
#pragma unroll
    for (int i = 0; i < 4; ++i) {
      *(ushort8v*)&As[((sr << 6) + skc + 8 * i) ^ sswz] = av4[i];
      *(ushort8v*)&Bs[((sr << 6) + skc + 8 * i) ^ sswz] = bv4[i];
    }
    __syncthreads();
#pragma unroll
    for (int ks = 0; ks < 2; ++ks) {
      const int koff = (ks << 5) + (bq << 3);
      short8v af[4], bf_[4];
#pragma unroll
      for (int mt = 0; mt < 4; ++mt) {
        const int ar = wm + mt * 16 + cl;
        af[mt] = *(const short8v*)&As[((ar << 6) + koff) ^ ((ar & 15) << 3)];
      }
#pragma unroll
      for (int nt = 0; nt < 4; ++nt) {
        const int br = wn + nt * 16 + cl;
        bf_[nt] = *(const short8v*)&Bs[((br << 6) + koff) ^ ((br & 15) << 3)];
      }
#pragma unroll
      for (int mt = 0; mt < 4; ++mt)
#pragma unroll
        for (int nt = 0; nt < 4; ++nt)
          acc[mt][nt] =
              __builtin_amdgcn_mfma_f32_16x16x32_bf16(af[mt], bf_[nt], acc[mt][nt], 0, 0, 0);
    }
  }
  // epilogue: 8B stores into block-chunked layout
#pragma unroll
  for (int mt = 0; mt < 4; ++mt) {
    const int mbase = m0 + wm + mt * 16 + (bq << 2);
    const int t = mbase >> 6, b4 = mbase & 63;
#pragma unroll
    for (int nt = 0; nt < 4; ++nt) {
      const int n = n0 + wn + nt * 16 + cl;
      const int dir = n >> 11, grow = n & 2047;
      const int g = grow >> 9, cb = (grow & 511) >> 4;
      const float4v a = acc[mt][nt];
      uint2 u;
      u.x = (unsigned)f2bf(a[0]) | ((unsigned)f2bf(a[1]) << 16);
      u.y = (unsigned)f2bf(a[2]) | ((unsigned)f2bf(a[3]) << 16);
      const size_t idx =
          ((((size_t)(dir * NS + t) * 32 + cb) * 4 + g) << 10) + (cl << 6) + b4;
      *(uint2*)&xpb[idx] = u;
    }
  }
}

// ---------------- K2: persistent BiLSTM scan, v8 --------------------------
__global__ __launch_bounds__(256) void k_lstm(
    const float* __restrict__ whh_f, const float* __restrict__ whh_b,
    const unsigned short* __restrict__ xpb, float* __restrict__ h_all,
    unsigned short* __restrict__ h_bf, int* __restrict__ bar) {
  __shared__ unsigned short WS[64 * 512];   // 64 KB, swizzled [gr][k]
  __shared__ unsigned short hOut[64 * 16];  // 2 KB bounce [b][col_local]
  const int bid = blockIdx.x;
  const int dir = bid >> 5;
  const int cb = bid & 31;
  const int col0 = cb << 4;
  const int tid = threadIdx.x;
  const int lane = tid & 63;
  const int w = tid >> 6;          // wave = M-tile
  const int cl = lane & 15, bq = lane >> 4;
  const int b4 = (w << 4) + (bq << 2);   // 4 owned b rows
  const int arow = (w << 4) + cl;        // A-fragment row (b)
  const float* whh = dir ? whh_b : whh_f;

  // one-time: W slice fp32 -> bf16 LDS. thread -> (gr = tid>>2, kc = (tid&3)*128)
  {
    const int gr = tid >> 2;
    const int kc = (tid & 3) << 7;
    const int gg = gr >> 4, cc = gr & 15;
    const float* src = whh + (size_t)(gg * NH + col0 + cc) * NH + kc;
    const int swz = (gr & 15) << 3;
#pragma unroll
    for (int i = 0; i < 16; ++i) {
      const float4 f0 = *(const float4*)(src + 8 * i);
      const float4 f1 = *(const float4*)(src + 8 * i + 4);
      ushort8v u;
      u[0] = f2bf(f0.x); u[1] = f2bf(f0.y); u[2] = f2bf(f0.z); u[3] = f2bf(f0.w);
      u[4] = f2bf(f1.x); u[5] = f2bf(f1.y); u[6] = f2bf(f1.z); u[7] = f2bf(f1.w);
      *(ushort8v*)&WS[((gr << 9) + kc + 8 * i) ^ swz] = u;
    }
  }
  __syncthreads();

  float* hd = h_all + (size_t)dir * NS * NH * NB;
  unsigned short* hb_us = h_bf + ((size_t)dir * NS << 15);      // [pos][b][k]
  unsigned long long* hb_ull = (unsigned long long*)h_bf + ((size_t)dir * NS << 12);

  float4v c4 = {0.f, 0.f, 0.f, 0.f};

  // prime xp for t=0
  uint2 xg0, xg1, xg2, xg3;
  {
    const int pos0 = dir ? (NS - 1) : 0;
    const unsigned short* xc = xpb + (((size_t)(dir * NS + pos0) * 32 + cb) << 12);
    xg0 = *(const uint2*)&xc[(0 << 10) + (cl << 6) + b4];
    xg1 = *(const uint2*)&xc[(1 << 10) + (cl << 6) + b4];
    xg2 = *(const uint2*)&xc[(2 << 10) + (cl << 6) + b4];
    xg3 = *(const uint2*)&xc[(3 << 10) + (cl << 6) + b4];
  }

  for (int t = 0; t < NS; ++t) {
    const int pos = dir ? (NS - 1 - t) : t;
    float4v acc[4] = {{0.f, 0.f, 0.f, 0.f}, {0.f, 0.f, 0.f, 0.f},
                      {0.f, 0.f, 0.f, 0.f}, {0.f, 0.f, 0.f, 0.f}};
    if (t > 0) {
      const int prevpos = dir ? (pos + 1) : (pos - 1);
      const unsigned long long* hsrc = hb_ull + ((size_t)prevpos << 13);
      // 32 independent 8B SC loads -> registers (A-fragments for 16 K-steps)
      unsigned long long ha0[16], ha1[16];
#pragma unroll
      for (int ks = 0; ks < 16; ++ks) {
        const int uidx = (arow << 7) + (ks << 3) + (bq << 1);
        ha0[ks] = __hip_atomic_load(&hsrc[uidx], __ATOMIC_RELAXED,
                                    __HIP_MEMORY_SCOPE_AGENT);
        ha1[ks] = __hip_atomic_load(&hsrc[uidx + 1], __ATOMIC_RELAXED,
                                    __HIP_MEMORY_SCOPE_AGENT);
      }
#pragma unroll
      for (int ks = 0; ks < 16; ++ks) {
        union { unsigned long long u[2]; short8v v; } au;
        au.u[0] = ha0[ks]; au.u[1] = ha1[ks];
        const short8v a = au.v;
        const int koff = (ks << 5) + (bq << 3);
#pragma unroll
        for (int g = 0; g < 4; ++g) {
          const short8v bb =
              *(const short8v*)&WS[((((g << 4) + cl) << 9) + koff) ^ (cl << 3)];
          acc[g] = __builtin_amdgcn_mfma_f32_16x16x32_bf16(a, bb, acc[g], 0, 0, 0);
        }
      }
    }
    // cell update: this thread owns (col0+cl, b4..b4+3)
    float hv[4];
#pragma unroll
    for (int i = 0; i < 4; ++i) {
      const unsigned xw0 = (i < 2) ? xg0.x : xg0.y;
      const unsigned xw1 = (i < 2) ? xg1.x : xg1.y;
      const unsigned xw2 = (i < 2) ? xg2.x : xg2.y;
      const unsigned xw3 = (i < 2) ? xg3.x : xg3.y;
      const int sh = (i & 1) << 4;
      const float gi = sigm(acc[0][i] + bf2f((unsigned short)(xw0 >> sh)));
      const float gf = sigm(acc[1][i] + bf2f((unsigned short)(xw1 >> sh)));
      const float gc = tanh_fast(acc[2][i] + bf2f((unsigned short)(xw2 >> sh)));
      const float go = sigm(acc[3][i] + bf2f((unsigned short)(xw3 >> sh)));
      c4[i] = gf * c4[i] + gi * gc;
      hv[i] = go * tanh_fast(c4[i]);
    }
    // fp32 h for k_comb (normal store; consumed after kernel end)
    *(float4*)(hd + ((size_t)pos * NH + col0 + cl) * NB + b4) =
        make_float4(hv[0], hv[1], hv[2], hv[3]);
    if (t < NS - 1) {
      // bf16 h into LDS bounce [b][col_local]
#pragma unroll
      for (int i = 0; i < 4; ++i) hOut[((b4 + i) << 4) + cl] = f2bf(hv[i]);
      // prefetch next-step xp while stores/barrier are in flight
      const int npos = dir ? (pos - 1) : (pos + 1);
      const unsigned short* xc =
          xpb + (((size_t)(dir * NS + npos) * 32 + cb) << 12);
      const uint2 nx0 = *(const uint2*)&xc[(0 << 10) + (cl << 6) + b4];
      const uint2 nx1 = *(const uint2*)&xc[(1 << 10) + (cl << 6) + b4];
      const uint2 nx2 = *(const uint2*)&xc[(2 << 10) + (cl << 6) + b4];
      const uint2 nx3 = *(const uint2*)&xc[(3 << 10) + (cl << 6) + b4];
      __syncthreads();  // hOut visible
      if (tid < 128) {
        const int bb = tid >> 1, half = tid & 1;
        const unsigned long long v =
            *(const unsigned long long*)&hOut[(bb << 4) + (half << 3)];
        __hip_atomic_store(
            (unsigned long long*)&hb_us[((size_t)pos << 15) + (bb << 9) + col0 +
                                        (half << 3)],
            v, __ATOMIC_RELAXED, __HIP_MEMORY_SCOPE_AGENT);
      }
      __syncthreads();  // drains the 128 packed SC stores before the signal
      if (tid == 0) {
        int* ctr = &bar[(((t << 1) + dir) << 5)];
        __hip_atomic_fetch_add(ctr, 1, __ATOMIC_RELAXED, __HIP_MEMORY_SCOPE_AGENT);
        while (__hip_atomic_load(ctr, __ATOMIC_RELAXED, __HIP_MEMORY_SCOPE_AGENT) < 32) {
        }
      }
      __syncthreads();
      xg0 = nx0; xg1 = nx1; xg2 = nx2; xg3 = nx3;
    }
  }
}

// ---------------- K3: combined = lrelu(fwd@W1^T + bwd@W2^T) -> vec --------
__global__ __launch_bounds__(256) void k_comb(
    const float* __restrict__ h_all, const float* __restrict__ W1,
    const float* __restrict__ W2, float* __restrict__ vec) {
  __shared__ float A1[16][68], A2[16][68], B1[16][68], B2[16][68];
  const int tid = threadIdx.x;
  const int n0 = blockIdx.x * 64;
  const int s = blockIdx.y;
  const float* h0 = h_all + (size_t)s * NH * NB;
  const float* h1 = h_all + ((size_t)NS + s) * NH * NB;
  const int aj = tid >> 4, ai4 = (tid & 15) << 2;
  const int lr = tid >> 2, lc4 = (tid & 3) << 2;
  const int tx = tid & 15, ty = tid >> 4;
  const float* b1row = W1 + (size_t)(n0 + lr) * NH;
  const float* b2row = W2 + (size_t)(n0 + lr) * NH;
  float acc[4][4] = {};
  for (int k0 = 0; k0 < NH; k0 += 16) {
    *(float4*)&A1[aj][ai4] = *(const float4*)(h0 + (size_t)(k0 + aj) * NB + ai4);
    *(float4*)&A2[aj][ai4] = *(const float4*)(h1 + (size_t)(k0 + aj) * NB + ai4);
    const float4 w1 = *(const float4*)(b1row + k0 + lc4);
    B1[lc4 + 0][lr] = w1.x; B1[lc4 + 1][lr] = w1.y;
    B1[lc4 + 2][lr] = w1.z; B1[lc4 + 3][lr] = w1.w;
    const float4 w2 = *(const float4*)(b2row + k0 + lc4);
    B2[lc4 + 0][lr] = w2.x; B2[lc4 + 1][lr] = w2.y;
    B2[lc4 + 2][lr] = w2.z; B2[lc4 + 3][lr] = w2.w;
    __syncthreads();
#pragma unroll
    for (int kk = 0; kk < 16; ++kk) {
      const float4 a1 = *(const float4*)&A1[kk][ty << 2];
      const float4 b1 = *(const float4*)&B1[kk][tx << 2];
      FMA4x4(acc, a1, b1)
      const float4 a2 = *(const float4*)&A2[kk][ty << 2];
      const float4 b2 = *(const float4*)&B2[kk][tx << 2];
      FMA4x4(acc, a2, b2)
    }
    __syncthreads();
  }
#pragma unroll
  for (int i = 0; i < 4; ++i) {
    const int b = (ty << 2) + i;
#pragma unroll
    for (int j = 0; j < 4; ++j) {
      const int nn = n0 + (tx << 2) + j;
      float v = acc[i][j];
      v = v > 0.f ? v : 0.01f * v;
      vec[((size_t)b * NTOT + s) * NH + nn] = v;
    }
  }
}

// ---------------- K4: l2-normalize word rows of vec -----------------------
__global__ __launch_bounds__(256) void k_norm(float* __restrict__ vec) {
  const int row = (blockIdx.x << 2) + (threadIdx.x >> 6);  // 0..8191
  const int lane = threadIdx.x & 63;
  const int b = row >> 7, s = row & 127;
  float* p = vec + ((size_t)b * NTOT + s) * NH;
  float4 v0 = *(float4*)(p + (lane << 3));
  float4 v1 = *(float4*)(p + (lane << 3) + 4);
  float ss = v0.x * v0.x + v0.y * v0.y + v0.z * v0.z + v0.w * v0.w +
             v1.x * v1.x + v1.y * v1.y + v1.z * v1.z + v1.w * v1.w;
#pragma unroll
  for (int off = 32; off; off >>= 1) ss += __shfl_down(ss, off);
  ss = __shfl(ss, 0);
  const float sc = 1.f / fmaxf(sqrtf(ss), 1e-12f);
  v0.x *= sc; v0.y *= sc; v0.z *= sc; v0.w *= sc;
  v1.x *= sc; v1.y *= sc; v1.z *= sc; v1.w *= sc;
  *(float4*)(p + (lane << 3)) = v0;
  *(float4*)(p + (lane << 3) + 4) = v1;
}

// ---------------- K5: per-batch tree composition scan, v2 -----------------
// kt=8 register tiling (3 rvd b128 -> 32 FMA), skewed LDS (SK: +4 per 32
// floats -> <=2-way bank access everywhere), packed cpart float4 stores,
// shfl_xor reduce + all-thread red sum (no serial tid0, 4 syncs/step).
#define SKW(f) ((f) + (((f) >> 5) << 2))
__global__ __launch_bounds__(512) void k_compose(
    float* __restrict__ vec, const int* __restrict__ cinfo) {
  __shared__ float lv[512];
  __shared__ float rvd[1152];       // skewed, logical [1024]
  __shared__ float cpart[8 * 576];  // [jq][k] skewed rows (18.4 KB)
  __shared__ float red[8];
  const int b = blockIdx.x;
  const int tid = threadIdx.x;
  float* vb = vec + (size_t)b * NTOT * NH;
  const int* ib = cinfo + b * NSTEPS * 4;
  const int jq = tid >> 6;          // 0..7 (uniform per wave)
  const int jb = jq << 6;           // 64 j's per thread
  const int k8 = (tid & 63) << 3;   // 8 k's per thread
  const int wid = tid >> 6, lane = tid & 63;
  for (int i = 0; i < NSTEPS; ++i) {
    const int tt = ib[i * 4 + 0], p = ib[i * 4 + 1];
    const int l = ib[i * 4 + 2], r = ib[i * 4 + 3];
    const float lvv = vb[(size_t)l * NH + tid];
    const float rvv = vb[(size_t)r * NH + tid];
    lv[tid] = lvv;
    rvd[SKW(tid)] = rvv;
    rvd[SKW(512 + tid)] = rvv;
    __syncthreads();
    if (tt == 2) {
      float acc[8] = {};
#pragma unroll 4
      for (int jj = 0; jj < 64; jj += 4) {
        const int j = jb + jj;
        const float4 l4 = *(const float4*)&lv[j];
        const int f0 = j + k8;
        const float4 r0 = *(const float4*)&rvd[SKW(f0)];
        const float4 r1 = *(const float4*)&rvd[SKW(f0 + 4)];
        const float4 r2 = *(const float4*)&rvd[SKW(f0 + 8)];
        const float rw[12] = {r0.x, r0.y, r0.z, r0.w, r1.x, r1.y,
                              r1.z, r1.w, r2.x, r2.y, r2.z, r2.w};
#pragma unroll
        for (int kk = 0; kk < 8; ++kk)
          acc[kk] += l4.x * rw[kk] + l4.y * rw[kk + 1] + l4.z * rw[kk + 2] +
                     l4.w * rw[kk + 3];
      }
      const int ca = jq * 576 + SKW(k8);   // SKW(k8+4) == SKW(k8)+4
      *(float4*)&cpart[ca] = make_float4(acc[0], acc[1], acc[2], acc[3]);
      *(float4*)&cpart[ca + 4] = make_float4(acc[4], acc[5], acc[6], acc[7]);
    }
    __syncthreads();
    float ck = 0.f;
    if (tt == 2) {
      const int ra = SKW(tid);
#pragma unroll
      for (int q = 0; q < 8; ++q) ck += cpart[q * 576 + ra];
    }
    float ss = ck * ck;
#pragma unroll
    for (int off = 32; off; off >>= 1) ss += __shfl_xor(ss, off);
    if (lane == 0) red[wid] = ss;
    __syncthreads();
    if (tt == 2) {
      const float tot = red[0] + red[1] + red[2] + red[3] +
                        red[4] + red[5] + red[6] + red[7];
      const float inv = 1.f / fmaxf(sqrtf(tot), 1e-12f);
      vb[(size_t)p * NH + tid] = ck * inv;
    } else if (tt == 1) {
      vb[(size_t)p * NH + tid] = lvv;
    }
    __syncthreads();
  }
}

// ---------------- K6: output GEMMs (word / phrase) ------------------------
template <int MODE>
__global__ __launch_bounds__(256) void k_out(
    const float* __restrict__ vec, const float* __restrict__ W,
    const float* __restrict__ bias, float* __restrict__ out) {
  constexpr int NOUT = MODE ? NPV : NWV;
  __shared__ float As[16][68], Bs[16][68];
  const int tid = threadIdx.x;
  const int n0 = blockIdx.x * 64, m0 = blockIdx.y * 64;
  const int lr = tid >> 2, lc4 = (tid & 3) << 2;
  const int tx = tid & 15, ty = tid >> 4;
  const int m = m0 + lr;
  int vr;
  if (MODE == 0) {
    vr = (m >> 7) * NTOT + (m & 127);
  } else {
    const int bb = m / 127;
    vr = bb * NTOT + NS + (m - bb * 127);
  }
  const float* arow = vec + (size_t)vr * NH;
  const int n = n0 + lr;
  const float* brow = W + (size_t)n * NH;
  const bool bok = (n < NOUT);
  float acc[4][4] = {};
  for (int k0 = 0; k0 < NH; k0 += 16) {
    const float4 a4 = *(const float4*)(arow + k0 + lc4);
    As[lc4 + 0][lr] = a4.x; As[lc4 + 1][lr] = a4.y;
    As[lc4 + 2][lr] = a4.z; As[lc4 + 3][lr] = a4.w;
    float4 b4 = make_float4(0.f, 0.f, 0.f, 0.f);
    if (bok) b4 = *(const float4*)(brow + k0 + lc4);
    Bs[lc4 + 0][lr] = b4.x; Bs[lc4 + 1][lr] = b4.y;
    Bs[lc4 + 2][lr] = b4.z; Bs[lc4 + 3][lr] = b4.w;
    __syncthreads();
#pragma unroll
    for (int kk = 0; kk < 16; ++kk) {
      const float4 av = *(const float4*)&As[kk][ty << 2];
      const float4 bv = *(const float4*)&Bs[kk][tx << 2];
      FMA4x4(acc, av, bv)
    }
    __syncthreads();
  }
#pragma unroll
  for (int i = 0; i < 4; ++i)
#pragma unroll
    for (int j = 0; j < 4; ++j) {
      const int nn = n0 + (tx << 2) + j;
      if (nn < NOUT)
        out[(size_t)(m0 + (ty << 2) + i) * NOUT + nn] = acc[i][j] + bias[nn];
    }
}

// ---------------- K7: labels (int32 -> f32 copy) --------------------------
__global__ __launch_bounds__(256) void k_labels(
    const int* __restrict__ lab, float* __restrict__ outw,
    float* __restrict__ outp) {
  const int i = blockIdx.x * 256 + threadIdx.x;
  if (i < NB * NS) {
    const int b = i >> 7, s = i & 127;
    outw[i] = (float)lab[b * NTOT + s];
  }
  if (i < NB * NSTEPS) {
    const int b = i / 127;
    outp[i] = (float)lab[b * NTOT + NS + (i - b * 127)];
  }
}

extern "C" void kernel_launch(void* const* d_in, const int* in_sizes, int n_in,
                              void* d_out, int out_size, void* d_ws, size_t ws_size,
                              hipStream_t stream) {
  (void)in_sizes; (void)n_in; (void)out_size; (void)ws_size;
  const float* elmo     = (const float*)d_in[0];
  const float* w_ih_f   = (const float*)d_in[1];
  const float* w_hh_f   = (const float*)d_in[2];
  const float* b_f      = (const float*)d_in[3];
  const float* w_ih_b   = (const float*)d_in[4];
  const float* w_hh_b   = (const float*)d_in[5];
  const float* b_b      = (const float*)d_in[6];
  const float* W1       = (const float*)d_in[7];
  const float* W2       = (const float*)d_in[8];
  const float* word_W   = (const float*)d_in[9];
  const float* word_b   = (const float*)d_in[10];
  const float* phrase_W = (const float*)d_in[11];
  const float* phrase_b = (const float*)d_in[12];
  const int* cinfo      = (const int*)d_in[13];
  const int* lab        = (const int*)d_in[15];

  unsigned short* xpb  = (unsigned short*)d_ws;
  float* h_all         = (float*)(xpb + XPB_SZ);
  float* vec           = h_all + H_SZ;
  unsigned short* h_bf = (unsigned short*)(vec + VEC_SZ);
  unsigned short* e_bf = h_bf + HB_SZ;
  unsigned short* W_bf = e_bf + EB_SZ;
  int* bar             = (int*)(W_bf + WB_SZ);

  float* out_word = (float*)d_out;                       // 8192 x 511
  float* out_phr  = out_word + (size_t)8192 * NWV;       // 8128 x 152
  float* out_lw   = out_phr + (size_t)8128 * NPV;        // 8192
  float* out_lp   = out_lw + 8192;                       // 8128

  k_cvt<<<dim3(2048), 256, 0, stream>>>(elmo, w_ih_f, w_ih_b, e_bf, W_bf, bar);
  k_xp<<<dim3(32, 64), 256, 0, stream>>>(e_bf, W_bf, b_f, b_b, xpb);
  k_lstm<<<dim3(64), 256, 0, stream>>>(w_hh_f, w_hh_b, xpb, h_all, h_bf, bar);
  k_comb<<<dim3(8, 128), 256, 0, stream>>>(h_all, W1, W2, vec);
  k_norm<<<dim3(2048), 256, 0, stream>>>(vec);
  k_compose<<<dim3(64), 512, 0, stream>>>(vec, cinfo);
  k_out<0><<<dim3(8, 128), 256, 0, stream>>>(vec, word_W, word_b, out_word);
  k_out<1><<<dim3(3, 127), 256, 0, stream>>>(vec, phrase_W, phrase_b, out_phr);
  k_labels<<<dim3(32), 256, 0, stream>>>(lab, out_lw, out_lp);
}

// Round 12
// 1556.462 us; speedup vs baseline: 3.1847x; 1.0862x over previous
//
#include <hip/hip_runtime.h>
#include <math.h>

// Problem constants
#define NB 64      // batch
#define NS 128     // seq len
#define ND 1024    // input dim
#define NH 512     // hidden
#define NG 2048    // 4*H
#define NTOT 255   // 2S-1
#define NSTEPS 127 // S-1
#define NWV 511
#define NPV 152

static const size_t XPB_SZ = (size_t)2 * NS * NG * NB;
static const size_t H_SZ   = (size_t)2 * NS * NH * NB;   // unused fp32 slot (layout kept)
static const size_t VEC_SZ = (size_t)NB * NTOT * NH;
static const size_t HB_SZ  = (size_t)2 * NS * NH * NB;
static const size_t EB_SZ  = (size_t)NB * NS * ND;
static const size_t WB_SZ  = (size_t)4096 * ND;
static const size_t W12_SZ = (size_t)2 * NH * NH;        // 524288
static const size_t WO_SZ  = (size_t)512 * NH;           // 262144 (511 rows + pad)
static const size_t VB_SZ  = (size_t)NB * NS * NH;       // 4194304

typedef __attribute__((ext_vector_type(8))) short short8v;
typedef __attribute__((ext_vector_type(8))) unsigned short ushort8v;
typedef __attribute__((ext_vector_type(4))) float float4v;

__device__ __forceinline__ float sigm(float x) { return 1.f / (1.f + __expf(-x)); }
__device__ __forceinline__ float tanh_fast(float x) {
  const float e = __expf(2.f * x);
  return 1.f - 2.f / (e + 1.f);
}
__device__ __forceinline__ unsigned short f2bf(float x) {
  unsigned b = __float_as_uint(x);
  return (unsigned short)((b + 0x7FFFu + ((b >> 16) & 1u)) >> 16);
}
__device__ __forceinline__ float bf2f(unsigned short u) {
  return __uint_as_float(((unsigned)u) << 16);
}

#define FMA4x4(acc, av, bv)                                                    \
  acc[0][0] += av.x * bv.x; acc[0][1] += av.x * bv.y;                          \
  acc[0][2] += av.x * bv.z; acc[0][3] += av.x * bv.w;                          \
  acc[1][0] += av.y * bv.x; acc[1][1] += av.y * bv.y;                          \
  acc[1][2] += av.y * bv.z; acc[1][3] += av.y * bv.w;                          \
  acc[2][0] += av.z * bv.x; acc[2][1] += av.z * bv.y;                          \
  acc[2][2] += av.z * bv.z; acc[2][3] += av.z * bv.w;                          \
  acc[3][0] += av.w * bv.x; acc[3][1] += av.w * bv.y;                          \
  acc[3][2] += av.w * bv.z; acc[3][3] += av.w * bv.w;

// ---------------- K0: fp32 -> bf16 conversions + barrier zero -------------
__global__ __launch_bounds__(256) void k_cvt(
    const float* __restrict__ elmo, const float* __restrict__ wf,
    const float* __restrict__ wb, const float* __restrict__ W1,
    const float* __restrict__ W2, const float* __restrict__ wordW,
    unsigned short* __restrict__ elmo_bf, unsigned short* __restrict__ W_bf,
    unsigned short* __restrict__ W12_bf, unsigned short* __restrict__ wout_bf,
    int* __restrict__ bar) {
  const int gid = blockIdx.x * 256 + threadIdx.x;
  if (gid < 8192) bar[gid] = 0;
  const int NE4 = (NB * NS * ND) / 4;   // 2,097,152
  const int NW4 = (4096 * ND) / 4;      // 1,048,576
  const int NW4h = NW4 / 2;
  const int N12 = (int)(W12_SZ / 4);    // 131,072
  const int NWO = (int)(WO_SZ / 4);     // 65,536
  const int NWO_real = (NWV * NH) / 4;  // 65,408
  const int TOT = NE4 + NW4 + N12 + NWO;
  for (int i = gid; i < TOT; i += gridDim.x * 256) {
    float4 v = make_float4(0.f, 0.f, 0.f, 0.f);
    unsigned short* dst;
    if (i < NE4) {
      const int e0 = i << 2;
      const int b = e0 >> 17;
      const int t = (e0 >> 10) & 127;
      const int k = e0 & 1023;
      v = *(const float4*)(elmo + e0);
      dst = elmo_bf + ((size_t)((t << 6) + b) << 10) + k;
    } else if (i < NE4 + NW4) {
      const int j = i - NE4;
      v = (j < NW4h) ? *(const float4*)(wf + ((size_t)j << 2))
                     : *(const float4*)(wb + ((size_t)(j - NW4h) << 2));
      dst = W_bf + ((size_t)j << 2);
    } else if (i < NE4 + NW4 + N12) {
      const int j = i - NE4 - NW4;
      const int half = N12 / 2;
      v = (j < half) ? *(const float4*)(W1 + ((size_t)j << 2))
                     : *(const float4*)(W2 + ((size_t)(j - half) << 2));
      dst = W12_bf + ((size_t)j << 2);
    } else {
      const int j = i - NE4 - NW4 - N12;
      if (j < NWO_real) v = *(const float4*)(wordW + ((size_t)j << 2));
      dst = wout_bf + ((size_t)j << 2);
    }
    uint2 u;
    u.x = (unsigned)f2bf(v.x) | ((unsigned)f2bf(v.y) << 16);
    u.y = (unsigned)f2bf(v.z) | ((unsigned)f2bf(v.w) << 16);
    *(uint2*)dst = u;
  }
}

// ---------------- K1: xp = elmo @ w_ih^T + bias (bf16 MFMA) ---------------
__global__ __launch_bounds__(256) void k_xp(
    const unsigned short* __restrict__ elmo_bf,
    const unsigned short* __restrict__ W_bf,
    const float* __restrict__ biasf, const float* __restrict__ biasb,
    unsigned short* __restrict__ xpb) {
  __shared__ unsigned short As[128 * 64];
  __shared__ unsigned short Bs[128 * 64];
  const int tid = threadIdx.x;
  const int n0 = blockIdx.x * 128;
  const int m0 = blockIdx.y * 128;
  const int wv = tid >> 6, lane = tid & 63;
  const int cl = lane & 15, bq = lane >> 4;
  const int wm = (wv >> 1) << 6;
  const int wn = (wv & 1) << 6;
  const int sr = tid >> 1, skc = (tid & 1) << 5;
  const unsigned short* asrc = elmo_bf + (size_t)(m0 + sr) * ND + skc;
  const unsigned short* bsrc = W_bf + (size_t)(n0 + sr) * ND + skc;
  const int sswz = (sr & 15) << 3;
  float4v acc[4][4];
#pragma unroll
  for (int nt = 0; nt < 4; ++nt) {
    const int n = n0 + wn + nt * 16 + cl;
    const float bv = (n < 2048) ? biasf[n] : biasb[n - 2048];
#pragma unroll
    for (int mt = 0; mt < 4; ++mt) acc[mt][nt] = (float4v){bv, bv, bv, bv};
  }
  for (int k0 = 0; k0 < ND; k0 += 64) {
    ushort8v av4[4], bv4[4];
#pragma unroll
    for (int i = 0; i < 4; ++i) av4[i] = *(const ushort8v*)(asrc + k0 + 8 * i);
#pragma unroll
    for (int i = 0; i < 4; ++i) bv4[i] = *(const ushort8v*)(bsrc + k0 + 8 * i);
    __syncthreads();
#pragma unroll
    for (int i = 0; i < 4; ++i) {
      *(ushort8v*)&As[((sr << 6) + skc + 8 * i) ^ sswz] = av4[i];
      *(ushort8v*)&Bs[((sr << 6) + skc + 8 * i) ^ sswz] = bv4[i];
    }
    __syncthreads();
#pragma unroll
    for (int ks = 0; ks < 2; ++ks) {
      const int koff = (ks << 5) + (bq << 3);
      short8v af[4], bf_[4];
#pragma unroll
      for (int mt = 0; mt < 4; ++mt) {
        const int ar = wm + mt * 16 + cl;
        af[mt] = *(const short8v*)&As[((ar << 6) + koff) ^ ((ar & 15) << 3)];
      }
#pragma unroll
      for (int nt = 0; nt < 4; ++nt) {
        const int br = wn + nt * 16 + cl;
        bf_[nt] = *(const short8v*)&Bs[((br << 6) + koff) ^ ((br & 15) << 3)];
      }
#pragma unroll
      for (int mt = 0; mt < 4; ++mt)
#pragma unroll
        for (int nt = 0; nt < 4; ++nt)
          acc[mt][nt] =
              __builtin_amdgcn_mfma_f32_16x16x32_bf16(af[mt], bf_[nt], acc[mt][nt], 0, 0, 0);
    }
  }
#pragma unroll
  for (int mt = 0; mt < 4; ++mt) {
    const int mbase = m0 + wm + mt * 16 + (bq << 2);
    const int t = mbase >> 6, b4 = mbase & 63;
#pragma unroll
    for (int nt = 0; nt < 4; ++nt) {
      const int n = n0 + wn + nt * 16 + cl;
      const int dir = n >> 11, grow = n & 2047;
      const int g = grow >> 9, cb = (grow & 511) >> 4;
      const float4v a = acc[mt][nt];
      uint2 u;
      u.x = (unsigned)f2bf(a[0]) | ((unsigned)f2bf(a[1]) << 16);
      u.y = (unsigned)f2bf(a[2]) | ((unsigned)f2bf(a[3]) << 16);
      const size_t idx =
          ((((size_t)(dir * NS + t) * 32 + cb) * 4 + g) << 10) + (cl << 6) + b4;
      *(uint2*)&xpb[idx] = u;
    }
  }
}

// ---------------- K2: persistent BiLSTM scan, v9 --------------------------
// v8 + h_bf stored for ALL steps (k_comb consumes it); fp32 h_all store
// removed (k_comb no longer reads it).
__global__ __launch_bounds__(256) void k_lstm(
    const float* __restrict__ whh_f, const float* __restrict__ whh_b,
    const unsigned short* __restrict__ xpb,
    unsigned short* __restrict__ h_bf, int* __restrict__ bar) {
  __shared__ unsigned short WS[64 * 512];   // 64 KB, swizzled [gr][k]
  __shared__ unsigned short hOut[64 * 16];  // 2 KB bounce [b][col_local]
  const int bid = blockIdx.x;
  const int dir = bid >> 5;
  const int cb = bid & 31;
  const int col0 = cb << 4;
  const int tid = threadIdx.x;
  const int lane = tid & 63;
  const int w = tid >> 6;
  const int cl = lane & 15, bq = lane >> 4;
  const int b4 = (w << 4) + (bq << 2);
  const int arow = (w << 4) + cl;
  const float* whh = dir ? whh_b : whh_f;

  {
    const int gr = tid >> 2;
    const int kc = (tid & 3) << 7;
    const int gg = gr >> 4, cc = gr & 15;
    const float* src = whh + (size_t)(gg * NH + col0 + cc) * NH + kc;
    const int swz = (gr & 15) << 3;
#pragma unroll
    for (int i = 0; i < 16; ++i) {
      const float4 f0 = *(const float4*)(src + 8 * i);
      const float4 f1 = *(const float4*)(src + 8 * i + 4);
      ushort8v u;
      u[0] = f2bf(f0.x); u[1] = f2bf(f0.y); u[2] = f2bf(f0.z); u[3] = f2bf(f0.w);
      u[4] = f2bf(f1.x); u[5] = f2bf(f1.y); u[6] = f2bf(f1.z); u[7] = f2bf(f1.w);
      *(ushort8v*)&WS[((gr << 9) + kc + 8 * i) ^ swz] = u;
    }
  }
  __syncthreads();

  unsigned short* hb_us = h_bf + ((size_t)dir * NS << 15);      // [pos][b][k]
  unsigned long long* hb_ull = (unsigned long long*)h_bf + ((size_t)dir * NS << 12);

  float4v c4 = {0.f, 0.f, 0.f, 0.f};

  uint2 xg0, xg1, xg2, xg3;
  {
    const int pos0 = dir ? (NS - 1) : 0;
    const unsigned short* xc = xpb + (((size_t)(dir * NS + pos0) * 32 + cb) << 12);
    xg0 = *(const uint2*)&xc[(0 << 10) + (cl << 6) + b4];
    xg1 = *(const uint2*)&xc[(1 << 10) + (cl << 6) + b4];
    xg2 = *(const uint2*)&xc[(2 << 10) + (cl << 6) + b4];
    xg3 = *(const uint2*)&xc[(3 << 10) + (cl << 6) + b4];
  }

  for (int t = 0; t < NS; ++t) {
    const int pos = dir ? (NS - 1 - t) : t;
    float4v acc[4] = {{0.f, 0.f, 0.f, 0.f}, {0.f, 0.f, 0.f, 0.f},
                      {0.f, 0.f, 0.f, 0.f}, {0.f, 0.f, 0.f, 0.f}};
    if (t > 0) {
      const int prevpos = dir ? (pos + 1) : (pos - 1);
      const unsigned long long* hsrc = hb_ull + ((size_t)prevpos << 13);
      unsigned long long ha0[16], ha1[16];
#pragma unroll
      for (int ks = 0; ks < 16; ++ks) {
        const int uidx = (arow << 7) + (ks << 3) + (bq << 1);
        ha0[ks] = __hip_atomic_load(&hsrc[uidx], __ATOMIC_RELAXED,
                                    __HIP_MEMORY_SCOPE_AGENT);
        ha1[ks] = __hip_atomic_load(&hsrc[uidx + 1], __ATOMIC_RELAXED,
                                    __HIP_MEMORY_SCOPE_AGENT);
      }
#pragma unroll
      for (int ks = 0; ks < 16; ++ks) {
        union { unsigned long long u[2]; short8v v; } au;
        au.u[0] = ha0[ks]; au.u[1] = ha1[ks];
        const short8v a = au.v;
        const int koff = (ks << 5) + (bq << 3);
#pragma unroll
        for (int g = 0; g < 4; ++g) {
          const short8v bb =
              *(const short8v*)&WS[((((g << 4) + cl) << 9) + koff) ^ (cl << 3)];
          acc[g] = __builtin_amdgcn_mfma_f32_16x16x32_bf16(a, bb, acc[g], 0, 0, 0);
        }
      }
    }
    float hv[4];
#pragma unroll
    for (int i = 0; i < 4; ++i) {
      const unsigned xw0 = (i < 2) ? xg0.x : xg0.y;
      const unsigned xw1 = (i < 2) ? xg1.x : xg1.y;
      const unsigned xw2 = (i < 2) ? xg2.x : xg2.y;
      const unsigned xw3 = (i < 2) ? xg3.x : xg3.y;
      const int sh = (i & 1) << 4;
      const float gi = sigm(acc[0][i] + bf2f((unsigned short)(xw0 >> sh)));
      const float gf = sigm(acc[1][i] + bf2f((unsigned short)(xw1 >> sh)));
      const float gc = tanh_fast(acc[2][i] + bf2f((unsigned short)(xw2 >> sh)));
      const float go = sigm(acc[3][i] + bf2f((unsigned short)(xw3 >> sh)));
      c4[i] = gf * c4[i] + gi * gc;
      hv[i] = go * tanh_fast(c4[i]);
    }
    // bf16 h into LDS bounce (all steps; consumed by exchange + k_comb)
#pragma unroll
    for (int i = 0; i < 4; ++i) hOut[((b4 + i) << 4) + cl] = f2bf(hv[i]);
    if (t < NS - 1) {
      const int npos = dir ? (pos - 1) : (pos + 1);
      const unsigned short* xc =
          xpb + (((size_t)(dir * NS + npos) * 32 + cb) << 12);
      const uint2 nx0 = *(const uint2*)&xc[(0 << 10) + (cl << 6) + b4];
      const uint2 nx1 = *(const uint2*)&xc[(1 << 10) + (cl << 6) + b4];
      const uint2 nx2 = *(const uint2*)&xc[(2 << 10) + (cl << 6) + b4];
      const uint2 nx3 = *(const uint2*)&xc[(3 << 10) + (cl << 6) + b4];
      __syncthreads();  // hOut visible
      if (tid < 128) {
        const int bb = tid >> 1, half = tid & 1;
        const unsigned long long v =
            *(const unsigned long long*)&hOut[(bb << 4) + (half << 3)];
        __hip_atomic_store(
            (unsigned long long*)&hb_us[((size_t)pos << 15) + (bb << 9) + col0 +
                                        (half << 3)],
            v, __ATOMIC_RELAXED, __HIP_MEMORY_SCOPE_AGENT);
      }
      __syncthreads();  // drains stores before the signal
      if (tid == 0) {
        int* ctr = &bar[(((t << 1) + dir) << 5)];
        __hip_atomic_fetch_add(ctr, 1, __ATOMIC_RELAXED, __HIP_MEMORY_SCOPE_AGENT);
        while (__hip_atomic_load(ctr, __ATOMIC_RELAXED, __HIP_MEMORY_SCOPE_AGENT) < 32) {
        }
      }
      __syncthreads();
      xg0 = nx0; xg1 = nx1; xg2 = nx2; xg3 = nx3;
    } else {
      __syncthreads();  // hOut visible
      if (tid < 128) {
        const int bb = tid >> 1, half = tid & 1;
        const unsigned long long v =
            *(const unsigned long long*)&hOut[(bb << 4) + (half << 3)];
        __hip_atomic_store(
            (unsigned long long*)&hb_us[((size_t)pos << 15) + (bb << 9) + col0 +
                                        (half << 3)],
            v, __ATOMIC_RELAXED, __HIP_MEMORY_SCOPE_AGENT);
      }
    }
  }
}

// ---------------- K3: combined = lrelu(fwd@W1^T + bwd@W2^T), bf16 MFMA ----
// A from h_bf[dir][s][b][k]; B from W12_bf[dir][n][k]. Per block: s, 64-n tile.
__global__ __launch_bounds__(256) void k_comb(
    const unsigned short* __restrict__ h_bf,
    const unsigned short* __restrict__ W12_bf, float* __restrict__ vec) {
  __shared__ unsigned short A1s[64 * 128], A2s[64 * 128];
  __shared__ unsigned short B1s[64 * 128], B2s[64 * 128];
  const int tid = threadIdx.x;
  const int n0 = blockIdx.x * 64;
  const int s = blockIdx.y;
  const int w = tid >> 6, lane = tid & 63;
  const int cl = lane & 15, bq = lane >> 4;
  const int wn = w << 4;
  const unsigned short* a1src = h_bf + ((size_t)s << 15);
  const unsigned short* a2src = h_bf + ((size_t)(NS + s) << 15);
  const unsigned short* b1src = W12_bf + (size_t)n0 * NH;
  const unsigned short* b2src = W12_bf + (size_t)(NH + n0) * NH;
  const int srow = tid >> 2, skq = (tid & 3) << 5;
  const int sswz = (srow & 15) << 3;
  float4v acc[4] = {{0.f, 0.f, 0.f, 0.f}, {0.f, 0.f, 0.f, 0.f},
                    {0.f, 0.f, 0.f, 0.f}, {0.f, 0.f, 0.f, 0.f}};
  for (int k0 = 0; k0 < NH; k0 += 128) {
    ushort8v a1[4], a2[4], b1[4], b2[4];
#pragma unroll
    for (int i = 0; i < 4; ++i) {
      const size_t off = (size_t)srow * NH + k0 + skq + 8 * i;
      a1[i] = *(const ushort8v*)(a1src + off);
      a2[i] = *(const ushort8v*)(a2src + off);
      b1[i] = *(const ushort8v*)(b1src + off);
      b2[i] = *(const ushort8v*)(b2src + off);
    }
    __syncthreads();  // prior-iter MFMA reads done
#pragma unroll
    for (int i = 0; i < 4; ++i) {
      const int idx = ((srow << 7) + skq + 8 * i) ^ sswz;
      *(ushort8v*)&A1s[idx] = a1[i];
      *(ushort8v*)&A2s[idx] = a2[i];
      *(ushort8v*)&B1s[idx] = b1[i];
      *(ushort8v*)&B2s[idx] = b2[i];
    }
    __syncthreads();
#pragma unroll
    for (int ks = 0; ks < 4; ++ks) {
      const int koff = (ks << 5) + (bq << 3);
      const short8v bf1 =
          *(const short8v*)&B1s[(((wn + cl) << 7) + koff) ^ (cl << 3)];
      const short8v bf2 =
          *(const short8v*)&B2s[(((wn + cl) << 7) + koff) ^ (cl << 3)];
#pragma unroll
      for (int mt = 0; mt < 4; ++mt) {
        const int ar = mt * 16 + cl;
        const short8v af1 = *(const short8v*)&A1s[((ar << 7) + koff) ^ (cl << 3)];
        const short8v af2 = *(const short8v*)&A2s[((ar << 7) + koff) ^ (cl << 3)];
        acc[mt] = __builtin_amdgcn_mfma_f32_16x16x32_bf16(af1, bf1, acc[mt], 0, 0, 0);
        acc[mt] = __builtin_amdgcn_mfma_f32_16x16x32_bf16(af2, bf2, acc[mt], 0, 0, 0);
      }
    }
  }
  const int n = n0 + wn + cl;
#pragma unroll
  for (int mt = 0; mt < 4; ++mt) {
    const int b0 = mt * 16 + (bq << 2);
#pragma unroll
    for (int i = 0; i < 4; ++i) {
      float v = acc[mt][i];
      v = v > 0.f ? v : 0.01f * v;
      vec[((size_t)(b0 + i) * NTOT + s) * NH + n] = v;
    }
  }
}

// ---------------- K4: l2-normalize word rows; emit fp32 + bf16 ------------
__global__ __launch_bounds__(256) void k_norm(float* __restrict__ vec,
                                              unsigned short* __restrict__ vec_bf) {
  const int row = (blockIdx.x << 2) + (threadIdx.x >> 6);  // 0..8191
  const int lane = threadIdx.x & 63;
  const int b = row >> 7, s = row & 127;
  float* p = vec + ((size_t)b * NTOT + s) * NH;
  float4 v0 = *(float4*)(p + (lane << 3));
  float4 v1 = *(float4*)(p + (lane << 3) + 4);
  float ss = v0.x * v0.x + v0.y * v0.y + v0.z * v0.z + v0.w * v0.w +
             v1.x * v1.x + v1.y * v1.y + v1.z * v1.z + v1.w * v1.w;
#pragma unroll
  for (int off = 32; off; off >>= 1) ss += __shfl_down(ss, off);
  ss = __shfl(ss, 0);
  const float sc = 1.f / fmaxf(sqrtf(ss), 1e-12f);
  v0.x *= sc; v0.y *= sc; v0.z *= sc; v0.w *= sc;
  v1.x *= sc; v1.y *= sc; v1.z *= sc; v1.w *= sc;
  *(float4*)(p + (lane << 3)) = v0;
  *(float4*)(p + (lane << 3) + 4) = v1;
  ushort8v u;
  u[0] = f2bf(v0.x); u[1] = f2bf(v0.y); u[2] = f2bf(v0.z); u[3] = f2bf(v0.w);
  u[4] = f2bf(v1.x); u[5] = f2bf(v1.y); u[6] = f2bf(v1.z); u[7] = f2bf(v1.w);
  *(ushort8v*)&vec_bf[((size_t)row << 9) + (lane << 3)] = u;
}

// ---------------- K5: per-batch tree composition scan, v2 -----------------
#define SKW(f) ((f) + (((f) >> 5) << 2))
__global__ __launch_bounds__(512) void k_compose(
    float* __restrict__ vec, const int* __restrict__ cinfo) {
  __shared__ float lv[512];
  __shared__ float rvd[1152];
  __shared__ float cpart[8 * 576];
  __shared__ float red[8];
  const int b = blockIdx.x;
  const int tid = threadIdx.x;
  float* vb = vec + (size_t)b * NTOT * NH;
  const int* ib = cinfo + b * NSTEPS * 4;
  const int jq = tid >> 6;
  const int jb = jq << 6;
  const int k8 = (tid & 63) << 3;
  const int wid = tid >> 6, lane = tid & 63;
  for (int i = 0; i < NSTEPS; ++i) {
    const int tt = ib[i * 4 + 0], p = ib[i * 4 + 1];
    const int l = ib[i * 4 + 2], r = ib[i * 4 + 3];
    const float lvv = vb[(size_t)l * NH + tid];
    const float rvv = vb[(size_t)r * NH + tid];
    lv[tid] = lvv;
    rvd[SKW(tid)] = rvv;
    rvd[SKW(512 + tid)] = rvv;
    __syncthreads();
    if (tt == 2) {
      float acc[8] = {};
#pragma unroll 4
      for (int jj = 0; jj < 64; jj += 4) {
        const int j = jb + jj;
        const float4 l4 = *(const float4*)&lv[j];
        const int f0 = j + k8;
        const float4 r0 = *(const float4*)&rvd[SKW(f0)];
        const float4 r1 = *(const float4*)&rvd[SKW(f0 + 4)];
        const float4 r2 = *(const float4*)&rvd[SKW(f0 + 8)];
        const float rw[12] = {r0.x, r0.y, r0.z, r0.w, r1.x, r1.y,
                              r1.z, r1.w, r2.x, r2.y, r2.z, r2.w};
#pragma unroll
        for (int kk = 0; kk < 8; ++kk)
          acc[kk] += l4.x * rw[kk] + l4.y * rw[kk + 1] + l4.z * rw[kk + 2] +
                     l4.w * rw[kk + 3];
      }
      const int ca = jq * 576 + SKW(k8);
      *(float4*)&cpart[ca] = make_float4(acc[0], acc[1], acc[2], acc[3]);
      *(float4*)&cpart[ca + 4] = make_float4(acc[4], acc[5], acc[6], acc[7]);
    }
    __syncthreads();
    float ck = 0.f;
    if (tt == 2) {
      const int ra = SKW(tid);
#pragma unroll
      for (int q = 0; q < 8; ++q) ck += cpart[q * 576 + ra];
    }
    float ss = ck * ck;
#pragma unroll
    for (int off = 32; off; off >>= 1) ss += __shfl_xor(ss, off);
    if (lane == 0) red[wid] = ss;
    __syncthreads();
    if (tt == 2) {
      const float tot = red[0] + red[1] + red[2] + red[3] +
                        red[4] + red[5] + red[6] + red[7];
      const float inv = 1.f / fmaxf(sqrtf(tot), 1e-12f);
      vb[(size_t)p * NH + tid] = ck * inv;
    } else if (tt == 1) {
      vb[(size_t)p * NH + tid] = lvv;
    }
    __syncthreads();
  }
}

// ---------------- K6a: word output GEMM, bf16 MFMA ------------------------
// out[m][n] = vec_bf[m] . wout_bf[n] + bias[n], m<8192, n<511 (row 511 pad=0)
__global__ __launch_bounds__(256) void k_outw(
    const unsigned short* __restrict__ vec_bf,
    const unsigned short* __restrict__ wout_bf,
    const float* __restrict__ bias, float* __restrict__ out) {
  __shared__ unsigned short As[128 * 64];
  __shared__ unsigned short Bs[128 * 64];
  const int tid = threadIdx.x;
  const int n0 = blockIdx.x * 128;
  const int m0 = blockIdx.y * 128;
  const int wv = tid >> 6, lane = tid & 63;
  const int cl = lane & 15, bq = lane >> 4;
  const int wm = (wv >> 1) << 6;
  const int wn = (wv & 1) << 6;
  const int sr = tid >> 1, skc = (tid & 1) << 5;
  const unsigned short* asrc = vec_bf + (size_t)(m0 + sr) * NH + skc;
  const unsigned short* bsrc = wout_bf + (size_t)(n0 + sr) * NH + skc;
  const int sswz = (sr & 15) << 3;
  float4v acc[4][4] = {};
  for (int k0 = 0; k0 < NH; k0 += 64) {
    ushort8v av4[4], bv4[4];
#pragma unroll
    for (int i = 0; i < 4; ++i) av4[i] = *(const ushort8v*)(asrc + k0 + 8 * i);
#pragma unroll
    for (int i = 0; i < 4; ++i) bv4[i] = *(const ushort8v*)(bsrc + k0 + 8 * i);
    __syncthreads();
#pragma unroll
    for (int i = 0; i < 4; ++i) {
      *(ushort8v*)&As[((sr << 6) + skc + 8 * i) ^ sswz] = av4[i];
      *(ushort8v*)&Bs[((sr << 6) + skc + 8 * i) ^ sswz] = bv4[i];
    }
    __syncthreads();
#pragma unroll
    for (int ks = 0; ks < 2; ++ks) {
      const int koff = (ks << 5) + (bq << 3);
      short8v af[4], bf_[4];
#pragma unroll
      for (int mt = 0; mt < 4; ++mt) {
        const int ar = wm + mt * 16 + cl;
        af[mt] = *(const short8v*)&As[((ar << 6) + koff) ^ ((ar & 15) << 3)];
      }
#pragma unroll
      for (int nt = 0; nt < 4; ++nt) {
        const int br = wn + nt * 16 + cl;
        bf_[nt] = *(const short8v*)&Bs[((br << 6) + koff) ^ ((br & 15) << 3)];
      }
#pragma unroll
      for (int mt = 0; mt < 4; ++mt)
#pragma unroll
        for (int nt = 0; nt < 4; ++nt)
          acc[mt][nt] =
              __builtin_amdgcn_mfma_f32_16x16x32_bf16(af[mt], bf_[nt], acc[mt][nt], 0, 0, 0);
    }
  }
#pragma unroll
  for (int mt = 0; mt < 4; ++mt) {
    const int mb = m0 + wm + mt * 16 + (bq << 2);
#pragma unroll
    for (int nt = 0; nt < 4; ++nt) {
      const int n = n0 + wn + nt * 16 + cl;
      if (n < NWV) {
        const float bn = bias[n];
#pragma unroll
        for (int i = 0; i < 4; ++i)
          out[(size_t)(mb + i) * NWV + n] = acc[mt][nt][i] + bn;
      }
    }
  }
}

// ---------------- K6b: phrase output GEMM (fp32, small) -------------------
__global__ __launch_bounds__(256) void k_outp(
    const float* __restrict__ vec, const float* __restrict__ W,
    const float* __restrict__ bias, float* __restrict__ out) {
  constexpr int NOUT = NPV;
  __shared__ float As[16][68], Bs[16][68];
  const int tid = threadIdx.x;
  const int n0 = blockIdx.x * 64, m0 = blockIdx.y * 64;
  const int lr = tid >> 2, lc4 = (tid & 3) << 2;
  const int tx = tid & 15, ty = tid >> 4;
  const int m = m0 + lr;
  const int bb = m / 127;
  const int vr = bb * NTOT + NS + (m - bb * 127);
  const float* arow = vec + (size_t)vr * NH;
  const int n = n0 + lr;
  const float* brow = W + (size_t)n * NH;
  const bool bok = (n < NOUT);
  float acc[4][4] = {};
  for (int k0 = 0; k0 < NH; k0 += 16) {
    const float4 a4 = *(const float4*)(arow + k0 + lc4);
    As[lc4 + 0][lr] = a4.x; As[lc4 + 1][lr] = a4.y;
    As[lc4 + 2][lr] = a4.z; As[lc4 + 3][lr] = a4.w;
    float4 b4 = make_float4(0.f, 0.f, 0.f, 0.f);
    if (bok) b4 = *(const float4*)(brow + k0 + lc4);
    Bs[lc4 + 0][lr] = b4.x; Bs[lc4 + 1][lr] = b4.y;
    Bs[lc4 + 2][lr] = b4.z; Bs[lc4 + 3][lr] = b4.w;
    __syncthreads();
#pragma unroll
    for (int kk = 0; kk < 16; ++kk) {
      const float4 av = *(const float4*)&As[kk][ty << 2];
      const float4 bv = *(const float4*)&Bs[kk][tx << 2];
      FMA4x4(acc, av, bv)
    }
    __syncthreads();
  }
#pragma unroll
  for (int i = 0; i < 4; ++i)
#pragma unroll
    for (int j = 0; j < 4; ++j) {
      const int nn = n0 + (tx << 2) + j;
      if (nn < NOUT)
        out[(size_t)(m0 + (ty << 2) + i) * NOUT + nn] = acc[i][j] + bias[nn];
    }
}

// ---------------- K7: labels (int32 -> f32 copy) --------------------------
__global__ __launch_bounds__(256) void k_labels(
    const int* __restrict__ lab, float* __restrict__ outw,
    float* __restrict__ outp) {
  const int i = blockIdx.x * 256 + threadIdx.x;
  if (i < NB * NS) {
    const int b = i >> 7, s = i & 127;
    outw[i] = (float)lab[b * NTOT + s];
  }
  if (i < NB * NSTEPS) {
    const int b = i / 127;
    outp[i] = (float)lab[b * NTOT + NS + (i - b * 127)];
  }
}

extern "C" void kernel_launch(void* const* d_in, const int* in_sizes, int n_in,
                              void* d_out, int out_size, void* d_ws, size_t ws_size,
                              hipStream_t stream) {
  (void)in_sizes; (void)n_in; (void)out_size; (void)ws_size;
  const float* elmo     = (const float*)d_in[0];
  const float* w_ih_f   = (const float*)d_in[1];
  const float* w_hh_f   = (const float*)d_in[2];
  const float* b_f      = (const float*)d_in[3];
  const float* w_ih_b   = (const float*)d_in[4];
  const float* w_hh_b   = (const float*)d_in[5];
  const float* b_b      = (const float*)d_in[6];
  const float* W1       = (const float*)d_in[7];
  const float* W2       = (const float*)d_in[8];
  const float* word_W   = (const float*)d_in[9];
  const float* word_b   = (const float*)d_in[10];
  const float* phrase_W = (const float*)d_in[11];
  const float* phrase_b = (const float*)d_in[12];
  const int* cinfo      = (const int*)d_in[13];
  const int* lab        = (const int*)d_in[15];

  unsigned short* xpb   = (unsigned short*)d_ws;
  float* h_all          = (float*)(xpb + XPB_SZ);   // unused slot (layout kept)
  float* vec            = h_all + H_SZ;
  unsigned short* h_bf  = (unsigned short*)(vec + VEC_SZ);
  unsigned short* e_bf  = h_bf + HB_SZ;
  unsigned short* W_bf  = e_bf + EB_SZ;
  unsigned short* W12_bf  = W_bf + WB_SZ;
  unsigned short* wout_bf = W12_bf + W12_SZ;
  unsigned short* vec_bf  = wout_bf + WO_SZ;
  int* bar              = (int*)(vec_bf + VB_SZ);

  float* out_word = (float*)d_out;                       // 8192 x 511
  float* out_phr  = out_word + (size_t)8192 * NWV;       // 8128 x 152
  float* out_lw   = out_phr + (size_t)8128 * NPV;        // 8192
  float* out_lp   = out_lw + 8192;                       // 8128

  k_cvt<<<dim3(2048), 256, 0, stream>>>(elmo, w_ih_f, w_ih_b, W1, W2, word_W,
                                        e_bf, W_bf, W12_bf, wout_bf, bar);
  k_xp<<<dim3(32, 64), 256, 0, stream>>>(e_bf, W_bf, b_f, b_b, xpb);
  k_lstm<<<dim3(64), 256, 0, stream>>>(w_hh_f, w_hh_b, xpb, h_bf, bar);
  k_comb<<<dim3(8, 128), 256, 0, stream>>>(h_bf, W12_bf, vec);
  k_norm<<<dim3(2048), 256, 0, stream>>>(vec, vec_bf);
  k_compose<<<dim3(64), 512, 0, stream>>>(vec, cinfo);
  k_outw<<<dim3(4, 64), 256, 0, stream>>>(vec_bf, wout_bf, word_b, out_word);
  k_outp<<<dim3(3, 127), 256, 0, stream>>>(vec, phrase_W, phrase_b, out_phr);
  k_labels<<<dim3(32), 256, 0, stream>>>(lab, out_lw, out_lp);
}

// Round 13
// 1521.018 us; speedup vs baseline: 3.2589x; 1.0233x over previous
//
#include <hip/hip_runtime.h>
#include <math.h>

// Problem constants
#define NB 64      // batch
#define NS 128     // seq len
#define ND 1024    // input dim
#define NH 512     // hidden
#define NG 2048    // 4*H
#define NTOT 255   // 2S-1
#define NSTEPS 127 // S-1
#define NWV 511
#define NPV 152

static const size_t XPB_SZ = (size_t)2 * NS * NG * NB;
static const size_t H_SZ   = (size_t)2 * NS * NH * NB;   // region reused: vecp_bf + wp_bf
static const size_t VEC_SZ = (size_t)NB * NTOT * NH;
static const size_t HB_SZ  = (size_t)2 * NS * NH * NB;
static const size_t EB_SZ  = (size_t)NB * NS * ND;
static const size_t WB_SZ  = (size_t)4096 * ND;
static const size_t W12_SZ = (size_t)2 * NH * NH;        // 524288
static const size_t WO_SZ  = (size_t)512 * NH;           // 262144 (511 rows + pad)
static const size_t VB_SZ  = (size_t)NB * NS * NH;       // 4194304
static const size_t VP_SZ  = (size_t)8192 * NH;          // 4194304 (8128 + pad)
static const size_t WP_SZ  = (size_t)256 * NH;           // 131072 (152 + pad)

typedef __attribute__((ext_vector_type(8))) short short8v;
typedef __attribute__((ext_vector_type(8))) unsigned short ushort8v;
typedef __attribute__((ext_vector_type(4))) float float4v;

__device__ __forceinline__ float sigm(float x) { return 1.f / (1.f + __expf(-x)); }
__device__ __forceinline__ float tanh_fast(float x) {
  const float e = __expf(2.f * x);
  return 1.f - 2.f / (e + 1.f);
}
__device__ __forceinline__ unsigned short f2bf(float x) {
  unsigned b = __float_as_uint(x);
  return (unsigned short)((b + 0x7FFFu + ((b >> 16) & 1u)) >> 16);
}
__device__ __forceinline__ float bf2f(unsigned short u) {
  return __uint_as_float(((unsigned)u) << 16);
}

#define FMA4x4(acc, av, bv)                                                    \
  acc[0][0] += av.x * bv.x; acc[0][1] += av.x * bv.y;                          \
  acc[0][2] += av.x * bv.z; acc[0][3] += av.x * bv.w;                          \
  acc[1][0] += av.y * bv.x; acc[1][1] += av.y * bv.y;                          \
  acc[1][2] += av.y * bv.z; acc[1][3] += av.y * bv.w;                          \
  acc[2][0] += av.z * bv.x; acc[2][1] += av.z * bv.y;                          \
  acc[2][2] += av.z * bv.z; acc[2][3] += av.z * bv.w;                          \
  acc[3][0] += av.w * bv.x; acc[3][1] += av.w * bv.y;                          \
  acc[3][2] += av.w * bv.z; acc[3][3] += av.w * bv.w;

// ---------------- K0: fp32 -> bf16 conversions + barrier zero -------------
__global__ __launch_bounds__(256) void k_cvt(
    const float* __restrict__ elmo, const float* __restrict__ wf,
    const float* __restrict__ wb, const float* __restrict__ W1,
    const float* __restrict__ W2, const float* __restrict__ wordW,
    const float* __restrict__ phraseW,
    unsigned short* __restrict__ elmo_bf, unsigned short* __restrict__ W_bf,
    unsigned short* __restrict__ W12_bf, unsigned short* __restrict__ wout_bf,
    unsigned short* __restrict__ wp_bf, int* __restrict__ bar) {
  const int gid = blockIdx.x * 256 + threadIdx.x;
  if (gid < 8192) bar[gid] = 0;
  const int NE4 = (NB * NS * ND) / 4;   // 2,097,152
  const int NW4 = (4096 * ND) / 4;      // 1,048,576
  const int NW4h = NW4 / 2;
  const int N12 = (int)(W12_SZ / 4);    // 131,072
  const int NWO = (int)(WO_SZ / 4);     // 65,536
  const int NWO_real = (NWV * NH) / 4;  // 65,408
  const int NP4 = (int)(WP_SZ / 4);     // 32,768
  const int NP4_real = (NPV * NH) / 4;  // 19,456
  const int TOT = NE4 + NW4 + N12 + NWO + NP4;
  for (int i = gid; i < TOT; i += gridDim.x * 256) {
    float4 v = make_float4(0.f, 0.f, 0.f, 0.f);
    unsigned short* dst;
    if (i < NE4) {
      const int e0 = i << 2;
      const int b = e0 >> 17;
      const int t = (e0 >> 10) & 127;
      const int k = e0 & 1023;
      v = *(const float4*)(elmo + e0);
      dst = elmo_bf + ((size_t)((t << 6) + b) << 10) + k;
    } else if (i < NE4 + NW4) {
      const int j = i - NE4;
      v = (j < NW4h) ? *(const float4*)(wf + ((size_t)j << 2))
                     : *(const float4*)(wb + ((size_t)(j - NW4h) << 2));
      dst = W_bf + ((size_t)j << 2);
    } else if (i < NE4 + NW4 + N12) {
      const int j = i - NE4 - NW4;
      const int half = N12 / 2;
      v = (j < half) ? *(const float4*)(W1 + ((size_t)j << 2))
                     : *(const float4*)(W2 + ((size_t)(j - half) << 2));
      dst = W12_bf + ((size_t)j << 2);
    } else if (i < NE4 + NW4 + N12 + NWO) {
      const int j = i - NE4 - NW4 - N12;
      if (j < NWO_real) v = *(const float4*)(wordW + ((size_t)j << 2));
      dst = wout_bf + ((size_t)j << 2);
    } else {
      const int j = i - NE4 - NW4 - N12 - NWO;
      if (j < NP4_real) v = *(const float4*)(phraseW + ((size_t)j << 2));
      dst = wp_bf + ((size_t)j << 2);
    }
    uint2 u;
    u.x = (unsigned)f2bf(v.x) | ((unsigned)f2bf(v.y) << 16);
    u.y = (unsigned)f2bf(v.z) | ((unsigned)f2bf(v.w) << 16);
    *(uint2*)dst = u;
  }
}

// ---------------- K1: xp = elmo @ w_ih^T + bias (bf16 MFMA) ---------------
__global__ __launch_bounds__(256) void k_xp(
    const unsigned short* __restrict__ elmo_bf,
    const unsigned short* __restrict__ W_bf,
    const float* __restrict__ biasf, const float* __restrict__ biasb,
    unsigned short* __restrict__ xpb) {
  __shared__ unsigned short As[128 * 64];
  __shared__ unsigned short Bs[128 * 64];
  const int tid = threadIdx.x;
  const int n0 = blockIdx.x * 128;
  const int m0 = blockIdx.y * 128;
  const int wv = tid >> 6, lane = tid & 63;
  const int cl = lane & 15, bq = lane >> 4;
  const int wm = (wv >> 1) << 6;
  const int wn = (wv & 1) << 6;
  const int sr = tid >> 1, skc = (tid & 1) << 5;
  const unsigned short* asrc = elmo_bf + (size_t)(m0 + sr) * ND + skc;
  const unsigned short* bsrc = W_bf + (size_t)(n0 + sr) * ND + skc;
  const int sswz = (sr & 15) << 3;
  float4v acc[4][4];
#pragma unroll
  for (int nt = 0; nt < 4; ++nt) {
    const int n = n0 + wn + nt * 16 + cl;
    const float bv = (n < 2048) ? biasf[n] : biasb[n - 2048];
#pragma unroll
    for (int mt = 0; mt < 4; ++mt) acc[mt][nt] = (float4v){bv, bv, bv, bv};
  }
  for (int k0 = 0; k0 < ND; k0 += 64) {
    ushort8v av4[4], bv4[4];
#pragma unroll
    for (int i = 0; i < 4; ++i) av4[i] = *(const ushort8v*)(asrc + k0 + 8 * i);
#pragma unroll
    for (int i = 0; i < 4; ++i) bv4[i] = *(const ushort8v*)(bsrc + k0 + 8 * i);
    __syncthreads();
#pragma unroll
    for (int i = 0; i < 4; ++i) {
      *(ushort8v*)&As[((sr << 6) + skc + 8 * i) ^ sswz] = av4[i];
      *(ushort8v*)&Bs[((sr << 6) + skc + 8 * i) ^ sswz] = bv4[i];
    }
    __syncthreads();
#pragma unroll
    for (int ks = 0; ks < 2; ++ks) {
      const int koff = (ks << 5) + (bq << 3);
      short8v af[4], bf_[4];
#pragma unroll
      for (int mt = 0; mt < 4; ++mt) {
        const int ar = wm + mt * 16 + cl;
        af[mt] = *(const short8v*)&As[((ar << 6) + koff) ^ ((ar & 15) << 3)];
      }
#pragma unroll
      for (int nt = 0; nt < 4; ++nt) {
        const int br = wn + nt * 16 + cl;
        bf_[nt] = *(const short8v*)&Bs[((br << 6) + koff) ^ ((br & 15) << 3)];
      }
#pragma unroll
      for (int mt = 0; mt < 4; ++mt)
#pragma unroll
        for (int nt = 0; nt < 4; ++nt)
          acc[mt][nt] =
              __builtin_amdgcn_mfma_f32_16x16x32_bf16(af[mt], bf_[nt], acc[mt][nt], 0, 0, 0);
    }
  }
#pragma unroll
  for (int mt = 0; mt < 4; ++mt) {
    const int mbase = m0 + wm + mt * 16 + (bq << 2);
    const int t = mbase >> 6, b4 = mbase & 63;
#pragma unroll
    for (int nt = 0; nt < 4; ++nt) {
      const int n = n0 + wn + nt * 16 + cl;
      const int dir = n >> 11, grow = n & 2047;
      const int g = grow >> 9, cb = (grow & 511) >> 4;
      const float4v a = acc[mt][nt];
      uint2 u;
      u.x = (unsigned)f2bf(a[0]) | ((unsigned)f2bf(a[1]) << 16);
      u.y = (unsigned)f2bf(a[2]) | ((unsigned)f2bf(a[3]) << 16);
      const size_t idx =
          ((((size_t)(dir * NS + t) * 32 + cb) * 4 + g) << 10) + (cl << 6) + b4;
      *(uint2*)&xpb[idx] = u;
    }
  }
}

// ---------------- K2: persistent BiLSTM scan, v9 --------------------------
__global__ __launch_bounds__(256) void k_lstm(
    const float* __restrict__ whh_f, const float* __restrict__ whh_b,
    const unsigned short* __restrict__ xpb,
    unsigned short* __restrict__ h_bf, int* __restrict__ bar) {
  __shared__ unsigned short WS[64 * 512];   // 64 KB, swizzled [gr][k]
  __shared__ unsigned short hOut[64 * 16];  // 2 KB bounce [b][col_local]
  const int bid = blockIdx.x;
  const int dir = bid >> 5;
  const int cb = bid & 31;
  const int col0 = cb << 4;
  const int tid = threadIdx.x;
  const int lane = tid & 63;
  const int w = tid >> 6;
  const int cl = lane & 15, bq = lane >> 4;
  const int b4 = (w << 4) + (bq << 2);
  const int arow = (w << 4) + cl;
  const float* whh = dir ? whh_b : whh_f;

  {
    const int gr = tid >> 2;
    const int kc = (tid & 3) << 7;
    const int gg = gr >> 4, cc = gr & 15;
    const float* src = whh + (size_t)(gg * NH + col0 + cc) * NH + kc;
    const int swz = (gr & 15) << 3;
#pragma unroll
    for (int i = 0; i < 16; ++i) {
      const float4 f0 = *(const float4*)(src + 8 * i);
      const float4 f1 = *(const float4*)(src + 8 * i + 4);
      ushort8v u;
      u[0] = f2bf(f0.x); u[1] = f2bf(f0.y); u[2] = f2bf(f0.z); u[3] = f2bf(f0.w);
      u[4] = f2bf(f1.x); u[5] = f2bf(f1.y); u[6] = f2bf(f1.z); u[7] = f2bf(f1.w);
      *(ushort8v*)&WS[((gr << 9) + kc + 8 * i) ^ swz] = u;
    }
  }
  __syncthreads();

  unsigned short* hb_us = h_bf + ((size_t)dir * NS << 15);      // [pos][b][k]
  unsigned long long* hb_ull = (unsigned long long*)h_bf + ((size_t)dir * NS << 12);

  float4v c4 = {0.f, 0.f, 0.f, 0.f};

  uint2 xg0, xg1, xg2, xg3;
  {
    const int pos0 = dir ? (NS - 1) : 0;
    const unsigned short* xc = xpb + (((size_t)(dir * NS + pos0) * 32 + cb) << 12);
    xg0 = *(const uint2*)&xc[(0 << 10) + (cl << 6) + b4];
    xg1 = *(const uint2*)&xc[(1 << 10) + (cl << 6) + b4];
    xg2 = *(const uint2*)&xc[(2 << 10) + (cl << 6) + b4];
    xg3 = *(const uint2*)&xc[(3 << 10) + (cl << 6) + b4];
  }

  for (int t = 0; t < NS; ++t) {
    const int pos = dir ? (NS - 1 - t) : t;
    float4v acc[4] = {{0.f, 0.f, 0.f, 0.f}, {0.f, 0.f, 0.f, 0.f},
                      {0.f, 0.f, 0.f, 0.f}, {0.f, 0.f, 0.f, 0.f}};
    if (t > 0) {
      const int prevpos = dir ? (pos + 1) : (pos - 1);
      const unsigned long long* hsrc = hb_ull + ((size_t)prevpos << 13);
      unsigned long long ha0[16], ha1[16];
#pragma unroll
      for (int ks = 0; ks < 16; ++ks) {
        const int uidx = (arow << 7) + (ks << 3) + (bq << 1);
        ha0[ks] = __hip_atomic_load(&hsrc[uidx], __ATOMIC_RELAXED,
                                    __HIP_MEMORY_SCOPE_AGENT);
        ha1[ks] = __hip_atomic_load(&hsrc[uidx + 1], __ATOMIC_RELAXED,
                                    __HIP_MEMORY_SCOPE_AGENT);
      }
#pragma unroll
      for (int ks = 0; ks < 16; ++ks) {
        union { unsigned long long u[2]; short8v v; } au;
        au.u[0] = ha0[ks]; au.u[1] = ha1[ks];
        const short8v a = au.v;
        const int koff = (ks << 5) + (bq << 3);
#pragma unroll
        for (int g = 0; g < 4; ++g) {
          const short8v bb =
              *(const short8v*)&WS[((((g << 4) + cl) << 9) + koff) ^ (cl << 3)];
          acc[g] = __builtin_amdgcn_mfma_f32_16x16x32_bf16(a, bb, acc[g], 0, 0, 0);
        }
      }
    }
    float hv[4];
#pragma unroll
    for (int i = 0; i < 4; ++i) {
      const unsigned xw0 = (i < 2) ? xg0.x : xg0.y;
      const unsigned xw1 = (i < 2) ? xg1.x : xg1.y;
      const unsigned xw2 = (i < 2) ? xg2.x : xg2.y;
      const unsigned xw3 = (i < 2) ? xg3.x : xg3.y;
      const int sh = (i & 1) << 4;
      const float gi = sigm(acc[0][i] + bf2f((unsigned short)(xw0 >> sh)));
      const float gf = sigm(acc[1][i] + bf2f((unsigned short)(xw1 >> sh)));
      const float gc = tanh_fast(acc[2][i] + bf2f((unsigned short)(xw2 >> sh)));
      const float go = sigm(acc[3][i] + bf2f((unsigned short)(xw3 >> sh)));
      c4[i] = gf * c4[i] + gi * gc;
      hv[i] = go * tanh_fast(c4[i]);
    }
#pragma unroll
    for (int i = 0; i < 4; ++i) hOut[((b4 + i) << 4) + cl] = f2bf(hv[i]);
    if (t < NS - 1) {
      const int npos = dir ? (pos - 1) : (pos + 1);
      const unsigned short* xc =
          xpb + (((size_t)(dir * NS + npos) * 32 + cb) << 12);
      const uint2 nx0 = *(const uint2*)&xc[(0 << 10) + (cl << 6) + b4];
      const uint2 nx1 = *(const uint2*)&xc[(1 << 10) + (cl << 6) + b4];
      const uint2 nx2 = *(const uint2*)&xc[(2 << 10) + (cl << 6) + b4];
      const uint2 nx3 = *(const uint2*)&xc[(3 << 10) + (cl << 6) + b4];
      __syncthreads();  // hOut visible
      if (tid < 128) {
        const int bb = tid >> 1, half = tid & 1;
        const unsigned long long v =
            *(const unsigned long long*)&hOut[(bb << 4) + (half << 3)];
        __hip_atomic_store(
            (unsigned long long*)&hb_us[((size_t)pos << 15) + (bb << 9) + col0 +
                                        (half << 3)],
            v, __ATOMIC_RELAXED, __HIP_MEMORY_SCOPE_AGENT);
      }
      __syncthreads();  // drains stores before the signal
      if (tid == 0) {
        int* ctr = &bar[(((t << 1) + dir) << 5)];
        __hip_atomic_fetch_add(ctr, 1, __ATOMIC_RELAXED, __HIP_MEMORY_SCOPE_AGENT);
        while (__hip_atomic_load(ctr, __ATOMIC_RELAXED, __HIP_MEMORY_SCOPE_AGENT) < 32) {
        }
      }
      __syncthreads();
      xg0 = nx0; xg1 = nx1; xg2 = nx2; xg3 = nx3;
    } else {
      __syncthreads();  // hOut visible
      if (tid < 128) {
        const int bb = tid >> 1, half = tid & 1;
        const unsigned long long v =
            *(const unsigned long long*)&hOut[(bb << 4) + (half << 3)];
        __hip_atomic_store(
            (unsigned long long*)&hb_us[((size_t)pos << 15) + (bb << 9) + col0 +
                                        (half << 3)],
            v, __ATOMIC_RELAXED, __HIP_MEMORY_SCOPE_AGENT);
      }
    }
  }
}

// ---------------- K3: combined = lrelu(fwd@W1^T + bwd@W2^T), bf16 MFMA ----
__global__ __launch_bounds__(256) void k_comb(
    const unsigned short* __restrict__ h_bf,
    const unsigned short* __restrict__ W12_bf, float* __restrict__ vec) {
  __shared__ unsigned short A1s[64 * 128], A2s[64 * 128];
  __shared__ unsigned short B1s[64 * 128], B2s[64 * 128];
  const int tid = threadIdx.x;
  const int n0 = blockIdx.x * 64;
  const int s = blockIdx.y;
  const int w = tid >> 6, lane = tid & 63;
  const int cl = lane & 15, bq = lane >> 4;
  const int wn = w << 4;
  const unsigned short* a1src = h_bf + ((size_t)s << 15);
  const unsigned short* a2src = h_bf + ((size_t)(NS + s) << 15);
  const unsigned short* b1src = W12_bf + (size_t)n0 * NH;
  const unsigned short* b2src = W12_bf + (size_t)(NH + n0) * NH;
  const int srow = tid >> 2, skq = (tid & 3) << 5;
  const int sswz = (srow & 15) << 3;
  float4v acc[4] = {{0.f, 0.f, 0.f, 0.f}, {0.f, 0.f, 0.f, 0.f},
                    {0.f, 0.f, 0.f, 0.f}, {0.f, 0.f, 0.f, 0.f}};
  for (int k0 = 0; k0 < NH; k0 += 128) {
    ushort8v a1[4], a2[4], b1[4], b2[4];
#pragma unroll
    for (int i = 0; i < 4; ++i) {
      const size_t off = (size_t)srow * NH + k0 + skq + 8 * i;
      a1[i] = *(const ushort8v*)(a1src + off);
      a2[i] = *(const ushort8v*)(a2src + off);
      b1[i] = *(const ushort8v*)(b1src + off);
      b2[i] = *(const ushort8v*)(b2src + off);
    }
    __syncthreads();
#pragma unroll
    for (int i = 0; i < 4; ++i) {
      const int idx = ((srow << 7) + skq + 8 * i) ^ sswz;
      *(ushort8v*)&A1s[idx] = a1[i];
      *(ushort8v*)&A2s[idx] = a2[i];
      *(ushort8v*)&B1s[idx] = b1[i];
      *(ushort8v*)&B2s[idx] = b2[i];
    }
    __syncthreads();
#pragma unroll
    for (int ks = 0; ks < 4; ++ks) {
      const int koff = (ks << 5) + (bq << 3);
      const short8v bf1 =
          *(const short8v*)&B1s[(((wn + cl) << 7) + koff) ^ (cl << 3)];
      const short8v bf2 =
          *(const short8v*)&B2s[(((wn + cl) << 7) + koff) ^ (cl << 3)];
#pragma unroll
      for (int mt = 0; mt < 4; ++mt) {
        const int ar = mt * 16 + cl;
        const short8v af1 = *(const short8v*)&A1s[((ar << 7) + koff) ^ (cl << 3)];
        const short8v af2 = *(const short8v*)&A2s[((ar << 7) + koff) ^ (cl << 3)];
        acc[mt] = __builtin_amdgcn_mfma_f32_16x16x32_bf16(af1, bf1, acc[mt], 0, 0, 0);
        acc[mt] = __builtin_amdgcn_mfma_f32_16x16x32_bf16(af2, bf2, acc[mt], 0, 0, 0);
      }
    }
  }
  const int n = n0 + wn + cl;
#pragma unroll
  for (int mt = 0; mt < 4; ++mt) {
    const int b0 = mt * 16 + (bq << 2);
#pragma unroll
    for (int i = 0; i < 4; ++i) {
      float v = acc[mt][i];
      v = v > 0.f ? v : 0.01f * v;
      vec[((size_t)(b0 + i) * NTOT + s) * NH + n] = v;
    }
  }
}

// ---------------- K4: l2-normalize word rows; emit fp32 + bf16 ------------
__global__ __launch_bounds__(256) void k_norm(float* __restrict__ vec,
                                              unsigned short* __restrict__ vec_bf) {
  const int row = (blockIdx.x << 2) + (threadIdx.x >> 6);  // 0..8191
  const int lane = threadIdx.x & 63;
  const int b = row >> 7, s = row & 127;
  float* p = vec + ((size_t)b * NTOT + s) * NH;
  float4 v0 = *(float4*)(p + (lane << 3));
  float4 v1 = *(float4*)(p + (lane << 3) + 4);
  float ss = v0.x * v0.x + v0.y * v0.y + v0.z * v0.z + v0.w * v0.w +
             v1.x * v1.x + v1.y * v1.y + v1.z * v1.z + v1.w * v1.w;
#pragma unroll
  for (int off = 32; off; off >>= 1) ss += __shfl_down(ss, off);
  ss = __shfl(ss, 0);
  const float sc = 1.f / fmaxf(sqrtf(ss), 1e-12f);
  v0.x *= sc; v0.y *= sc; v0.z *= sc; v0.w *= sc;
  v1.x *= sc; v1.y *= sc; v1.z *= sc; v1.w *= sc;
  *(float4*)(p + (lane << 3)) = v0;
  *(float4*)(p + (lane << 3) + 4) = v1;
  ushort8v u;
  u[0] = f2bf(v0.x); u[1] = f2bf(v0.y); u[2] = f2bf(v0.z); u[3] = f2bf(v0.w);
  u[4] = f2bf(v1.x); u[5] = f2bf(v1.y); u[6] = f2bf(v1.z); u[7] = f2bf(v1.w);
  *(ushort8v*)&vec_bf[((size_t)row << 9) + (lane << 3)] = u;
}

// ---------------- K5: per-batch tree composition scan, v3 -----------------
// Always-compose (cinfo type==2 by construction). cinfo preloaded to LDS;
// next-step lv/rv prefetched during the reduce phase (register alias patch:
// column tid of any row is only ever written by thread tid, rows written
// once at p=S+i increasing -> only possible stale read is the current p).
// Emits bf16 phrase row at write time for the MFMA k_outp.
#define SKW(f) ((f) + (((f) >> 5) << 2))
__global__ __launch_bounds__(512) void k_compose(
    float* __restrict__ vec, const int* __restrict__ cinfo,
    unsigned short* __restrict__ vecp_bf) {
  __shared__ float lv[512];
  __shared__ float rvd[1152];
  __shared__ float cpart[8 * 576];
  __shared__ float red[8];
  __shared__ int ciS[NSTEPS * 4];
  const int b = blockIdx.x;
  const int tid = threadIdx.x;
  float* vb = vec + (size_t)b * NTOT * NH;
  const int* ib = cinfo + b * NSTEPS * 4;
  for (int idx = tid; idx < NSTEPS * 4; idx += 512) ciS[idx] = ib[idx];
  const int jq = tid >> 6;
  const int jb = jq << 6;
  const int k8 = (tid & 63) << 3;
  const int wid = tid >> 6, lane = tid & 63;
  __syncthreads();
  int p = ciS[1];
  float lvv = vb[(size_t)ciS[2] * NH + tid];
  float rvv = vb[(size_t)ciS[3] * NH + tid];
  for (int i = 0; i < NSTEPS; ++i) {
    lv[tid] = lvv;
    rvd[SKW(tid)] = rvv;
    rvd[SKW(512 + tid)] = rvv;
    __syncthreads();
    float acc[8] = {};
#pragma unroll 4
    for (int jj = 0; jj < 64; jj += 4) {
      const int j = jb + jj;
      const float4 l4 = *(const float4*)&lv[j];
      const int f0 = j + k8;
      const float4 r0 = *(const float4*)&rvd[SKW(f0)];
      const float4 r1 = *(const float4*)&rvd[SKW(f0 + 4)];
      const float4 r2 = *(const float4*)&rvd[SKW(f0 + 8)];
      const float rw[12] = {r0.x, r0.y, r0.z, r0.w, r1.x, r1.y,
                            r1.z, r1.w, r2.x, r2.y, r2.z, r2.w};
#pragma unroll
      for (int kk = 0; kk < 8; ++kk)
        acc[kk] += l4.x * rw[kk] + l4.y * rw[kk + 1] + l4.z * rw[kk + 2] +
                   l4.w * rw[kk + 3];
    }
    const int ca = jq * 576 + SKW(k8);
    *(float4*)&cpart[ca] = make_float4(acc[0], acc[1], acc[2], acc[3]);
    *(float4*)&cpart[ca + 4] = make_float4(acc[4], acc[5], acc[6], acc[7]);
    __syncthreads();
    // prefetch next step rows (loads overlap the reduce below)
    int pn = 0, ln = 0, rn = 0;
    float lf = 0.f, rf = 0.f;
    const bool more = (i + 1 < NSTEPS);
    if (more) {
      pn = ciS[(i + 1) * 4 + 1];
      ln = ciS[(i + 1) * 4 + 2];
      rn = ciS[(i + 1) * 4 + 3];
      lf = vb[(size_t)ln * NH + tid];
      rf = vb[(size_t)rn * NH + tid];
    }
    float ck = 0.f;
    const int ra = SKW(tid);
#pragma unroll
    for (int q = 0; q < 8; ++q) ck += cpart[q * 576 + ra];
    float ss = ck * ck;
#pragma unroll
    for (int off = 32; off; off >>= 1) ss += __shfl_xor(ss, off);
    if (lane == 0) red[wid] = ss;
    __syncthreads();
    const float tot = red[0] + red[1] + red[2] + red[3] +
                      red[4] + red[5] + red[6] + red[7];
    const float inv = 1.f / fmaxf(sqrtf(tot), 1e-12f);
    const float written = ck * inv;
    vb[(size_t)p * NH + tid] = written;
    vecp_bf[((size_t)b * 127 + (p - NS)) * NH + tid] = f2bf(written);
    if (more) {
      lvv = (ln == p) ? written : lf;
      rvv = (rn == p) ? written : rf;
      p = pn;
    }
    __syncthreads();
  }
}

// ---------------- K6a: word output GEMM, bf16 MFMA ------------------------
__global__ __launch_bounds__(256) void k_outw(
    const unsigned short* __restrict__ vec_bf,
    const unsigned short* __restrict__ wout_bf,
    const float* __restrict__ bias, float* __restrict__ out) {
  __shared__ unsigned short As[128 * 64];
  __shared__ unsigned short Bs[128 * 64];
  const int tid = threadIdx.x;
  const int n0 = blockIdx.x * 128;
  const int m0 = blockIdx.y * 128;
  const int wv = tid >> 6, lane = tid & 63;
  const int cl = lane & 15, bq = lane >> 4;
  const int wm = (wv >> 1) << 6;
  const int wn = (wv & 1) << 6;
  const int sr = tid >> 1, skc = (tid & 1) << 5;
  const unsigned short* asrc = vec_bf + (size_t)(m0 + sr) * NH + skc;
  const unsigned short* bsrc = wout_bf + (size_t)(n0 + sr) * NH + skc;
  const int sswz = (sr & 15) << 3;
  float4v acc[4][4] = {};
  for (int k0 = 0; k0 < NH; k0 += 64) {
    ushort8v av4[4], bv4[4];
#pragma unroll
    for (int i = 0; i < 4; ++i) av4[i] = *(const ushort8v*)(asrc + k0 + 8 * i);
#pragma unroll
    for (int i = 0; i < 4; ++i) bv4[i] = *(const ushort8v*)(bsrc + k0 + 8 * i);
    __syncthreads();
#pragma unroll
    for (int i = 0; i < 4; ++i) {
      *(ushort8v*)&As[((sr << 6) + skc + 8 * i) ^ sswz] = av4[i];
      *(ushort8v*)&Bs[((sr << 6) + skc + 8 * i) ^ sswz] = bv4[i];
    }
    __syncthreads();
#pragma unroll
    for (int ks = 0; ks < 2; ++ks) {
      const int koff = (ks << 5) + (bq << 3);
      short8v af[4], bf_[4];
#pragma unroll
      for (int mt = 0; mt < 4; ++mt) {
        const int ar = wm + mt * 16 + cl;
        af[mt] = *(const short8v*)&As[((ar << 6) + koff) ^ ((ar & 15) << 3)];
      }
#pragma unroll
      for (int nt = 0; nt < 4; ++nt) {
        const int br = wn + nt * 16 + cl;
        bf_[nt] = *(const short8v*)&Bs[((br << 6) + koff) ^ ((br & 15) << 3)];
      }
#pragma unroll
      for (int mt = 0; mt < 4; ++mt)
#pragma unroll
        for (int nt = 0; nt < 4; ++nt)
          acc[mt][nt] =
              __builtin_amdgcn_mfma_f32_16x16x32_bf16(af[mt], bf_[nt], acc[mt][nt], 0, 0, 0);
    }
  }
#pragma unroll
  for (int mt = 0; mt < 4; ++mt) {
    const int mb = m0 + wm + mt * 16 + (bq << 2);
#pragma unroll
    for (int nt = 0; nt < 4; ++nt) {
      const int n = n0 + wn + nt * 16 + cl;
      if (n < NWV) {
        const float bn = bias[n];
#pragma unroll
        for (int i = 0; i < 4; ++i)
          out[(size_t)(mb + i) * NWV + n] = acc[mt][nt][i] + bn;
      }
    }
  }
}

// ---------------- K6b: phrase output GEMM, bf16 MFMA ----------------------
// M = 8128 (pad 8192) rows of vecp_bf, N = 152 (pad), K = 512.
__global__ __launch_bounds__(256) void k_outp(
    const unsigned short* __restrict__ vecp_bf,
    const unsigned short* __restrict__ wp_bf,
    const float* __restrict__ bias, float* __restrict__ out) {
  __shared__ unsigned short As[128 * 64];
  __shared__ unsigned short Bs[128 * 64];
  const int tid = threadIdx.x;
  const int n0 = blockIdx.x * 128;   // 0 or 128
  const int m0 = blockIdx.y * 128;
  const int wv = tid >> 6, lane = tid & 63;
  const int cl = lane & 15, bq = lane >> 4;
  const int wm = (wv >> 1) << 6;
  const int wn = (wv & 1) << 6;
  const int sr = tid >> 1, skc = (tid & 1) << 5;
  const unsigned short* asrc = vecp_bf + (size_t)(m0 + sr) * NH + skc;
  const unsigned short* bsrc = wp_bf + (size_t)(n0 + sr) * NH + skc;
  const int sswz = (sr & 15) << 3;
  float4v acc[4][4] = {};
  for (int k0 = 0; k0 < NH; k0 += 64) {
    ushort8v av4[4], bv4[4];
#pragma unroll
    for (int i = 0; i < 4; ++i) av4[i] = *(const ushort8v*)(asrc + k0 + 8 * i);
#pragma unroll
    for (int i = 0; i < 4; ++i) bv4[i] = *(const ushort8v*)(bsrc + k0 + 8 * i);
    __syncthreads();
#pragma unroll
    for (int i = 0; i < 4; ++i) {
      *(ushort8v*)&As[((sr << 6) + skc + 8 * i) ^ sswz] = av4[i];
      *(ushort8v*)&Bs[((sr << 6) + skc + 8 * i) ^ sswz] = bv4[i];
    }
    __syncthreads();
#pragma unroll
    for (int ks = 0; ks < 2; ++ks) {
      const int koff = (ks << 5) + (bq << 3);
      short8v af[4], bf_[4];
#pragma unroll
      for (int mt = 0; mt < 4; ++mt) {
        const int ar = wm + mt * 16 + cl;
        af[mt] = *(const short8v*)&As[((ar << 6) + koff) ^ ((ar & 15) << 3)];
      }
#pragma unroll
      for (int nt = 0; nt < 4; ++nt) {
        const int br = wn + nt * 16 + cl;
        bf_[nt] = *(const short8v*)&Bs[((br << 6) + koff) ^ ((br & 15) << 3)];
      }
#pragma unroll
      for (int mt = 0; mt < 4; ++mt)
#pragma unroll
        for (int nt = 0; nt < 4; ++nt)
          acc[mt][nt] =
              __builtin_amdgcn_mfma_f32_16x16x32_bf16(af[mt], bf_[nt], acc[mt][nt], 0, 0, 0);
    }
  }
#pragma unroll
  for (int mt = 0; mt < 4; ++mt) {
    const int mb = m0 + wm + mt * 16 + (bq << 2);
#pragma unroll
    for (int nt = 0; nt < 4; ++nt) {
      const int n = n0 + wn + nt * 16 + cl;
      if (n < NPV) {
        const float bn = bias[n];
#pragma unroll
        for (int i = 0; i < 4; ++i)
          if (mb + i < 8128)
            out[(size_t)(mb + i) * NPV + n] = acc[mt][nt][i] + bn;
      }
    }
  }
}

// ---------------- K7: labels (int32 -> f32 copy) --------------------------
__global__ __launch_bounds__(256) void k_labels(
    const int* __restrict__ lab, float* __restrict__ outw,
    float* __restrict__ outp) {
  const int i = blockIdx.x * 256 + threadIdx.x;
  if (i < NB * NS) {
    const int b = i >> 7, s = i & 127;
    outw[i] = (float)lab[b * NTOT + s];
  }
  if (i < NB * NSTEPS) {
    const int b = i / 127;
    outp[i] = (float)lab[b * NTOT + NS + (i - b * 127)];
  }
}

extern "C" void kernel_launch(void* const* d_in, const int* in_sizes, int n_in,
                              void* d_out, int out_size, void* d_ws, size_t ws_size,
                              hipStream_t stream) {
  (void)in_sizes; (void)n_in; (void)out_size; (void)ws_size;
  const float* elmo     = (const float*)d_in[0];
  const float* w_ih_f   = (const float*)d_in[1];
  const float* w_hh_f   = (const float*)d_in[2];
  const float* b_f      = (const float*)d_in[3];
  const float* w_ih_b   = (const float*)d_in[4];
  const float* w_hh_b   = (const float*)d_in[5];
  const float* b_b      = (const float*)d_in[6];
  const float* W1       = (const float*)d_in[7];
  const float* W2       = (const float*)d_in[8];
  const float* word_W   = (const float*)d_in[9];
  const float* word_b   = (const float*)d_in[10];
  const float* phrase_W = (const float*)d_in[11];
  const float* phrase_b = (const float*)d_in[12];
  const int* cinfo      = (const int*)d_in[13];
  const int* lab        = (const int*)d_in[15];

  unsigned short* xpb   = (unsigned short*)d_ws;
  float* h_region       = (float*)(xpb + XPB_SZ);   // reused for vecp_bf/wp_bf
  unsigned short* vecp_bf = (unsigned short*)h_region;
  unsigned short* wp_bf   = vecp_bf + VP_SZ;
  float* vec            = h_region + H_SZ;
  unsigned short* h_bf  = (unsigned short*)(vec + VEC_SZ);
  unsigned short* e_bf  = h_bf + HB_SZ;
  unsigned short* W_bf  = e_bf + EB_SZ;
  unsigned short* W12_bf  = W_bf + WB_SZ;
  unsigned short* wout_bf = W12_bf + W12_SZ;
  unsigned short* vec_bf  = wout_bf + WO_SZ;
  int* bar              = (int*)(vec_bf + VB_SZ);

  float* out_word = (float*)d_out;                       // 8192 x 511
  float* out_phr  = out_word + (size_t)8192 * NWV;       // 8128 x 152
  float* out_lw   = out_phr + (size_t)8128 * NPV;        // 8192
  float* out_lp   = out_lw + 8192;                       // 8128

  k_cvt<<<dim3(2048), 256, 0, stream>>>(elmo, w_ih_f, w_ih_b, W1, W2, word_W,
                                        phrase_W, e_bf, W_bf, W12_bf, wout_bf,
                                        wp_bf, bar);
  k_xp<<<dim3(32, 64), 256, 0, stream>>>(e_bf, W_bf, b_f, b_b, xpb);
  k_lstm<<<dim3(64), 256, 0, stream>>>(w_hh_f, w_hh_b, xpb, h_bf, bar);
  k_comb<<<dim3(8, 128), 256, 0, stream>>>(h_bf, W12_bf, vec);
  k_norm<<<dim3(2048), 256, 0, stream>>>(vec, vec_bf);
  k_compose<<<dim3(64), 512, 0, stream>>>(vec, cinfo, vecp_bf);
  k_outw<<<dim3(4, 64), 256, 0, stream>>>(vec_bf, wout_bf, word_b, out_word);
  k_outp<<<dim3(2, 64), 256, 0, stream>>>(vecp_bf, wp_bf, phrase_b, out_phr);
  k_labels<<<dim3(32), 256, 0, stream>>>(lab, out_lw, out_lp);
}

// Round 14
// 1520.045 us; speedup vs baseline: 3.2610x; 1.0006x over previous
//
#include <hip/hip_runtime.h>
#include <math.h>

// Problem constants
#define NB 64      // batch
#define NS 128     // seq len
#define ND 1024    // input dim
#define NH 512     // hidden
#define NG 2048    // 4*H
#define NTOT 255   // 2S-1
#define NSTEPS 127 // S-1
#define NWV 511
#define NPV 152

static const size_t XPB_SZ = (size_t)2 * NS * NG * NB;
static const size_t H_SZ   = (size_t)2 * NS * NH * NB;   // region reused: vecp_bf + wp_bf
static const size_t VEC_SZ = (size_t)NB * NTOT * NH;
static const size_t HB_SZ  = (size_t)2 * NS * NH * NB;
static const size_t EB_SZ  = (size_t)NB * NS * ND;
static const size_t WB_SZ  = (size_t)4096 * ND;
static const size_t W12_SZ = (size_t)2 * NH * NH;        // 524288
static const size_t WO_SZ  = (size_t)512 * NH;           // 262144 (511 rows + pad)
static const size_t VB_SZ  = (size_t)NB * NS * NH;       // 4194304
static const size_t VP_SZ  = (size_t)8192 * NH;          // 4194304 (8128 + pad)
static const size_t WP_SZ  = (size_t)256 * NH;           // 131072 (152 + pad)
// flag-array barrier: [t<127][dir<2][cb<32] x 32-int (128B) padding
#define BAR_TOT (127 * 2 * 32 * 32)

typedef __attribute__((ext_vector_type(8))) short short8v;
typedef __attribute__((ext_vector_type(8))) unsigned short ushort8v;
typedef __attribute__((ext_vector_type(4))) float float4v;

__device__ __forceinline__ float sigm(float x) { return 1.f / (1.f + __expf(-x)); }
__device__ __forceinline__ float tanh_fast(float x) {
  const float e = __expf(2.f * x);
  return 1.f - 2.f / (e + 1.f);
}
__device__ __forceinline__ unsigned short f2bf(float x) {
  unsigned b = __float_as_uint(x);
  return (unsigned short)((b + 0x7FFFu + ((b >> 16) & 1u)) >> 16);
}
__device__ __forceinline__ float bf2f(unsigned short u) {
  return __uint_as_float(((unsigned)u) << 16);
}

#define FMA4x4(acc, av, bv)                                                    \
  acc[0][0] += av.x * bv.x; acc[0][1] += av.x * bv.y;                          \
  acc[0][2] += av.x * bv.z; acc[0][3] += av.x * bv.w;                          \
  acc[1][0] += av.y * bv.x; acc[1][1] += av.y * bv.y;                          \
  acc[1][2] += av.y * bv.z; acc[1][3] += av.y * bv.w;                          \
  acc[2][0] += av.z * bv.x; acc[2][1] += av.z * bv.y;                          \
  acc[2][2] += av.z * bv.z; acc[2][3] += av.z * bv.w;                          \
  acc[3][0] += av.w * bv.x; acc[3][1] += av.w * bv.y;                          \
  acc[3][2] += av.w * bv.z; acc[3][3] += av.w * bv.w;

// ---------------- K0: fp32 -> bf16 conversions + barrier zero -------------
__global__ __launch_bounds__(256) void k_cvt(
    const float* __restrict__ elmo, const float* __restrict__ wf,
    const float* __restrict__ wb, const float* __restrict__ W1,
    const float* __restrict__ W2, const float* __restrict__ wordW,
    const float* __restrict__ phraseW,
    unsigned short* __restrict__ elmo_bf, unsigned short* __restrict__ W_bf,
    unsigned short* __restrict__ W12_bf, unsigned short* __restrict__ wout_bf,
    unsigned short* __restrict__ wp_bf, int* __restrict__ bar) {
  const int gid = blockIdx.x * 256 + threadIdx.x;
  if (gid < BAR_TOT) bar[gid] = 0;
  const int NE4 = (NB * NS * ND) / 4;   // 2,097,152
  const int NW4 = (4096 * ND) / 4;      // 1,048,576
  const int NW4h = NW4 / 2;
  const int N12 = (int)(W12_SZ / 4);    // 131,072
  const int NWO = (int)(WO_SZ / 4);     // 65,536
  const int NWO_real = (NWV * NH) / 4;  // 65,408
  const int NP4 = (int)(WP_SZ / 4);     // 32,768
  const int NP4_real = (NPV * NH) / 4;  // 19,456
  const int TOT = NE4 + NW4 + N12 + NWO + NP4;
  for (int i = gid; i < TOT; i += gridDim.x * 256) {
    float4 v = make_float4(0.f, 0.f, 0.f, 0.f);
    unsigned short* dst;
    if (i < NE4) {
      const int e0 = i << 2;
      const int b = e0 >> 17;
      const int t = (e0 >> 10) & 127;
      const int k = e0 & 1023;
      v = *(const float4*)(elmo + e0);
      dst = elmo_bf + ((size_t)((t << 6) + b) << 10) + k;
    } else if (i < NE4 + NW4) {
      const int j = i - NE4;
      v = (j < NW4h) ? *(const float4*)(wf + ((size_t)j << 2))
                     : *(const float4*)(wb + ((size_t)(j - NW4h) << 2));
      dst = W_bf + ((size_t)j << 2);
    } else if (i < NE4 + NW4 + N12) {
      const int j = i - NE4 - NW4;
      const int half = N12 / 2;
      v = (j < half) ? *(const float4*)(W1 + ((size_t)j << 2))
                     : *(const float4*)(W2 + ((size_t)(j - half) << 2));
      dst = W12_bf + ((size_t)j << 2);
    } else if (i < NE4 + NW4 + N12 + NWO) {
      const int j = i - NE4 - NW4 - N12;
      if (j < NWO_real) v = *(const float4*)(wordW + ((size_t)j << 2));
      dst = wout_bf + ((size_t)j << 2);
    } else {
      const int j = i - NE4 - NW4 - N12 - NWO;
      if (j < NP4_real) v = *(const float4*)(phraseW + ((size_t)j << 2));
      dst = wp_bf + ((size_t)j << 2);
    }
    uint2 u;
    u.x = (unsigned)f2bf(v.x) | ((unsigned)f2bf(v.y) << 16);
    u.y = (unsigned)f2bf(v.z) | ((unsigned)f2bf(v.w) << 16);
    *(uint2*)dst = u;
  }
}

// ---------------- K1: xp = elmo @ w_ih^T + bias (bf16 MFMA) ---------------
__global__ __launch_bounds__(256) void k_xp(
    const unsigned short* __restrict__ elmo_bf,
    const unsigned short* __restrict__ W_bf,
    const float* __restrict__ biasf, const float* __restrict__ biasb,
    unsigned short* __restrict__ xpb) {
  __shared__ unsigned short As[128 * 64];
  __shared__ unsigned short Bs[128 * 64];
  const int tid = threadIdx.x;
  const int n0 = blockIdx.x * 128;
  const int m0 = blockIdx.y * 128;
  const int wv = tid >> 6, lane = tid & 63;
  const int cl = lane & 15, bq = lane >> 4;
  const int wm = (wv >> 1) << 6;
  const int wn = (wv & 1) << 6;
  const int sr = tid >> 1, skc = (tid & 1) << 5;
  const unsigned short* asrc = elmo_bf + (size_t)(m0 + sr) * ND + skc;
  const unsigned short* bsrc = W_bf + (size_t)(n0 + sr) * ND + skc;
  const int sswz = (sr & 15) << 3;
  float4v acc[4][4];
#pragma unroll
  for (int nt = 0; nt < 4; ++nt) {
    const int n = n0 + wn + nt * 16 + cl;
    const float bv = (n < 2048) ? biasf[n] : biasb[n - 2048];
#pragma unroll
    for (int mt = 0; mt < 4; ++mt) acc[mt][nt] = (float4v){bv, bv, bv, bv};
  }
  for (int k0 = 0; k0 < ND; k0 += 64) {
    ushort8v av4[4], bv4[4];
#pragma unroll
    for (int i = 0; i < 4; ++i) av4[i] = *(const ushort8v*)(asrc + k0 + 8 * i);
#pragma unroll
    for (int i = 0; i < 4; ++i) bv4[i] = *(const ushort8v*)(bsrc + k0 + 8 * i);
    __syncthreads();
#pragma unroll
    for (int i = 0; i < 4; ++i) {
      *(ushort8v*)&As[((sr << 6) + skc + 8 * i) ^ sswz] = av4[i];
      *(ushort8v*)&Bs[((sr << 6) + skc + 8 * i) ^ sswz] = bv4[i];
    }
    __syncthreads();
#pragma unroll
    for (int ks = 0; ks < 2; ++ks) {
      const int koff = (ks << 5) + (bq << 3);
      short8v af[4], bf_[4];
#pragma unroll
      for (int mt = 0; mt < 4; ++mt) {
        const int ar = wm + mt * 16 + cl;
        af[mt] = *(const short8v*)&As[((ar << 6) + koff) ^ ((ar & 15) << 3)];
      }
#pragma unroll
      for (int nt = 0; nt < 4; ++nt) {
        const int br = wn + nt * 16 + cl;
        bf_[nt] = *(const short8v*)&Bs[((br << 6) + koff) ^ ((br & 15) << 3)];
      }
#pragma unroll
      for (int mt = 0; mt < 4; ++mt)
#pragma unroll
        for (int nt = 0; nt < 4; ++nt)
          acc[mt][nt] =
              __builtin_amdgcn_mfma_f32_16x16x32_bf16(af[mt], bf_[nt], acc[mt][nt], 0, 0, 0);
    }
  }
#pragma unroll
  for (int mt = 0; mt < 4; ++mt) {
    const int mbase = m0 + wm + mt * 16 + (bq << 2);
    const int t = mbase >> 6, b4 = mbase & 63;
#pragma unroll
    for (int nt = 0; nt < 4; ++nt) {
      const int n = n0 + wn + nt * 16 + cl;
      const int dir = n >> 11, grow = n & 2047;
      const int g = grow >> 9, cb = (grow & 511) >> 4;
      const float4v a = acc[mt][nt];
      uint2 u;
      u.x = (unsigned)f2bf(a[0]) | ((unsigned)f2bf(a[1]) << 16);
      u.y = (unsigned)f2bf(a[2]) | ((unsigned)f2bf(a[3]) << 16);
      const size_t idx =
          ((((size_t)(dir * NS + t) * 32 + cb) * 4 + g) << 10) + (cl << 6) + b4;
      *(uint2*)&xpb[idx] = u;
    }
  }
}

// ---------------- K2: persistent BiLSTM scan, v10 -------------------------
// v9 with the single-counter barrier replaced by a FLAG-ARRAY barrier:
// each block stores 1 to its own 128B-padded flag (no RMW serialization);
// wave 0 polls all 32 flags with ONE wave64 load per iteration (parallel
// L3 round trip) until __all(flag).
__global__ __launch_bounds__(256) void k_lstm(
    const float* __restrict__ whh_f, const float* __restrict__ whh_b,
    const unsigned short* __restrict__ xpb,
    unsigned short* __restrict__ h_bf, int* __restrict__ bar) {
  __shared__ unsigned short WS[64 * 512];   // 64 KB, swizzled [gr][k]
  __shared__ unsigned short hOut[64 * 16];  // 2 KB bounce [b][col_local]
  const int bid = blockIdx.x;
  const int dir = bid >> 5;
  const int cb = bid & 31;
  const int col0 = cb << 4;
  const int tid = threadIdx.x;
  const int lane = tid & 63;
  const int w = tid >> 6;
  const int cl = lane & 15, bq = lane >> 4;
  const int b4 = (w << 4) + (bq << 2);
  const int arow = (w << 4) + cl;
  const float* whh = dir ? whh_b : whh_f;

  {
    const int gr = tid >> 2;
    const int kc = (tid & 3) << 7;
    const int gg = gr >> 4, cc = gr & 15;
    const float* src = whh + (size_t)(gg * NH + col0 + cc) * NH + kc;
    const int swz = (gr & 15) << 3;
#pragma unroll
    for (int i = 0; i < 16; ++i) {
      const float4 f0 = *(const float4*)(src + 8 * i);
      const float4 f1 = *(const float4*)(src + 8 * i + 4);
      ushort8v u;
      u[0] = f2bf(f0.x); u[1] = f2bf(f0.y); u[2] = f2bf(f0.z); u[3] = f2bf(f0.w);
      u[4] = f2bf(f1.x); u[5] = f2bf(f1.y); u[6] = f2bf(f1.z); u[7] = f2bf(f1.w);
      *(ushort8v*)&WS[((gr << 9) + kc + 8 * i) ^ swz] = u;
    }
  }
  __syncthreads();

  unsigned short* hb_us = h_bf + ((size_t)dir * NS << 15);      // [pos][b][k]
  unsigned long long* hb_ull = (unsigned long long*)h_bf + ((size_t)dir * NS << 12);

  float4v c4 = {0.f, 0.f, 0.f, 0.f};

  uint2 xg0, xg1, xg2, xg3;
  {
    const int pos0 = dir ? (NS - 1) : 0;
    const unsigned short* xc = xpb + (((size_t)(dir * NS + pos0) * 32 + cb) << 12);
    xg0 = *(const uint2*)&xc[(0 << 10) + (cl << 6) + b4];
    xg1 = *(const uint2*)&xc[(1 << 10) + (cl << 6) + b4];
    xg2 = *(const uint2*)&xc[(2 << 10) + (cl << 6) + b4];
    xg3 = *(const uint2*)&xc[(3 << 10) + (cl << 6) + b4];
  }

  for (int t = 0; t < NS; ++t) {
    const int pos = dir ? (NS - 1 - t) : t;
    float4v acc[4] = {{0.f, 0.f, 0.f, 0.f}, {0.f, 0.f, 0.f, 0.f},
                      {0.f, 0.f, 0.f, 0.f}, {0.f, 0.f, 0.f, 0.f}};
    if (t > 0) {
      const int prevpos = dir ? (pos + 1) : (pos - 1);
      const unsigned long long* hsrc = hb_ull + ((size_t)prevpos << 13);
      unsigned long long ha0[16], ha1[16];
#pragma unroll
      for (int ks = 0; ks < 16; ++ks) {
        const int uidx = (arow << 7) + (ks << 3) + (bq << 1);
        ha0[ks] = __hip_atomic_load(&hsrc[uidx], __ATOMIC_RELAXED,
                                    __HIP_MEMORY_SCOPE_AGENT);
        ha1[ks] = __hip_atomic_load(&hsrc[uidx + 1], __ATOMIC_RELAXED,
                                    __HIP_MEMORY_SCOPE_AGENT);
      }
#pragma unroll
      for (int ks = 0; ks < 16; ++ks) {
        union { unsigned long long u[2]; short8v v; } au;
        au.u[0] = ha0[ks]; au.u[1] = ha1[ks];
        const short8v a = au.v;
        const int koff = (ks << 5) + (bq << 3);
#pragma unroll
        for (int g = 0; g < 4; ++g) {
          const short8v bb =
              *(const short8v*)&WS[((((g << 4) + cl) << 9) + koff) ^ (cl << 3)];
          acc[g] = __builtin_amdgcn_mfma_f32_16x16x32_bf16(a, bb, acc[g], 0, 0, 0);
        }
      }
    }
    float hv[4];
#pragma unroll
    for (int i = 0; i < 4; ++i) {
      const unsigned xw0 = (i < 2) ? xg0.x : xg0.y;
      const unsigned xw1 = (i < 2) ? xg1.x : xg1.y;
      const unsigned xw2 = (i < 2) ? xg2.x : xg2.y;
      const unsigned xw3 = (i < 2) ? xg3.x : xg3.y;
      const int sh = (i & 1) << 4;
      const float gi = sigm(acc[0][i] + bf2f((unsigned short)(xw0 >> sh)));
      const float gf = sigm(acc[1][i] + bf2f((unsigned short)(xw1 >> sh)));
      const float gc = tanh_fast(acc[2][i] + bf2f((unsigned short)(xw2 >> sh)));
      const float go = sigm(acc[3][i] + bf2f((unsigned short)(xw3 >> sh)));
      c4[i] = gf * c4[i] + gi * gc;
      hv[i] = go * tanh_fast(c4[i]);
    }
#pragma unroll
    for (int i = 0; i < 4; ++i) hOut[((b4 + i) << 4) + cl] = f2bf(hv[i]);
    if (t < NS - 1) {
      const int npos = dir ? (pos - 1) : (pos + 1);
      const unsigned short* xc =
          xpb + (((size_t)(dir * NS + npos) * 32 + cb) << 12);
      const uint2 nx0 = *(const uint2*)&xc[(0 << 10) + (cl << 6) + b4];
      const uint2 nx1 = *(const uint2*)&xc[(1 << 10) + (cl << 6) + b4];
      const uint2 nx2 = *(const uint2*)&xc[(2 << 10) + (cl << 6) + b4];
      const uint2 nx3 = *(const uint2*)&xc[(3 << 10) + (cl << 6) + b4];
      __syncthreads();  // hOut visible
      if (tid < 128) {
        const int bb = tid >> 1, half = tid & 1;
        const unsigned long long v =
            *(const unsigned long long*)&hOut[(bb << 4) + (half << 3)];
        __hip_atomic_store(
            (unsigned long long*)&hb_us[((size_t)pos << 15) + (bb << 9) + col0 +
                                        (half << 3)],
            v, __ATOMIC_RELAXED, __HIP_MEMORY_SCOPE_AGENT);
      }
      __syncthreads();  // drains h stores before the flag (release ordering)
      const int fbase = (((t << 1) + dir) << 5);
      if (tid == 0) {
        __hip_atomic_store(&bar[(size_t)(fbase + cb) << 5], 1,
                           __ATOMIC_RELAXED, __HIP_MEMORY_SCOPE_AGENT);
      }
      if (tid < 64) {
        const size_t fl = (size_t)(fbase + (lane & 31)) << 5;
        while (true) {
          int v = 1;
          if (lane < 32)
            v = __hip_atomic_load(&bar[fl], __ATOMIC_RELAXED,
                                  __HIP_MEMORY_SCOPE_AGENT);
          if (__all(v != 0)) break;
        }
      }
      __syncthreads();
      xg0 = nx0; xg1 = nx1; xg2 = nx2; xg3 = nx3;
    } else {
      __syncthreads();  // hOut visible
      if (tid < 128) {
        const int bb = tid >> 1, half = tid & 1;
        const unsigned long long v =
            *(const unsigned long long*)&hOut[(bb << 4) + (half << 3)];
        __hip_atomic_store(
            (unsigned long long*)&hb_us[((size_t)pos << 15) + (bb << 9) + col0 +
                                        (half << 3)],
            v, __ATOMIC_RELAXED, __HIP_MEMORY_SCOPE_AGENT);
      }
    }
  }
}

// ---------------- K3: combined = lrelu(fwd@W1^T + bwd@W2^T), bf16 MFMA ----
__global__ __launch_bounds__(256) void k_comb(
    const unsigned short* __restrict__ h_bf,
    const unsigned short* __restrict__ W12_bf, float* __restrict__ vec) {
  __shared__ unsigned short A1s[64 * 128], A2s[64 * 128];
  __shared__ unsigned short B1s[64 * 128], B2s[64 * 128];
  const int tid = threadIdx.x;
  const int n0 = blockIdx.x * 64;
  const int s = blockIdx.y;
  const int w = tid >> 6, lane = tid & 63;
  const int cl = lane & 15, bq = lane >> 4;
  const int wn = w << 4;
  const unsigned short* a1src = h_bf + ((size_t)s << 15);
  const unsigned short* a2src = h_bf + ((size_t)(NS + s) << 15);
  const unsigned short* b1src = W12_bf + (size_t)n0 * NH;
  const unsigned short* b2src = W12_bf + (size_t)(NH + n0) * NH;
  const int srow = tid >> 2, skq = (tid & 3) << 5;
  const int sswz = (srow & 15) << 3;
  float4v acc[4] = {{0.f, 0.f, 0.f, 0.f}, {0.f, 0.f, 0.f, 0.f},
                    {0.f, 0.f, 0.f, 0.f}, {0.f, 0.f, 0.f, 0.f}};
  for (int k0 = 0; k0 < NH; k0 += 128) {
    ushort8v a1[4], a2[4], b1[4], b2[4];
#pragma unroll
    for (int i = 0; i < 4; ++i) {
      const size_t off = (size_t)srow * NH + k0 + skq + 8 * i;
      a1[i] = *(const ushort8v*)(a1src + off);
      a2[i] = *(const ushort8v*)(a2src + off);
      b1[i] = *(const ushort8v*)(b1src + off);
      b2[i] = *(const ushort8v*)(b2src + off);
    }
    __syncthreads();
#pragma unroll
    for (int i = 0; i < 4; ++i) {
      const int idx = ((srow << 7) + skq + 8 * i) ^ sswz;
      *(ushort8v*)&A1s[idx] = a1[i];
      *(ushort8v*)&A2s[idx] = a2[i];
      *(ushort8v*)&B1s[idx] = b1[i];
      *(ushort8v*)&B2s[idx] = b2[i];
    }
    __syncthreads();
#pragma unroll
    for (int ks = 0; ks < 4; ++ks) {
      const int koff = (ks << 5) + (bq << 3);
      const short8v bf1 =
          *(const short8v*)&B1s[(((wn + cl) << 7) + koff) ^ (cl << 3)];
      const short8v bf2 =
          *(const short8v*)&B2s[(((wn + cl) << 7) + koff) ^ (cl << 3)];
#pragma unroll
      for (int mt = 0; mt < 4; ++mt) {
        const int ar = mt * 16 + cl;
        const short8v af1 = *(const short8v*)&A1s[((ar << 7) + koff) ^ (cl << 3)];
        const short8v af2 = *(const short8v*)&A2s[((ar << 7) + koff) ^ (cl << 3)];
        acc[mt] = __builtin_amdgcn_mfma_f32_16x16x32_bf16(af1, bf1, acc[mt], 0, 0, 0);
        acc[mt] = __builtin_amdgcn_mfma_f32_16x16x32_bf16(af2, bf2, acc[mt], 0, 0, 0);
      }
    }
  }
  const int n = n0 + wn + cl;
#pragma unroll
  for (int mt = 0; mt < 4; ++mt) {
    const int b0 = mt * 16 + (bq << 2);
#pragma unroll
    for (int i = 0; i < 4; ++i) {
      float v = acc[mt][i];
      v = v > 0.f ? v : 0.01f * v;
      vec[((size_t)(b0 + i) * NTOT + s) * NH + n] = v;
    }
  }
}

// ---------------- K4: l2-normalize word rows; emit fp32 + bf16 ------------
__global__ __launch_bounds__(256) void k_norm(float* __restrict__ vec,
                                              unsigned short* __restrict__ vec_bf) {
  const int row = (blockIdx.x << 2) + (threadIdx.x >> 6);  // 0..8191
  const int lane = threadIdx.x & 63;
  const int b = row >> 7, s = row & 127;
  float* p = vec + ((size_t)b * NTOT + s) * NH;
  float4 v0 = *(float4*)(p + (lane << 3));
  float4 v1 = *(float4*)(p + (lane << 3) + 4);
  float ss = v0.x * v0.x + v0.y * v0.y + v0.z * v0.z + v0.w * v0.w +
             v1.x * v1.x + v1.y * v1.y + v1.z * v1.z + v1.w * v1.w;
#pragma unroll
  for (int off = 32; off; off >>= 1) ss += __shfl_down(ss, off);
  ss = __shfl(ss, 0);
  const float sc = 1.f / fmaxf(sqrtf(ss), 1e-12f);
  v0.x *= sc; v0.y *= sc; v0.z *= sc; v0.w *= sc;
  v1.x *= sc; v1.y *= sc; v1.z *= sc; v1.w *= sc;
  *(float4*)(p + (lane << 3)) = v0;
  *(float4*)(p + (lane << 3) + 4) = v1;
  ushort8v u;
  u[0] = f2bf(v0.x); u[1] = f2bf(v0.y); u[2] = f2bf(v0.z); u[3] = f2bf(v0.w);
  u[4] = f2bf(v1.x); u[5] = f2bf(v1.y); u[6] = f2bf(v1.z); u[7] = f2bf(v1.w);
  *(ushort8v*)&vec_bf[((size_t)row << 9) + (lane << 3)] = u;
}

// ---------------- K5: per-batch tree composition scan, v3 -----------------
#define SKW(f) ((f) + (((f) >> 5) << 2))
__global__ __launch_bounds__(512) void k_compose(
    float* __restrict__ vec, const int* __restrict__ cinfo,
    unsigned short* __restrict__ vecp_bf) {
  __shared__ float lv[512];
  __shared__ float rvd[1152];
  __shared__ float cpart[8 * 576];
  __shared__ float red[8];
  __shared__ int ciS[NSTEPS * 4];
  const int b = blockIdx.x;
  const int tid = threadIdx.x;
  float* vb = vec + (size_t)b * NTOT * NH;
  const int* ib = cinfo + b * NSTEPS * 4;
  for (int idx = tid; idx < NSTEPS * 4; idx += 512) ciS[idx] = ib[idx];
  const int jq = tid >> 6;
  const int jb = jq << 6;
  const int k8 = (tid & 63) << 3;
  const int wid = tid >> 6, lane = tid & 63;
  __syncthreads();
  int p = ciS[1];
  float lvv = vb[(size_t)ciS[2] * NH + tid];
  float rvv = vb[(size_t)ciS[3] * NH + tid];
  for (int i = 0; i < NSTEPS; ++i) {
    lv[tid] = lvv;
    rvd[SKW(tid)] = rvv;
    rvd[SKW(512 + tid)] = rvv;
    __syncthreads();
    float acc[8] = {};
#pragma unroll 4
    for (int jj = 0; jj < 64; jj += 4) {
      const int j = jb + jj;
      const float4 l4 = *(const float4*)&lv[j];
      const int f0 = j + k8;
      const float4 r0 = *(const float4*)&rvd[SKW(f0)];
      const float4 r1 = *(const float4*)&rvd[SKW(f0 + 4)];
      const float4 r2 = *(const float4*)&rvd[SKW(f0 + 8)];
      const float rw[12] = {r0.x, r0.y, r0.z, r0.w, r1.x, r1.y,
                            r1.z, r1.w, r2.x, r2.y, r2.z, r2.w};
#pragma unroll
      for (int kk = 0; kk < 8; ++kk)
        acc[kk] += l4.x * rw[kk] + l4.y * rw[kk + 1] + l4.z * rw[kk + 2] +
                   l4.w * rw[kk + 3];
    }
    const int ca = jq * 576 + SKW(k8);
    *(float4*)&cpart[ca] = make_float4(acc[0], acc[1], acc[2], acc[3]);
    *(float4*)&cpart[ca + 4] = make_float4(acc[4], acc[5], acc[6], acc[7]);
    __syncthreads();
    int pn = 0, ln = 0, rn = 0;
    float lf = 0.f, rf = 0.f;
    const bool more = (i + 1 < NSTEPS);
    if (more) {
      pn = ciS[(i + 1) * 4 + 1];
      ln = ciS[(i + 1) * 4 + 2];
      rn = ciS[(i + 1) * 4 + 3];
      lf = vb[(size_t)ln * NH + tid];
      rf = vb[(size_t)rn * NH + tid];
    }
    float ck = 0.f;
    const int ra = SKW(tid);
#pragma unroll
    for (int q = 0; q < 8; ++q) ck += cpart[q * 576 + ra];
    float ss = ck * ck;
#pragma unroll
    for (int off = 32; off; off >>= 1) ss += __shfl_xor(ss, off);
    if (lane == 0) red[wid] = ss;
    __syncthreads();
    const float tot = red[0] + red[1] + red[2] + red[3] +
                      red[4] + red[5] + red[6] + red[7];
    const float inv = 1.f / fmaxf(sqrtf(tot), 1e-12f);
    const float written = ck * inv;
    vb[(size_t)p * NH + tid] = written;
    vecp_bf[((size_t)b * 127 + (p - NS)) * NH + tid] = f2bf(written);
    if (more) {
      lvv = (ln == p) ? written : lf;
      rvv = (rn == p) ? written : rf;
      p = pn;
    }
    __syncthreads();
  }
}

// ---------------- K6a: word output GEMM, bf16 MFMA ------------------------
__global__ __launch_bounds__(256) void k_outw(
    const unsigned short* __restrict__ vec_bf,
    const unsigned short* __restrict__ wout_bf,
    const float* __restrict__ bias, float* __restrict__ out) {
  __shared__ unsigned short As[128 * 64];
  __shared__ unsigned short Bs[128 * 64];
  const int tid = threadIdx.x;
  const int n0 = blockIdx.x * 128;
  const int m0 = blockIdx.y * 128;
  const int wv = tid >> 6, lane = tid & 63;
  const int cl = lane & 15, bq = lane >> 4;
  const int wm = (wv >> 1) << 6;
  const int wn = (wv & 1) << 6;
  const int sr = tid >> 1, skc = (tid & 1) << 5;
  const unsigned short* asrc = vec_bf + (size_t)(m0 + sr) * NH + skc;
  const unsigned short* bsrc = wout_bf + (size_t)(n0 + sr) * NH + skc;
  const int sswz = (sr & 15) << 3;
  float4v acc[4][4] = {};
  for (int k0 = 0; k0 < NH; k0 += 64) {
    ushort8v av4[4], bv4[4];
#pragma unroll
    for (int i = 0; i < 4; ++i) av4[i] = *(const ushort8v*)(asrc + k0 + 8 * i);
#pragma unroll
    for (int i = 0; i < 4; ++i) bv4[i] = *(const ushort8v*)(bsrc + k0 + 8 * i);
    __syncthreads();
#pragma unroll
    for (int i = 0; i < 4; ++i) {
      *(ushort8v*)&As[((sr << 6) + skc + 8 * i) ^ sswz] = av4[i];
      *(ushort8v*)&Bs[((sr << 6) + skc + 8 * i) ^ sswz] = bv4[i];
    }
    __syncthreads();
#pragma unroll
    for (int ks = 0; ks < 2; ++ks) {
      const int koff = (ks << 5) + (bq << 3);
      short8v af[4], bf_[4];
#pragma unroll
      for (int mt = 0; mt < 4; ++mt) {
        const int ar = wm + mt * 16 + cl;
        af[mt] = *(const short8v*)&As[((ar << 6) + koff) ^ ((ar & 15) << 3)];
      }
#pragma unroll
      for (int nt = 0; nt < 4; ++nt) {
        const int br = wn + nt * 16 + cl;
        bf_[nt] = *(const short8v*)&Bs[((br << 6) + koff) ^ ((br & 15) << 3)];
      }
#pragma unroll
      for (int mt = 0; mt < 4; ++mt)
#pragma unroll
        for (int nt = 0; nt < 4; ++nt)
          acc[mt][nt] =
              __builtin_amdgcn_mfma_f32_16x16x32_bf16(af[mt], bf_[nt], acc[mt][nt], 0, 0, 0);
    }
  }
#pragma unroll
  for (int mt = 0; mt < 4; ++mt) {
    const int mb = m0 + wm + mt * 16 + (bq << 2);
#pragma unroll
    for (int nt = 0; nt < 4; ++nt) {
      const int n = n0 + wn + nt * 16 + cl;
      if (n < NWV) {
        const float bn = bias[n];
#pragma unroll
        for (int i = 0; i < 4; ++i)
          out[(size_t)(mb + i) * NWV + n] = acc[mt][nt][i] + bn;
      }
    }
  }
}

// ---------------- K6b: phrase output GEMM, bf16 MFMA ----------------------
__global__ __launch_bounds__(256) void k_outp(
    const unsigned short* __restrict__ vecp_bf,
    const unsigned short* __restrict__ wp_bf,
    const float* __restrict__ bias, float* __restrict__ out) {
  __shared__ unsigned short As[128 * 64];
  __shared__ unsigned short Bs[128 * 64];
  const int tid = threadIdx.x;
  const int n0 = blockIdx.x * 128;   // 0 or 128
  const int m0 = blockIdx.y * 128;
  const int wv = tid >> 6, lane = tid & 63;
  const int cl = lane & 15, bq = lane >> 4;
  const int wm = (wv >> 1) << 6;
  const int wn = (wv & 1) << 6;
  const int sr = tid >> 1, skc = (tid & 1) << 5;
  const unsigned short* asrc = vecp_bf + (size_t)(m0 + sr) * NH + skc;
  const unsigned short* bsrc = wp_bf + (size_t)(n0 + sr) * NH + skc;
  const int sswz = (sr & 15) << 3;
  float4v acc[4][4] = {};
  for (int k0 = 0; k0 < NH; k0 += 64) {
    ushort8v av4[4], bv4[4];
#pragma unroll
    for (int i = 0; i < 4; ++i) av4[i] = *(const ushort8v*)(asrc + k0 + 8 * i);
#pragma unroll
    for (int i = 0; i < 4; ++i) bv4[i] = *(const ushort8v*)(bsrc + k0 + 8 * i);
    __syncthreads();
#pragma unroll
    for (int i = 0; i < 4; ++i) {
      *(ushort8v*)&As[((sr << 6) + skc + 8 * i) ^ sswz] = av4[i];
      *(ushort8v*)&Bs[((sr << 6) + skc + 8 * i) ^ sswz] = bv4[i];
    }
    __syncthreads();
#pragma unroll
    for (int ks = 0; ks < 2; ++ks) {
      const int koff = (ks << 5) + (bq << 3);
      short8v af[4], bf_[4];
#pragma unroll
      for (int mt = 0; mt < 4; ++mt) {
        const int ar = wm + mt * 16 + cl;
        af[mt] = *(const short8v*)&As[((ar << 6) + koff) ^ ((ar & 15) << 3)];
      }
#pragma unroll
      for (int nt = 0; nt < 4; ++nt) {
        const int br = wn + nt * 16 + cl;
        bf_[nt] = *(const short8v*)&Bs[((br << 6) + koff) ^ ((br & 15) << 3)];
      }
#pragma unroll
      for (int mt = 0; mt < 4; ++mt)
#pragma unroll
        for (int nt = 0; nt < 4; ++nt)
          acc[mt][nt] =
              __builtin_amdgcn_mfma_f32_16x16x32_bf16(af[mt], bf_[nt], acc[mt][nt], 0, 0, 0);
    }
  }
#pragma unroll
  for (int mt = 0; mt < 4; ++mt) {
    const int mb = m0 + wm + mt * 16 + (bq << 2);
#pragma unroll
    for (int nt = 0; nt < 4; ++nt) {
      const int n = n0 + wn + nt * 16 + cl;
      if (n < NPV) {
        const float bn = bias[n];
#pragma unroll
        for (int i = 0; i < 4; ++i)
          if (mb + i < 8128)
            out[(size_t)(mb + i) * NPV + n] = acc[mt][nt][i] + bn;
      }
    }
  }
}

// ---------------- K7: labels (int32 -> f32 copy) --------------------------
__global__ __launch_bounds__(256) void k_labels(
    const int* __restrict__ lab, float* __restrict__ outw,
    float* __restrict__ outp) {
  const int i = blockIdx.x * 256 + threadIdx.x;
  if (i < NB * NS) {
    const int b = i >> 7, s = i & 127;
    outw[i] = (float)lab[b * NTOT + s];
  }
  if (i < NB * NSTEPS) {
    const int b = i / 127;
    outp[i] = (float)lab[b * NTOT + NS + (i - b * 127)];
  }
}

extern "C" void kernel_launch(void* const* d_in, const int* in_sizes, int n_in,
                              void* d_out, int out_size, void* d_ws, size_t ws_size,
                              hipStream_t stream) {
  (void)in_sizes; (void)n_in; (void)out_size; (void)ws_size;
  const float* elmo     = (const float*)d_in[0];
  const float* w_ih_f   = (const float*)d_in[1];
  const float* w_hh_f   = (const float*)d_in[2];
  const float* b_f      = (const float*)d_in[3];
  const float* w_ih_b   = (const float*)d_in[4];
  const float* w_hh_b   = (const float*)d_in[5];
  const float* b_b      = (const float*)d_in[6];
  const float* W1       = (const float*)d_in[7];
  const float* W2       = (const float*)d_in[8];
  const float* word_W   = (const float*)d_in[9];
  const float* word_b   = (const float*)d_in[10];
  const float* phrase_W = (const float*)d_in[11];
  const float* phrase_b = (const float*)d_in[12];
  const int* cinfo      = (const int*)d_in[13];
  const int* lab        = (const int*)d_in[15];

  unsigned short* xpb   = (unsigned short*)d_ws;
  float* h_region       = (float*)(xpb + XPB_SZ);   // reused for vecp_bf/wp_bf
  unsigned short* vecp_bf = (unsigned short*)h_region;
  unsigned short* wp_bf   = vecp_bf + VP_SZ;
  float* vec            = h_region + H_SZ;
  unsigned short* h_bf  = (unsigned short*)(vec + VEC_SZ);
  unsigned short* e_bf  = h_bf + HB_SZ;
  unsigned short* W_bf  = e_bf + EB_SZ;
  unsigned short* W12_bf  = W_bf + WB_SZ;
  unsigned short* wout_bf = W12_bf + W12_SZ;
  unsigned short* vec_bf  = wout_bf + WO_SZ;
  int* bar              = (int*)(vec_bf + VB_SZ);

  float* out_word = (float*)d_out;                       // 8192 x 511
  float* out_phr  = out_word + (size_t)8192 * NWV;       // 8128 x 152
  float* out_lw   = out_phr + (size_t)8128 * NPV;        // 8192
  float* out_lp   = out_lw + 8192;                       // 8128

  k_cvt<<<dim3(2048), 256, 0, stream>>>(elmo, w_ih_f, w_ih_b, W1, W2, word_W,
                                        phrase_W, e_bf, W_bf, W12_bf, wout_bf,
                                        wp_bf, bar);
  k_xp<<<dim3(32, 64), 256, 0, stream>>>(e_bf, W_bf, b_f, b_b, xpb);
  k_lstm<<<dim3(64), 256, 0, stream>>>(w_hh_f, w_hh_b, xpb, h_bf, bar);
  k_comb<<<dim3(8, 128), 256, 0, stream>>>(h_bf, W12_bf, vec);
  k_norm<<<dim3(2048), 256, 0, stream>>>(vec, vec_bf);
  k_compose<<<dim3(64), 512, 0, stream>>>(vec, cinfo, vecp_bf);
  k_outw<<<dim3(4, 64), 256, 0, stream>>>(vec_bf, wout_bf, word_b, out_word);
  k_outp<<<dim3(2, 64), 256, 0, stream>>>(vecp_bf, wp_bf, phrase_b, out_phr);
  k_labels<<<dim3(32), 256, 0, stream>>>(lab, out_lw, out_lp);
}

// Round 15
// 1484.146 us; speedup vs baseline: 3.3399x; 1.0242x over previous
//
#include <hip/hip_runtime.h>
#include <math.h>

// Problem constants
#define NB 64      // batch
#define NS 128     // seq len
#define ND 1024    // input dim
#define NH 512     // hidden
#define NG 2048    // 4*H
#define NTOT 255   // 2S-1
#define NSTEPS 127 // S-1
#define NWV 511
#define NPV 152

static const size_t XPB_SZ = (size_t)2 * NS * NG * NB;
static const size_t H_SZ   = (size_t)2 * NS * NH * NB;   // region reused: vecp_bf + wp_bf
static const size_t VEC_SZ = (size_t)NB * NTOT * NH;
static const size_t HB_SZ  = (size_t)2 * NS * NH * NB;
static const size_t EB_SZ  = (size_t)NB * NS * ND;
static const size_t WB_SZ  = (size_t)4096 * ND;
static const size_t W12_SZ = (size_t)2 * NH * NH;        // 524288
static const size_t WO_SZ  = (size_t)512 * NH;           // 262144 (511 rows + pad)
static const size_t VB_SZ  = (size_t)NB * NS * NH;       // 4194304
static const size_t VP_SZ  = (size_t)8192 * NH;          // 4194304 (8128 + pad)
static const size_t WP_SZ  = (size_t)256 * NH;           // 131072 (152 + pad)
// flag-array barrier: [t<127][dir<2][cb<32] x 32-int (128B) padding
#define BAR_TOT (127 * 2 * 32 * 32)

typedef __attribute__((ext_vector_type(8))) short short8v;
typedef __attribute__((ext_vector_type(8))) unsigned short ushort8v;
typedef __attribute__((ext_vector_type(4))) float float4v;

__device__ __forceinline__ float sigm(float x) { return 1.f / (1.f + __expf(-x)); }
__device__ __forceinline__ float tanh_fast(float x) {
  const float e = __expf(2.f * x);
  return 1.f - 2.f / (e + 1.f);
}
__device__ __forceinline__ unsigned short f2bf(float x) {
  unsigned b = __float_as_uint(x);
  return (unsigned short)((b + 0x7FFFu + ((b >> 16) & 1u)) >> 16);
}
__device__ __forceinline__ float bf2f(unsigned short u) {
  return __uint_as_float(((unsigned)u) << 16);
}

// ---------------- K0: fp32 -> bf16 conversions + barrier zero -------------
__global__ __launch_bounds__(256) void k_cvt(
    const float* __restrict__ elmo, const float* __restrict__ wf,
    const float* __restrict__ wb, const float* __restrict__ W1,
    const float* __restrict__ W2, const float* __restrict__ wordW,
    const float* __restrict__ phraseW,
    unsigned short* __restrict__ elmo_bf, unsigned short* __restrict__ W_bf,
    unsigned short* __restrict__ W12_bf, unsigned short* __restrict__ wout_bf,
    unsigned short* __restrict__ wp_bf, int* __restrict__ bar) {
  const int gid = blockIdx.x * 256 + threadIdx.x;
  if (gid < BAR_TOT) bar[gid] = 0;
  const int NE4 = (NB * NS * ND) / 4;   // 2,097,152
  const int NW4 = (4096 * ND) / 4;      // 1,048,576
  const int NW4h = NW4 / 2;
  const int N12 = (int)(W12_SZ / 4);    // 131,072
  const int NWO = (int)(WO_SZ / 4);     // 65,536
  const int NWO_real = (NWV * NH) / 4;  // 65,408
  const int NP4 = (int)(WP_SZ / 4);     // 32,768
  const int NP4_real = (NPV * NH) / 4;  // 19,456
  const int TOT = NE4 + NW4 + N12 + NWO + NP4;
  for (int i = gid; i < TOT; i += gridDim.x * 256) {
    float4 v = make_float4(0.f, 0.f, 0.f, 0.f);
    unsigned short* dst;
    if (i < NE4) {
      const int e0 = i << 2;
      const int b = e0 >> 17;
      const int t = (e0 >> 10) & 127;
      const int k = e0 & 1023;
      v = *(const float4*)(elmo + e0);
      dst = elmo_bf + ((size_t)((t << 6) + b) << 10) + k;
    } else if (i < NE4 + NW4) {
      const int j = i - NE4;
      v = (j < NW4h) ? *(const float4*)(wf + ((size_t)j << 2))
                     : *(const float4*)(wb + ((size_t)(j - NW4h) << 2));
      dst = W_bf + ((size_t)j << 2);
    } else if (i < NE4 + NW4 + N12) {
      const int j = i - NE4 - NW4;
      const int half = N12 / 2;
      v = (j < half) ? *(const float4*)(W1 + ((size_t)j << 2))
                     : *(const float4*)(W2 + ((size_t)(j - half) << 2));
      dst = W12_bf + ((size_t)j << 2);
    } else if (i < NE4 + NW4 + N12 + NWO) {
      const int j = i - NE4 - NW4 - N12;
      if (j < NWO_real) v = *(const float4*)(wordW + ((size_t)j << 2));
      dst = wout_bf + ((size_t)j << 2);
    } else {
      const int j = i - NE4 - NW4 - N12 - NWO;
      if (j < NP4_real) v = *(const float4*)(phraseW + ((size_t)j << 2));
      dst = wp_bf + ((size_t)j << 2);
    }
    uint2 u;
    u.x = (unsigned)f2bf(v.x) | ((unsigned)f2bf(v.y) << 16);
    u.y = (unsigned)f2bf(v.z) | ((unsigned)f2bf(v.w) << 16);
    *(uint2*)dst = u;
  }
}

// ---------------- K1: xp = elmo @ w_ih^T + bias (bf16 MFMA) ---------------
__global__ __launch_bounds__(256) void k_xp(
    const unsigned short* __restrict__ elmo_bf,
    const unsigned short* __restrict__ W_bf,
    const float* __restrict__ biasf, const float* __restrict__ biasb,
    unsigned short* __restrict__ xpb) {
  __shared__ unsigned short As[128 * 64];
  __shared__ unsigned short Bs[128 * 64];
  const int tid = threadIdx.x;
  const int n0 = blockIdx.x * 128;
  const int m0 = blockIdx.y * 128;
  const int wv = tid >> 6, lane = tid & 63;
  const int cl = lane & 15, bq = lane >> 4;
  const int wm = (wv >> 1) << 6;
  const int wn = (wv & 1) << 6;
  const int sr = tid >> 1, skc = (tid & 1) << 5;
  const unsigned short* asrc = elmo_bf + (size_t)(m0 + sr) * ND + skc;
  const unsigned short* bsrc = W_bf + (size_t)(n0 + sr) * ND + skc;
  const int sswz = (sr & 15) << 3;
  float4v acc[4][4];
#pragma unroll
  for (int nt = 0; nt < 4; ++nt) {
    const int n = n0 + wn + nt * 16 + cl;
    const float bv = (n < 2048) ? biasf[n] : biasb[n - 2048];
#pragma unroll
    for (int mt = 0; mt < 4; ++mt) acc[mt][nt] = (float4v){bv, bv, bv, bv};
  }
  for (int k0 = 0; k0 < ND; k0 += 64) {
    ushort8v av4[4], bv4[4];
#pragma unroll
    for (int i = 0; i < 4; ++i) av4[i] = *(const ushort8v*)(asrc + k0 + 8 * i);
#pragma unroll
    for (int i = 0; i < 4; ++i) bv4[i] = *(const ushort8v*)(bsrc + k0 + 8 * i);
    __syncthreads();
#pragma unroll
    for (int i = 0; i < 4; ++i) {
      *(ushort8v*)&As[((sr << 6) + skc + 8 * i) ^ sswz] = av4[i];
      *(ushort8v*)&Bs[((sr << 6) + skc + 8 * i) ^ sswz] = bv4[i];
    }
    __syncthreads();
#pragma unroll
    for (int ks = 0; ks < 2; ++ks) {
      const int koff = (ks << 5) + (bq << 3);
      short8v af[4], bf_[4];
#pragma unroll
      for (int mt = 0; mt < 4; ++mt) {
        const int ar = wm + mt * 16 + cl;
        af[mt] = *(const short8v*)&As[((ar << 6) + koff) ^ ((ar & 15) << 3)];
      }
#pragma unroll
      for (int nt = 0; nt < 4; ++nt) {
        const int br = wn + nt * 16 + cl;
        bf_[nt] = *(const short8v*)&Bs[((br << 6) + koff) ^ ((br & 15) << 3)];
      }
#pragma unroll
      for (int mt = 0; mt < 4; ++mt)
#pragma unroll
        for (int nt = 0; nt < 4; ++nt)
          acc[mt][nt] =
              __builtin_amdgcn_mfma_f32_16x16x32_bf16(af[mt], bf_[nt], acc[mt][nt], 0, 0, 0);
    }
  }
#pragma unroll
  for (int mt = 0; mt < 4; ++mt) {
    const int mbase = m0 + wm + mt * 16 + (bq << 2);
    const int t = mbase >> 6, b4 = mbase & 63;
#pragma unroll
    for (int nt = 0; nt < 4; ++nt) {
      const int n = n0 + wn + nt * 16 + cl;
      const int dir = n >> 11, grow = n & 2047;
      const int g = grow >> 9, cb = (grow & 511) >> 4;
      const float4v a = acc[mt][nt];
      uint2 u;
      u.x = (unsigned)f2bf(a[0]) | ((unsigned)f2bf(a[1]) << 16);
      u.y = (unsigned)f2bf(a[2]) | ((unsigned)f2bf(a[3]) << 16);
      const size_t idx =
          ((((size_t)(dir * NS + t) * 32 + cb) * 4 + g) << 10) + (cl << 6) + b4;
      *(uint2*)&xpb[idx] = u;
    }
  }
}

// ---------------- K2: persistent BiLSTM scan, v11 -------------------------
// v10 + xp(t+1) prefetch moved AFTER the flag store: the drain sync no
// longer waits for the xp L2-miss loads; their latency hides under the poll.
__global__ __launch_bounds__(256) void k_lstm(
    const float* __restrict__ whh_f, const float* __restrict__ whh_b,
    const unsigned short* __restrict__ xpb,
    unsigned short* __restrict__ h_bf, int* __restrict__ bar) {
  __shared__ unsigned short WS[64 * 512];   // 64 KB, swizzled [gr][k]
  __shared__ unsigned short hOut[64 * 16];  // 2 KB bounce [b][col_local]
  const int bid = blockIdx.x;
  const int dir = bid >> 5;
  const int cb = bid & 31;
  const int col0 = cb << 4;
  const int tid = threadIdx.x;
  const int lane = tid & 63;
  const int w = tid >> 6;
  const int cl = lane & 15, bq = lane >> 4;
  const int b4 = (w << 4) + (bq << 2);
  const int arow = (w << 4) + cl;
  const float* whh = dir ? whh_b : whh_f;

  {
    const int gr = tid >> 2;
    const int kc = (tid & 3) << 7;
    const int gg = gr >> 4, cc = gr & 15;
    const float* src = whh + (size_t)(gg * NH + col0 + cc) * NH + kc;
    const int swz = (gr & 15) << 3;
#pragma unroll
    for (int i = 0; i < 16; ++i) {
      const float4 f0 = *(const float4*)(src + 8 * i);
      const float4 f1 = *(const float4*)(src + 8 * i + 4);
      ushort8v u;
      u[0] = f2bf(f0.x); u[1] = f2bf(f0.y); u[2] = f2bf(f0.z); u[3] = f2bf(f0.w);
      u[4] = f2bf(f1.x); u[5] = f2bf(f1.y); u[6] = f2bf(f1.z); u[7] = f2bf(f1.w);
      *(ushort8v*)&WS[((gr << 9) + kc + 8 * i) ^ swz] = u;
    }
  }
  __syncthreads();

  unsigned short* hb_us = h_bf + ((size_t)dir * NS << 15);      // [pos][b][k]
  unsigned long long* hb_ull = (unsigned long long*)h_bf + ((size_t)dir * NS << 12);

  float4v c4 = {0.f, 0.f, 0.f, 0.f};

  uint2 xg0, xg1, xg2, xg3;
  {
    const int pos0 = dir ? (NS - 1) : 0;
    const unsigned short* xc = xpb + (((size_t)(dir * NS + pos0) * 32 + cb) << 12);
    xg0 = *(const uint2*)&xc[(0 << 10) + (cl << 6) + b4];
    xg1 = *(const uint2*)&xc[(1 << 10) + (cl << 6) + b4];
    xg2 = *(const uint2*)&xc[(2 << 10) + (cl << 6) + b4];
    xg3 = *(const uint2*)&xc[(3 << 10) + (cl << 6) + b4];
  }

  for (int t = 0; t < NS; ++t) {
    const int pos = dir ? (NS - 1 - t) : t;
    float4v acc[4] = {{0.f, 0.f, 0.f, 0.f}, {0.f, 0.f, 0.f, 0.f},
                      {0.f, 0.f, 0.f, 0.f}, {0.f, 0.f, 0.f, 0.f}};
    if (t > 0) {
      const int prevpos = dir ? (pos + 1) : (pos - 1);
      const unsigned long long* hsrc = hb_ull + ((size_t)prevpos << 13);
      unsigned long long ha0[16], ha1[16];
#pragma unroll
      for (int ks = 0; ks < 16; ++ks) {
        const int uidx = (arow << 7) + (ks << 3) + (bq << 1);
        ha0[ks] = __hip_atomic_load(&hsrc[uidx], __ATOMIC_RELAXED,
                                    __HIP_MEMORY_SCOPE_AGENT);
        ha1[ks] = __hip_atomic_load(&hsrc[uidx + 1], __ATOMIC_RELAXED,
                                    __HIP_MEMORY_SCOPE_AGENT);
      }
#pragma unroll
      for (int ks = 0; ks < 16; ++ks) {
        union { unsigned long long u[2]; short8v v; } au;
        au.u[0] = ha0[ks]; au.u[1] = ha1[ks];
        const short8v a = au.v;
        const int koff = (ks << 5) + (bq << 3);
#pragma unroll
        for (int g = 0; g < 4; ++g) {
          const short8v bb =
              *(const short8v*)&WS[((((g << 4) + cl) << 9) + koff) ^ (cl << 3)];
          acc[g] = __builtin_amdgcn_mfma_f32_16x16x32_bf16(a, bb, acc[g], 0, 0, 0);
        }
      }
    }
    float hv[4];
#pragma unroll
    for (int i = 0; i < 4; ++i) {
      const unsigned xw0 = (i < 2) ? xg0.x : xg0.y;
      const unsigned xw1 = (i < 2) ? xg1.x : xg1.y;
      const unsigned xw2 = (i < 2) ? xg2.x : xg2.y;
      const unsigned xw3 = (i < 2) ? xg3.x : xg3.y;
      const int sh = (i & 1) << 4;
      const float gi = sigm(acc[0][i] + bf2f((unsigned short)(xw0 >> sh)));
      const float gf = sigm(acc[1][i] + bf2f((unsigned short)(xw1 >> sh)));
      const float gc = tanh_fast(acc[2][i] + bf2f((unsigned short)(xw2 >> sh)));
      const float go = sigm(acc[3][i] + bf2f((unsigned short)(xw3 >> sh)));
      c4[i] = gf * c4[i] + gi * gc;
      hv[i] = go * tanh_fast(c4[i]);
    }
#pragma unroll
    for (int i = 0; i < 4; ++i) hOut[((b4 + i) << 4) + cl] = f2bf(hv[i]);
    if (t < NS - 1) {
      __syncthreads();  // hOut visible
      if (tid < 128) {
        const int bb = tid >> 1, half = tid & 1;
        const unsigned long long v =
            *(const unsigned long long*)&hOut[(bb << 4) + (half << 3)];
        __hip_atomic_store(
            (unsigned long long*)&hb_us[((size_t)pos << 15) + (bb << 9) + col0 +
                                        (half << 3)],
            v, __ATOMIC_RELAXED, __HIP_MEMORY_SCOPE_AGENT);
      }
      __syncthreads();  // drains ONLY h stores before the flag (release order)
      const int fbase = (((t << 1) + dir) << 5);
      if (tid == 0) {
        __hip_atomic_store(&bar[(size_t)(fbase + cb) << 5], 1,
                           __ATOMIC_RELAXED, __HIP_MEMORY_SCOPE_AGENT);
      }
      // xp(t+1) prefetch issued NOW: latency hides under the poll
      const int npos = dir ? (pos - 1) : (pos + 1);
      const unsigned short* xc =
          xpb + (((size_t)(dir * NS + npos) * 32 + cb) << 12);
      const uint2 nx0 = *(const uint2*)&xc[(0 << 10) + (cl << 6) + b4];
      const uint2 nx1 = *(const uint2*)&xc[(1 << 10) + (cl << 6) + b4];
      const uint2 nx2 = *(const uint2*)&xc[(2 << 10) + (cl << 6) + b4];
      const uint2 nx3 = *(const uint2*)&xc[(3 << 10) + (cl << 6) + b4];
      if (tid < 64) {
        const size_t fl = (size_t)(fbase + (lane & 31)) << 5;
        while (true) {
          int v = 1;
          if (lane < 32)
            v = __hip_atomic_load(&bar[fl], __ATOMIC_RELAXED,
                                  __HIP_MEMORY_SCOPE_AGENT);
          if (__all(v != 0)) break;
        }
      }
      __syncthreads();
      xg0 = nx0; xg1 = nx1; xg2 = nx2; xg3 = nx3;
    } else {
      __syncthreads();  // hOut visible
      if (tid < 128) {
        const int bb = tid >> 1, half = tid & 1;
        const unsigned long long v =
            *(const unsigned long long*)&hOut[(bb << 4) + (half << 3)];
        __hip_atomic_store(
            (unsigned long long*)&hb_us[((size_t)pos << 15) + (bb << 9) + col0 +
                                        (half << 3)],
            v, __ATOMIC_RELAXED, __HIP_MEMORY_SCOPE_AGENT);
      }
    }
  }
}

// ---------------- K3: combined = lrelu(fwd@W1^T + bwd@W2^T), bf16 MFMA ----
__global__ __launch_bounds__(256) void k_comb(
    const unsigned short* __restrict__ h_bf,
    const unsigned short* __restrict__ W12_bf, float* __restrict__ vec) {
  __shared__ unsigned short A1s[64 * 128], A2s[64 * 128];
  __shared__ unsigned short B1s[64 * 128], B2s[64 * 128];
  const int tid = threadIdx.x;
  const int n0 = blockIdx.x * 64;
  const int s = blockIdx.y;
  const int w = tid >> 6, lane = tid & 63;
  const int cl = lane & 15, bq = lane >> 4;
  const int wn = w << 4;
  const unsigned short* a1src = h_bf + ((size_t)s << 15);
  const unsigned short* a2src = h_bf + ((size_t)(NS + s) << 15);
  const unsigned short* b1src = W12_bf + (size_t)n0 * NH;
  const unsigned short* b2src = W12_bf + (size_t)(NH + n0) * NH;
  const int srow = tid >> 2, skq = (tid & 3) << 5;
  const int sswz = (srow & 15) << 3;
  float4v acc[4] = {{0.f, 0.f, 0.f, 0.f}, {0.f, 0.f, 0.f, 0.f},
                    {0.f, 0.f, 0.f, 0.f}, {0.f, 0.f, 0.f, 0.f}};
  for (int k0 = 0; k0 < NH; k0 += 128) {
    ushort8v a1[4], a2[4], b1[4], b2[4];
#pragma unroll
    for (int i = 0; i < 4; ++i) {
      const size_t off = (size_t)srow * NH + k0 + skq + 8 * i;
      a1[i] = *(const ushort8v*)(a1src + off);
      a2[i] = *(const ushort8v*)(a2src + off);
      b1[i] = *(const ushort8v*)(b1src + off);
      b2[i] = *(const ushort8v*)(b2src + off);
    }
    __syncthreads();
#pragma unroll
    for (int i = 0; i < 4; ++i) {
      const int idx = ((srow << 7) + skq + 8 * i) ^ sswz;
      *(ushort8v*)&A1s[idx] = a1[i];
      *(ushort8v*)&A2s[idx] = a2[i];
      *(ushort8v*)&B1s[idx] = b1[i];
      *(ushort8v*)&B2s[idx] = b2[i];
    }
    __syncthreads();
#pragma unroll
    for (int ks = 0; ks < 4; ++ks) {
      const int koff = (ks << 5) + (bq << 3);
      const short8v bf1 =
          *(const short8v*)&B1s[(((wn + cl) << 7) + koff) ^ (cl << 3)];
      const short8v bf2 =
          *(const short8v*)&B2s[(((wn + cl) << 7) + koff) ^ (cl << 3)];
#pragma unroll
      for (int mt = 0; mt < 4; ++mt) {
        const int ar = mt * 16 + cl;
        const short8v af1 = *(const short8v*)&A1s[((ar << 7) + koff) ^ (cl << 3)];
        const short8v af2 = *(const short8v*)&A2s[((ar << 7) + koff) ^ (cl << 3)];
        acc[mt] = __builtin_amdgcn_mfma_f32_16x16x32_bf16(af1, bf1, acc[mt], 0, 0, 0);
        acc[mt] = __builtin_amdgcn_mfma_f32_16x16x32_bf16(af2, bf2, acc[mt], 0, 0, 0);
      }
    }
  }
  const int n = n0 + wn + cl;
#pragma unroll
  for (int mt = 0; mt < 4; ++mt) {
    const int b0 = mt * 16 + (bq << 2);
#pragma unroll
    for (int i = 0; i < 4; ++i) {
      float v = acc[mt][i];
      v = v > 0.f ? v : 0.01f * v;
      vec[((size_t)(b0 + i) * NTOT + s) * NH + n] = v;
    }
  }
}

// ---------------- K4: l2-normalize word rows; emit fp32 + bf16 ------------
__global__ __launch_bounds__(256) void k_norm(float* __restrict__ vec,
                                              unsigned short* __restrict__ vec_bf) {
  const int row = (blockIdx.x << 2) + (threadIdx.x >> 6);  // 0..8191
  const int lane = threadIdx.x & 63;
  const int b = row >> 7, s = row & 127;
  float* p = vec + ((size_t)b * NTOT + s) * NH;
  float4 v0 = *(float4*)(p + (lane << 3));
  float4 v1 = *(float4*)(p + (lane << 3) + 4);
  float ss = v0.x * v0.x + v0.y * v0.y + v0.z * v0.z + v0.w * v0.w +
             v1.x * v1.x + v1.y * v1.y + v1.z * v1.z + v1.w * v1.w;
#pragma unroll
  for (int off = 32; off; off >>= 1) ss += __shfl_down(ss, off);
  ss = __shfl(ss, 0);
  const float sc = 1.f / fmaxf(sqrtf(ss), 1e-12f);
  v0.x *= sc; v0.y *= sc; v0.z *= sc; v0.w *= sc;
  v1.x *= sc; v1.y *= sc; v1.z *= sc; v1.w *= sc;
  *(float4*)(p + (lane << 3)) = v0;
  *(float4*)(p + (lane << 3) + 4) = v1;
  ushort8v u;
  u[0] = f2bf(v0.x); u[1] = f2bf(v0.y); u[2] = f2bf(v0.z); u[3] = f2bf(v0.w);
  u[4] = f2bf(v1.x); u[5] = f2bf(v1.y); u[6] = f2bf(v1.z); u[7] = f2bf(v1.w);
  *(ushort8v*)&vec_bf[((size_t)row << 9) + (lane << 3)] = u;
}

// ---------------- K5: fused tail: compose (64) | word GEMM (256) | labels -
// blocks 0..63: per-batch tree composition scan (v3 logic, 512 thr)
// blocks 64..319: word output GEMM (bf16 MFMA, 512-thread variant)
// blocks 320..335: labels
// compose depends only on k_norm; word GEMM/labels run on otherwise-idle CUs.
#define SKW(f) ((f) + (((f) >> 5) << 2))
__global__ __launch_bounds__(512) void k_tail(
    float* __restrict__ vec, const int* __restrict__ cinfo,
    unsigned short* __restrict__ vecp_bf,
    const unsigned short* __restrict__ vec_bf,
    const unsigned short* __restrict__ wout_bf,
    const float* __restrict__ wbias, float* __restrict__ out_word,
    const int* __restrict__ lab, float* __restrict__ out_lw,
    float* __restrict__ out_lp) {
  __shared__ float lv[512];
  __shared__ float rvd[1152];
  __shared__ float cpart[8 * 576];
  __shared__ float red[8];
  __shared__ int ciS[NSTEPS * 4];
  __shared__ unsigned short As[128 * 64];
  __shared__ unsigned short Bs[128 * 64];
  const int bid = blockIdx.x;
  const int tid = threadIdx.x;

  if (bid < 64) {
    // ---------------- compose ----------------
    const int b = bid;
    float* vb = vec + (size_t)b * NTOT * NH;
    const int* ib = cinfo + b * NSTEPS * 4;
    for (int idx = tid; idx < NSTEPS * 4; idx += 512) ciS[idx] = ib[idx];
    const int jq = tid >> 6;
    const int jb = jq << 6;
    const int k8 = (tid & 63) << 3;
    const int wid = tid >> 6, lane = tid & 63;
    __syncthreads();
    int p = ciS[1];
    float lvv = vb[(size_t)ciS[2] * NH + tid];
    float rvv = vb[(size_t)ciS[3] * NH + tid];
    for (int i = 0; i < NSTEPS; ++i) {
      lv[tid] = lvv;
      rvd[SKW(tid)] = rvv;
      rvd[SKW(512 + tid)] = rvv;
      __syncthreads();
      float acc[8] = {};
#pragma unroll 4
      for (int jj = 0; jj < 64; jj += 4) {
        const int j = jb + jj;
        const float4 l4 = *(const float4*)&lv[j];
        const int f0 = j + k8;
        const float4 r0 = *(const float4*)&rvd[SKW(f0)];
        const float4 r1 = *(const float4*)&rvd[SKW(f0 + 4)];
        const float4 r2 = *(const float4*)&rvd[SKW(f0 + 8)];
        const float rw[12] = {r0.x, r0.y, r0.z, r0.w, r1.x, r1.y,
                              r1.z, r1.w, r2.x, r2.y, r2.z, r2.w};
#pragma unroll
        for (int kk = 0; kk < 8; ++kk)
          acc[kk] += l4.x * rw[kk] + l4.y * rw[kk + 1] + l4.z * rw[kk + 2] +
                     l4.w * rw[kk + 3];
      }
      const int ca = jq * 576 + SKW(k8);
      *(float4*)&cpart[ca] = make_float4(acc[0], acc[1], acc[2], acc[3]);
      *(float4*)&cpart[ca + 4] = make_float4(acc[4], acc[5], acc[6], acc[7]);
      __syncthreads();
      int pn = 0, ln = 0, rn = 0;
      float lf = 0.f, rf = 0.f;
      const bool more = (i + 1 < NSTEPS);
      if (more) {
        pn = ciS[(i + 1) * 4 + 1];
        ln = ciS[(i + 1) * 4 + 2];
        rn = ciS[(i + 1) * 4 + 3];
        lf = vb[(size_t)ln * NH + tid];
        rf = vb[(size_t)rn * NH + tid];
      }
      float ck = 0.f;
      const int ra = SKW(tid);
#pragma unroll
      for (int q = 0; q < 8; ++q) ck += cpart[q * 576 + ra];
      float ss = ck * ck;
#pragma unroll
      for (int off = 32; off; off >>= 1) ss += __shfl_xor(ss, off);
      if (lane == 0) red[wid] = ss;
      __syncthreads();
      const float tot = red[0] + red[1] + red[2] + red[3] +
                        red[4] + red[5] + red[6] + red[7];
      const float inv = 1.f / fmaxf(sqrtf(tot), 1e-12f);
      const float written = ck * inv;
      vb[(size_t)p * NH + tid] = written;
      vecp_bf[((size_t)b * 127 + (p - NS)) * NH + tid] = f2bf(written);
      if (more) {
        lvv = (ln == p) ? written : lf;
        rvv = (rn == p) ? written : rf;
        p = pn;
      }
      __syncthreads();
    }
  } else if (bid < 320) {
    // ---------------- word output GEMM (512-thread) ----------------
    const int obid = bid - 64;
    const int n0 = (obid & 3) * 128;
    const int m0 = (obid >> 2) * 128;
    const int wv = tid >> 6, lane = tid & 63;
    const int cl = lane & 15, bq = lane >> 4;
    const int wm = (wv >> 2) << 6;
    const int wn = ((wv >> 1) & 1) << 6;
    const int mts = (wv & 1) << 1;   // mt base: 0 or 2
    const int sr = tid >> 2, skc = (tid & 3) << 4;   // 128 rows x 4 thr x 16 us
    const unsigned short* asrc = vec_bf + (size_t)(m0 + sr) * NH + skc;
    const unsigned short* bsrc = wout_bf + (size_t)(n0 + sr) * NH + skc;
    const int sswz = (sr & 15) << 3;
    float4v acc[2][4] = {};
    for (int k0 = 0; k0 < NH; k0 += 64) {
      ushort8v av4[2], bv4[2];
#pragma unroll
      for (int i = 0; i < 2; ++i) av4[i] = *(const ushort8v*)(asrc + k0 + 8 * i);
#pragma unroll
      for (int i = 0; i < 2; ++i) bv4[i] = *(const ushort8v*)(bsrc + k0 + 8 * i);
      __syncthreads();
#pragma unroll
      for (int i = 0; i < 2; ++i) {
        *(ushort8v*)&As[((sr << 6) + skc + 8 * i) ^ sswz] = av4[i];
        *(ushort8v*)&Bs[((sr << 6) + skc + 8 * i) ^ sswz] = bv4[i];
      }
      __syncthreads();
#pragma unroll
      for (int ks = 0; ks < 2; ++ks) {
        const int koff = (ks << 5) + (bq << 3);
        short8v af[2], bf_[4];
#pragma unroll
        for (int mtl = 0; mtl < 2; ++mtl) {
          const int ar = wm + (mts + mtl) * 16 + cl;
          af[mtl] = *(const short8v*)&As[((ar << 6) + koff) ^ ((ar & 15) << 3)];
        }
#pragma unroll
        for (int nt = 0; nt < 4; ++nt) {
          const int br = wn + nt * 16 + cl;
          bf_[nt] = *(const short8v*)&Bs[((br << 6) + koff) ^ ((br & 15) << 3)];
        }
#pragma unroll
        for (int mtl = 0; mtl < 2; ++mtl)
#pragma unroll
          for (int nt = 0; nt < 4; ++nt)
            acc[mtl][nt] = __builtin_amdgcn_mfma_f32_16x16x32_bf16(
                af[mtl], bf_[nt], acc[mtl][nt], 0, 0, 0);
      }
    }
#pragma unroll
    for (int mtl = 0; mtl < 2; ++mtl) {
      const int mb = m0 + wm + (mts + mtl) * 16 + (bq << 2);
#pragma unroll
      for (int nt = 0; nt < 4; ++nt) {
        const int n = n0 + wn + nt * 16 + cl;
        if (n < NWV) {
          const float bn = wbias[n];
#pragma unroll
          for (int i = 0; i < 4; ++i)
            out_word[(size_t)(mb + i) * NWV + n] = acc[mtl][nt][i] + bn;
        }
      }
    }
  } else {
    // ---------------- labels ----------------
    const int i = (bid - 320) * 512 + tid;
    if (i < NB * NS) {
      const int b = i >> 7, s = i & 127;
      out_lw[i] = (float)lab[b * NTOT + s];
    }
    if (i < NB * NSTEPS) {
      const int b = i / 127;
      out_lp[i] = (float)lab[b * NTOT + NS + (i - b * 127)];
    }
  }
}

// ---------------- K6b: phrase output GEMM, bf16 MFMA ----------------------
__global__ __launch_bounds__(256) void k_outp(
    const unsigned short* __restrict__ vecp_bf,
    const unsigned short* __restrict__ wp_bf,
    const float* __restrict__ bias, float* __restrict__ out) {
  __shared__ unsigned short As[128 * 64];
  __shared__ unsigned short Bs[128 * 64];
  const int tid = threadIdx.x;
  const int n0 = blockIdx.x * 128;   // 0 or 128
  const int m0 = blockIdx.y * 128;
  const int wv = tid >> 6, lane = tid & 63;
  const int cl = lane & 15, bq = lane >> 4;
  const int wm = (wv >> 1) << 6;
  const int wn = (wv & 1) << 6;
  const int sr = tid >> 1, skc = (tid & 1) << 5;
  const unsigned short* asrc = vecp_bf + (size_t)(m0 + sr) * NH + skc;
  const unsigned short* bsrc = wp_bf + (size_t)(n0 + sr) * NH + skc;
  const int sswz = (sr & 15) << 3;
  float4v acc[4][4] = {};
  for (int k0 = 0; k0 < NH; k0 += 64) {
    ushort8v av4[4], bv4[4];
#pragma unroll
    for (int i = 0; i < 4; ++i) av4[i] = *(const ushort8v*)(asrc + k0 + 8 * i);
#pragma unroll
    for (int i = 0; i < 4; ++i) bv4[i] = *(const ushort8v*)(bsrc + k0 + 8 * i);
    __syncthreads();
#pragma unroll
    for (int i = 0; i < 4; ++i) {
      *(ushort8v*)&As[((sr << 6) + skc + 8 * i) ^ sswz] = av4[i];
      *(ushort8v*)&Bs[((sr << 6) + skc + 8 * i) ^ sswz] = bv4[i];
    }
    __syncthreads();
#pragma unroll
    for (int ks = 0; ks < 2; ++ks) {
      const int koff = (ks << 5) + (bq << 3);
      short8v af[4], bf_[4];
#pragma unroll
      for (int mt = 0; mt < 4; ++mt) {
        const int ar = wm + mt * 16 + cl;
        af[mt] = *(const short8v*)&As[((ar << 6) + koff) ^ ((ar & 15) << 3)];
      }
#pragma unroll
      for (int nt = 0; nt < 4; ++nt) {
        const int br = wn + nt * 16 + cl;
        bf_[nt] = *(const short8v*)&Bs[((br << 6) + koff) ^ ((br & 15) << 3)];
      }
#pragma unroll
      for (int mt = 0; mt < 4; ++mt)
#pragma unroll
        for (int nt = 0; nt < 4; ++nt)
          acc[mt][nt] =
              __builtin_amdgcn_mfma_f32_16x16x32_bf16(af[mt], bf_[nt], acc[mt][nt], 0, 0, 0);
    }
  }
#pragma unroll
  for (int mt = 0; mt < 4; ++mt) {
    const int mb = m0 + wm + mt * 16 + (bq << 2);
#pragma unroll
    for (int nt = 0; nt < 4; ++nt) {
      const int n = n0 + wn + nt * 16 + cl;
      if (n < NPV) {
        const float bn = bias[n];
#pragma unroll
        for (int i = 0; i < 4; ++i)
          if (mb + i < 8128)
            out[(size_t)(mb + i) * NPV + n] = acc[mt][nt][i] + bn;
      }
    }
  }
}

extern "C" void kernel_launch(void* const* d_in, const int* in_sizes, int n_in,
                              void* d_out, int out_size, void* d_ws, size_t ws_size,
                              hipStream_t stream) {
  (void)in_sizes; (void)n_in; (void)out_size; (void)ws_size;
  const float* elmo     = (const float*)d_in[0];
  const float* w_ih_f   = (const float*)d_in[1];
  const float* w_hh_f   = (const float*)d_in[2];
  const float* b_f      = (const float*)d_in[3];
  const float* w_ih_b   = (const float*)d_in[4];
  const float* w_hh_b   = (const float*)d_in[5];
  const float* b_b      = (const float*)d_in[6];
  const float* W1       = (const float*)d_in[7];
  const float* W2       = (const float*)d_in[8];
  const float* word_W   = (const float*)d_in[9];
  const float* word_b   = (const float*)d_in[10];
  const float* phrase_W = (const float*)d_in[11];
  const float* phrase_b = (const float*)d_in[12];
  const int* cinfo      = (const int*)d_in[13];
  const int* lab        = (const int*)d_in[15];

  unsigned short* xpb   = (unsigned short*)d_ws;
  float* h_region       = (float*)(xpb + XPB_SZ);   // reused for vecp_bf/wp_bf
  unsigned short* vecp_bf = (unsigned short*)h_region;
  unsigned short* wp_bf   = vecp_bf + VP_SZ;
  float* vec            = h_region + H_SZ;
  unsigned short* h_bf  = (unsigned short*)(vec + VEC_SZ);
  unsigned short* e_bf  = h_bf + HB_SZ;
  unsigned short* W_bf  = e_bf + EB_SZ;
  unsigned short* W12_bf  = W_bf + WB_SZ;
  unsigned short* wout_bf = W12_bf + W12_SZ;
  unsigned short* vec_bf  = wout_bf + WO_SZ;
  int* bar              = (int*)(vec_bf + VB_SZ);

  float* out_word = (float*)d_out;                       // 8192 x 511
  float* out_phr  = out_word + (size_t)8192 * NWV;       // 8128 x 152
  float* out_lw   = out_phr + (size_t)8128 * NPV;        // 8192
  float* out_lp   = out_lw + 8192;                       // 8128

  k_cvt<<<dim3(2048), 256, 0, stream>>>(elmo, w_ih_f, w_ih_b, W1, W2, word_W,
                                        phrase_W, e_bf, W_bf, W12_bf, wout_bf,
                                        wp_bf, bar);
  k_xp<<<dim3(32, 64), 256, 0, stream>>>(e_bf, W_bf, b_f, b_b, xpb);
  k_lstm<<<dim3(64), 256, 0, stream>>>(w_hh_f, w_hh_b, xpb, h_bf, bar);
  k_comb<<<dim3(8, 128), 256, 0, stream>>>(h_bf, W12_bf, vec);
  k_norm<<<dim3(2048), 256, 0, stream>>>(vec, vec_bf);
  k_tail<<<dim3(336), 512, 0, stream>>>(vec, cinfo, vecp_bf, vec_bf, wout_bf,
                                        word_b, out_word, lab, out_lw, out_lp);
  k_outp<<<dim3(2, 64), 256, 0, stream>>>(vecp_bf, wp_bf, phrase_b, out_phr);
}